// Round 5
// baseline (1139.485 us; speedup 1.0000x reference)
//
#include <hip/hip_runtime.h>
#include <hip/hip_bf16.h>
#include <stdint.h>

#define BB 4
#define NN 16384
#define HDIM 1024
#define HH 8
#define MM 32
#define DD 128
#define K2HD 2048

typedef unsigned int u32;
typedef unsigned short u16;
typedef __attribute__((ext_vector_type(8))) short short8;
typedef __attribute__((ext_vector_type(4))) float f32x4;

__device__ __forceinline__ float bflo(u32 v) {
    union { u32 u; float f; } c; c.u = v << 16; return c.f;
}
__device__ __forceinline__ float bfhi(u32 v) {
    union { u32 u; float f; } c; c.u = v & 0xffff0000u; return c.f;
}
__device__ __forceinline__ float bf2f(u16 v) {
    union { u32 u; float f; } c; c.u = ((u32)v) << 16; return c.f;
}
__device__ __forceinline__ u16 f2bf(float f) {
    union { float f; u32 u; } c; c.f = f;
    u32 r = c.u + 0x7fffu + ((c.u >> 16) & 1u);
    return (u16)(r >> 16);
}

__device__ __forceinline__ void gload16(const u16* g, u16* l) {
    __builtin_amdgcn_global_load_lds(
        (const __attribute__((address_space(1))) void*)g,
        (__attribute__((address_space(3))) void*)l, 16, 0, 0);
}

// ---------------------------------------------------------------- convert
__global__ void convert_kernel(const float* __restrict__ x, const float* __restrict__ wkv,
                               const float* __restrict__ outw,
                               u16* __restrict__ xb, u16* __restrict__ wkvb, u16* __restrict__ outwb,
                               const float* __restrict__ wtq_bias, float* __restrict__ out_misc) {
    size_t i = (size_t)blockIdx.x * blockDim.x + threadIdx.x;
    size_t stride = (size_t)gridDim.x * blockDim.x;
    const size_t nx = (size_t)BB * NN * HDIM / 4;     // uint4 groups of 4 floats
    const size_t nw = (size_t)K2HD * HDIM / 4;
    const size_t no = (size_t)HDIM * HDIM / 4;
    for (size_t j = i; j < nx; j += stride) {
        float4 v = ((const float4*)x)[j];
        ushort4 o; o.x = f2bf(v.x); o.y = f2bf(v.y); o.z = f2bf(v.z); o.w = f2bf(v.w);
        ((ushort4*)xb)[j] = o;
    }
    for (size_t j = i; j < nw; j += stride) {
        float4 v = ((const float4*)wkv)[j];
        ushort4 o; o.x = f2bf(v.x); o.y = f2bf(v.y); o.z = f2bf(v.z); o.w = f2bf(v.w);
        ((ushort4*)wkvb)[j] = o;
    }
    for (size_t j = i; j < no; j += stride) {
        float4 v = ((const float4*)outw)[j];
        ushort4 o; o.x = f2bf(v.x); o.y = f2bf(v.y); o.z = f2bf(v.z); o.w = f2bf(v.w);
        ((ushort4*)outwb)[j] = o;
    }
    if (blockIdx.x == 0) {
        if (threadIdx.x == 0) out_misc[0] = 1.0f;               // temperature
        if (threadIdx.x < HH * MM) out_misc[1 + threadIdx.x] = wtq_bias[threadIdx.x];  // bias output
    }
}

// ---------------------------------------------------------------- GEMM C = A @ B^T (+bias)
// 256x256 tile, BK=32, 512 threads (8 waves 2Mx4N), 4-slot LDS ring (128 KiB),
// counted vmcnt(8) pipeline, 4 phases per K-tile (quadrant MFMA clusters with
// double-barrier + setprio), XOR-swizzled LDS, XCD grid swizzle.
template<int OUT_F32>
__global__ __launch_bounds__(512, 2) void gemm256(
        const u16* __restrict__ A, const u16* __restrict__ Bm,
        const float* __restrict__ bias, void* __restrict__ Cout,
        int Ncols, int Kd, int ntn) {
    __shared__ u16 ldsA[4][8192];   // 4 ring slots x [256 rows][32 k] bf16 (64 KiB)
    __shared__ u16 ldsB[4][8192];   // 64 KiB
    const int t = threadIdx.x, l = t & 63, w = t >> 6;
    const int wr = w >> 2, wc = w & 3;

    const int nwg = gridDim.x;
    const int cpx = nwg >> 3;
    const int bid = blockIdx.x;
    const int swz = (bid & 7) * cpx + (bid >> 3);
    const int tm = swz / ntn, tn = swz % ntn;

    f32x4 acc[8][4];
    const f32x4 zero = {0.f, 0.f, 0.f, 0.f};
#pragma unroll
    for (int mi = 0; mi < 8; mi++)
#pragma unroll
        for (int ni = 0; ni < 4; ni++) acc[mi][ni] = zero;

    const int srow = w * 16 + (l >> 2);
    const int kel  = ((l & 3) ^ ((l >> 3) & 3)) * 8;
    const u16* gA0 = A  + (size_t)(tm * 256 + srow) * Kd + kel;
    const u16* gA1 = gA0 + (size_t)128 * Kd;
    const u16* gB0 = Bm + (size_t)(tn * 256 + srow) * Kd + kel;
    const u16* gB1 = gB0 + (size_t)128 * Kd;
    const int ldst = w * 512;

    const int arow = wr * 128 + (l & 15);
    const int brow = wc * 64 + (l & 15);
    const int koff = (((l >> 4) ^ ((l >> 1) & 3)) << 3);

    const int nK = Kd >> 5;

    {
        gload16(gA0, &ldsA[0][ldst]);           gload16(gA1, &ldsA[0][4096 + ldst]);
        gload16(gB0, &ldsB[0][ldst]);           gload16(gB1, &ldsB[0][4096 + ldst]);
        __builtin_amdgcn_sched_barrier(0);
        gload16(gA0 + 32, &ldsA[1][ldst]);      gload16(gA1 + 32, &ldsA[1][4096 + ldst]);
        gload16(gB0 + 32, &ldsB[1][ldst]);      gload16(gB1 + 32, &ldsB[1][4096 + ldst]);
        __builtin_amdgcn_sched_barrier(0);
        gload16(gA0 + 64, &ldsA[2][ldst]);      gload16(gA1 + 64, &ldsA[2][4096 + ldst]);
        gload16(gB0 + 64, &ldsB[2][ldst]);      gload16(gB1 + 64, &ldsB[2][4096 + ldst]);
    }
    asm volatile("s_waitcnt vmcnt(8)" ::: "memory");
    __builtin_amdgcn_s_barrier();

    for (int kt = 0; kt < nK; ++kt) {
        const int sk = kt & 3;
        const bool st = (kt + 3) < nK;
        const int ss = (kt + 3) & 3;
        const int ko = (kt + 3) * 32;

        // ---- phase 1: af03 (4 reads) + b0,b1 (2 reads); stage A-low(kt+3); Q(mi0-3,ni0-1)
        short8 a0 = *(const short8*)&ldsA[sk][(arow + 0 * 16) * 32 + koff];
        short8 a1 = *(const short8*)&ldsA[sk][(arow + 1 * 16) * 32 + koff];
        short8 a2 = *(const short8*)&ldsA[sk][(arow + 2 * 16) * 32 + koff];
        short8 a3 = *(const short8*)&ldsA[sk][(arow + 3 * 16) * 32 + koff];
        short8 b0 = *(const short8*)&ldsB[sk][(brow + 0) * 32 + koff];
        short8 b1 = *(const short8*)&ldsB[sk][(brow + 16) * 32 + koff];
        if (st) gload16(gA0 + ko, &ldsA[ss][ldst]);
        __builtin_amdgcn_s_barrier();
        __builtin_amdgcn_s_setprio(1);
        acc[0][0] = __builtin_amdgcn_mfma_f32_16x16x32_bf16(a0, b0, acc[0][0], 0, 0, 0);
        acc[1][0] = __builtin_amdgcn_mfma_f32_16x16x32_bf16(a1, b0, acc[1][0], 0, 0, 0);
        acc[2][0] = __builtin_amdgcn_mfma_f32_16x16x32_bf16(a2, b0, acc[2][0], 0, 0, 0);
        acc[3][0] = __builtin_amdgcn_mfma_f32_16x16x32_bf16(a3, b0, acc[3][0], 0, 0, 0);
        acc[0][1] = __builtin_amdgcn_mfma_f32_16x16x32_bf16(a0, b1, acc[0][1], 0, 0, 0);
        acc[1][1] = __builtin_amdgcn_mfma_f32_16x16x32_bf16(a1, b1, acc[1][1], 0, 0, 0);
        acc[2][1] = __builtin_amdgcn_mfma_f32_16x16x32_bf16(a2, b1, acc[2][1], 0, 0, 0);
        acc[3][1] = __builtin_amdgcn_mfma_f32_16x16x32_bf16(a3, b1, acc[3][1], 0, 0, 0);
        __builtin_amdgcn_s_setprio(0);
        __builtin_amdgcn_s_barrier();

        // ---- phase 2: b2,b3 (2 reads); stage A-high(kt+3); Q(mi0-3,ni2-3)
        short8 b2 = *(const short8*)&ldsB[sk][(brow + 32) * 32 + koff];
        short8 b3 = *(const short8*)&ldsB[sk][(brow + 48) * 32 + koff];
        if (st) gload16(gA1 + ko, &ldsA[ss][4096 + ldst]);
        __builtin_amdgcn_s_barrier();
        __builtin_amdgcn_s_setprio(1);
        acc[0][2] = __builtin_amdgcn_mfma_f32_16x16x32_bf16(a0, b2, acc[0][2], 0, 0, 0);
        acc[1][2] = __builtin_amdgcn_mfma_f32_16x16x32_bf16(a1, b2, acc[1][2], 0, 0, 0);
        acc[2][2] = __builtin_amdgcn_mfma_f32_16x16x32_bf16(a2, b2, acc[2][2], 0, 0, 0);
        acc[3][2] = __builtin_amdgcn_mfma_f32_16x16x32_bf16(a3, b2, acc[3][2], 0, 0, 0);
        acc[0][3] = __builtin_amdgcn_mfma_f32_16x16x32_bf16(a0, b3, acc[0][3], 0, 0, 0);
        acc[1][3] = __builtin_amdgcn_mfma_f32_16x16x32_bf16(a1, b3, acc[1][3], 0, 0, 0);
        acc[2][3] = __builtin_amdgcn_mfma_f32_16x16x32_bf16(a2, b3, acc[2][3], 0, 0, 0);
        acc[3][3] = __builtin_amdgcn_mfma_f32_16x16x32_bf16(a3, b3, acc[3][3], 0, 0, 0);
        __builtin_amdgcn_s_setprio(0);
        __builtin_amdgcn_s_barrier();

        // ---- phase 3: af47 (4 reads); stage B-low(kt+3); Q(mi4-7,ni0-1)
        short8 a4 = *(const short8*)&ldsA[sk][(arow + 4 * 16) * 32 + koff];
        short8 a5 = *(const short8*)&ldsA[sk][(arow + 5 * 16) * 32 + koff];
        short8 a6 = *(const short8*)&ldsA[sk][(arow + 6 * 16) * 32 + koff];
        short8 a7 = *(const short8*)&ldsA[sk][(arow + 7 * 16) * 32 + koff];
        if (st) gload16(gB0 + ko, &ldsB[ss][ldst]);
        __builtin_amdgcn_s_barrier();
        __builtin_amdgcn_s_setprio(1);
        acc[4][0] = __builtin_amdgcn_mfma_f32_16x16x32_bf16(a4, b0, acc[4][0], 0, 0, 0);
        acc[5][0] = __builtin_amdgcn_mfma_f32_16x16x32_bf16(a5, b0, acc[5][0], 0, 0, 0);
        acc[6][0] = __builtin_amdgcn_mfma_f32_16x16x32_bf16(a6, b0, acc[6][0], 0, 0, 0);
        acc[7][0] = __builtin_amdgcn_mfma_f32_16x16x32_bf16(a7, b0, acc[7][0], 0, 0, 0);
        acc[4][1] = __builtin_amdgcn_mfma_f32_16x16x32_bf16(a4, b1, acc[4][1], 0, 0, 0);
        acc[5][1] = __builtin_amdgcn_mfma_f32_16x16x32_bf16(a5, b1, acc[5][1], 0, 0, 0);
        acc[6][1] = __builtin_amdgcn_mfma_f32_16x16x32_bf16(a6, b1, acc[6][1], 0, 0, 0);
        acc[7][1] = __builtin_amdgcn_mfma_f32_16x16x32_bf16(a7, b1, acc[7][1], 0, 0, 0);
        __builtin_amdgcn_s_setprio(0);
        __builtin_amdgcn_s_barrier();

        // ---- phase 4: no reads; stage B-high(kt+3); Q(mi4-7,ni2-3); tile-boundary wait
        if (st) gload16(gB1 + ko, &ldsB[ss][4096 + ldst]);
        __builtin_amdgcn_s_barrier();
        __builtin_amdgcn_s_setprio(1);
        acc[4][2] = __builtin_amdgcn_mfma_f32_16x16x32_bf16(a4, b2, acc[4][2], 0, 0, 0);
        acc[5][2] = __builtin_amdgcn_mfma_f32_16x16x32_bf16(a5, b2, acc[5][2], 0, 0, 0);
        acc[6][2] = __builtin_amdgcn_mfma_f32_16x16x32_bf16(a6, b2, acc[6][2], 0, 0, 0);
        acc[7][2] = __builtin_amdgcn_mfma_f32_16x16x32_bf16(a7, b2, acc[7][2], 0, 0, 0);
        acc[4][3] = __builtin_amdgcn_mfma_f32_16x16x32_bf16(a4, b3, acc[4][3], 0, 0, 0);
        acc[5][3] = __builtin_amdgcn_mfma_f32_16x16x32_bf16(a5, b3, acc[5][3], 0, 0, 0);
        acc[6][3] = __builtin_amdgcn_mfma_f32_16x16x32_bf16(a6, b3, acc[6][3], 0, 0, 0);
        acc[7][3] = __builtin_amdgcn_mfma_f32_16x16x32_bf16(a7, b3, acc[7][3], 0, 0, 0);
        __builtin_amdgcn_s_setprio(0);

        if (kt < nK - 1) {
            if (kt <= nK - 4)      asm volatile("s_waitcnt vmcnt(8)" ::: "memory");
            else if (kt == nK - 3) asm volatile("s_waitcnt vmcnt(4)" ::: "memory");
            else                   asm volatile("s_waitcnt vmcnt(0)" ::: "memory");
            __builtin_amdgcn_s_barrier();
        }
    }

    const int cr = (l >> 4) * 4;
    const int cc = l & 15;
#pragma unroll
    for (int ni = 0; ni < 4; ni++) {
        const int col = tn * 256 + wc * 64 + ni * 16 + cc;
        const float bv = bias[col];
#pragma unroll
        for (int mi = 0; mi < 8; mi++) {
            const int row0 = tm * 256 + wr * 128 + mi * 16 + cr;
#pragma unroll
            for (int q = 0; q < 4; q++) {
                float v = acc[mi][ni][q] + bv;
                if (OUT_F32) ((float*)Cout)[(size_t)(row0 + q) * Ncols + col] = v;
                else         ((u16*)Cout)[(size_t)(row0 + q) * Ncols + col] = f2bf(v);
            }
        }
    }
}

// ---------------------------------------------------------------- fused slice pass v2
// Phase 1: S' = wtq @ xk^T via MFMA (swapped operands: lane-group softmax over m).
// Phase 2: scalar P@V accumulation (float2), xv staged via global_load_lds.
__global__ __launch_bounds__(256) void slice_pass(
        const u16* __restrict__ kv, const float* __restrict__ wtq,
        float* __restrict__ sw_out, float* __restrict__ pst, float* __restrict__ pnorm) {
    __shared__ u16 xk_lds[128 * 128];   // 32 KB: xk half-tile (swizzled), reused for xv (linear)
    __shared__ u16 wtq_lds[MM * DD];    // 8 KB, swizzled chunks
    __shared__ u16 w_lds[MM * 258];     // 16.5 KB (pitch 258: conflict-free column reads)
    const int t = threadIdx.x, l = t & 63, w = t >> 6;
    const int bh = blockIdx.y, b = bh >> 3, h = bh & 7;
    const int n0 = blockIdx.x * 256;

    // stage wtq (f32 -> bf16), chunk-swizzled: phys_chunk = (d>>3) ^ (m&7)
    for (int i = t; i < MM * DD; i += 256) {
        int m = i >> 7, d = i & 127;
        int idx = m * 128 + (((d >> 3) ^ (m & 7)) << 3) + (d & 7);
        wtq_lds[idx] = f2bf(wtq[(size_t)h * MM * DD + i]);
    }

    // staging constants: round j covers rows j*16 + (t>>4), 16B slot (t&15)
    const int srow = t >> 4;
    const int sswz = (t & 15) ^ (srow & 7);     // pre-swizzled source chunk for xk
    const int mrow = l & 15;
    const int kg = l >> 4;                       // 0..3

    // ---------------- phase 1: per half, MFMA scores + softmax over m
    for (int half = 0; half < 2; half++) {
        __syncthreads();    // wtq staged (h=0) / previous half's frag reads done (h=1)
        {
            const u16* src = kv + ((size_t)(b * NN) + n0 + half * 128 + srow) * K2HD + h * DD + sswz * 8;
            for (int j = 0; j < 8; j++)
                gload16(src + (size_t)j * 16 * K2HD, xk_lds + j * 2048 + w * 512);
        }
        __syncthreads();    // xk half staged (vmcnt drained by syncthreads)

        f32x4 s[2][2];
        const f32x4 zero = {0.f, 0.f, 0.f, 0.f};
        s[0][0] = zero; s[0][1] = zero; s[1][0] = zero; s[1][1] = zero;
#pragma unroll
        for (int ks = 0; ks < 4; ks++) {
            const int pc = (((ks << 2) + kg) ^ (l & 7)) << 3;   // swizzled byte-chunk -> elem offset
            short8 a0 = *(const short8*)&wtq_lds[mrow * 128 + pc];
            short8 a1 = *(const short8*)&wtq_lds[(16 + mrow) * 128 + pc];
            short8 bb0 = *(const short8*)&xk_lds[(w * 32 + mrow) * 128 + pc];
            short8 bb1 = *(const short8*)&xk_lds[(w * 32 + 16 + mrow) * 128 + pc];
            s[0][0] = __builtin_amdgcn_mfma_f32_16x16x32_bf16(a0, bb0, s[0][0], 0, 0, 0);
            s[0][1] = __builtin_amdgcn_mfma_f32_16x16x32_bf16(a0, bb1, s[0][1], 0, 0, 0);
            s[1][0] = __builtin_amdgcn_mfma_f32_16x16x32_bf16(a1, bb0, s[1][0], 0, 0, 0);
            s[1][1] = __builtin_amdgcn_mfma_f32_16x16x32_bf16(a1, bb1, s[1][1], 0, 0, 0);
        }

        // softmax over m (32 values live in 4-lane group {l, l^16, l^32, l^48})
#pragma unroll
        for (int nj = 0; nj < 2; nj++) {
            float mx = s[0][nj][0];
#pragma unroll
            for (int mi = 0; mi < 2; mi++)
#pragma unroll
                for (int q = 0; q < 4; q++) mx = fmaxf(mx, s[mi][nj][q]);
            mx = fmaxf(mx, __shfl_xor(mx, 16));
            mx = fmaxf(mx, __shfl_xor(mx, 32));
            float ex[2][4], sum = 0.f;
#pragma unroll
            for (int mi = 0; mi < 2; mi++)
#pragma unroll
                for (int q = 0; q < 4; q++) { ex[mi][q] = __expf(s[mi][nj][q] - mx); sum += ex[mi][q]; }
            sum += __shfl_xor(sum, 16);
            sum += __shfl_xor(sum, 32);
            const float inv = 1.f / sum;
            const int ncol = half * 128 + w * 32 + nj * 16 + mrow;
#pragma unroll
            for (int mi = 0; mi < 2; mi++)
#pragma unroll
                for (int q = 0; q < 4; q++) {
                    const int m = mi * 16 + kg * 4 + q;
                    const float wv = ex[mi][q] * inv;
                    sw_out[((size_t)bh * MM + m) * NN + n0 + ncol] = wv;
                    w_lds[m * 258 + ncol] = f2bf(wv);
                }
        }
    }

    // ---------------- phase 2: partial slice_token. thread -> (m = t>>3, d-range (t&7)*16)
    const int am = t >> 3;
    const int ad = (t & 7) * 16;
    float2 accv[8];
#pragma unroll
    for (int j = 0; j < 8; j++) accv[j] = make_float2(0.f, 0.f);
    float wsum = 0.f;

    for (int half = 0; half < 2; half++) {
        __syncthreads();    // phase-1 xk reads + w_lds writes done (h=0) / xv reads done (h=1)
        {
            const u16* src = kv + ((size_t)(b * NN) + n0 + half * 128 + srow) * K2HD + HDIM + h * DD + (t & 15) * 8;
            for (int j = 0; j < 8; j++)
                gload16(src + (size_t)j * 16 * K2HD, xk_lds + j * 2048 + w * 512);
        }
        __syncthreads();
        for (int n = 0; n < 128; n++) {
            float wv = bf2f(w_lds[am * 258 + half * 128 + n]);
            wsum += wv;
            const u32* xvr = (const u32*)&xk_lds[n * 128 + ad];
#pragma unroll
            for (int j = 0; j < 8; j++) {
                u32 xd = xvr[j];
                accv[j].x += wv * bflo(xd);
                accv[j].y += wv * bfhi(xd);
            }
        }
    }

    float* dst = &pst[(((size_t)bh * 64 + blockIdx.x) * MM + am) * DD + ad];
#pragma unroll
    for (int j = 0; j < 8; j += 2) {
        float4 v = make_float4(accv[j].x, accv[j].y, accv[j + 1].x, accv[j + 1].y);
        *(float4*)&dst[j * 2] = v;
    }
    if ((t & 7) == 0) pnorm[((size_t)bh * 64 + blockIdx.x) * MM + am] = wsum;
}

// ---------------------------------------------------------------- reduce pst partials (parallel)
__global__ __launch_bounds__(256) void reduce_pst(const float* __restrict__ pst,
                                                  const float* __restrict__ pnorm,
                                                  u16* __restrict__ st_red) {
    __shared__ float norm_lds[MM];
    const int bh = blockIdx.y, es = blockIdx.x, t = threadIdx.x;
    if (t < MM) {
        float s = 0.f;
        for (int g = 0; g < 64; g++) s += pnorm[((size_t)bh * 64 + g) * MM + t];
        norm_lds[t] = s + 1e-5f;
    }
    __syncthreads();
    const int e = es * 512 + t * 2;
    float ax = 0.f, ay = 0.f;
    for (int g = 0; g < 64; g++) {
        const float2 v = *(const float2*)&pst[((size_t)bh * 64 + g) * 4096 + e];
        ax += v.x; ay += v.y;
    }
    const float nv = norm_lds[e >> 7];
    u32 pk = (u32)f2bf(ax / nv) | ((u32)f2bf(ay / nv) << 16);
    ((u32*)st_red)[((size_t)bh * 4096 + e) >> 1] = pk;
}

// ---------------------------------------------------------------- finalize (per b,h)
__global__ void finalize_kernel(const u16* __restrict__ st_red,
                                const float* __restrict__ qkvp, float* __restrict__ attn_out,
                                float* __restrict__ otw) {
    __shared__ float qt[MM * 384];      // 48 KB
    __shared__ u16 st_lds[MM * DD];     // 8 KB
    __shared__ float dots[MM * MM];     // 4 KB
    const int bh = blockIdx.x, h = bh & 7, t = threadIdx.x;

    {
        const uint4* src = (const uint4*)(st_red + (size_t)bh * 4096);
        ((uint4*)st_lds)[t] = src[t];
        ((uint4*)st_lds)[t + 256] = src[t + 256];
    }
    __syncthreads();
    const float* qw = qkvp + (size_t)h * DD * 384;
    for (int i = 0; i < 48; i++) {
        int j = t + i * 256;
        int m = j / 384, e = j - m * 384;
        float s = 0.f;
        for (int d = 0; d < DD; d++) s += bf2f(st_lds[m * DD + d]) * qw[d * 384 + e];
        qt[m * 384 + e] = s;
    }
    __syncthreads();
    const float scale = 0.08838834764831845f;
#pragma unroll
    for (int i = 0; i < 4; i++) {
        int idx = t * 4 + i;
        int qi = idx >> 5, kj = idx & 31;
        float s = 0.f;
        for (int d = 0; d < DD; d++) s += qt[qi * 384 + d] * qt[kj * 384 + 128 + d];
        dots[idx] = s * scale;
    }
    __syncthreads();
    if (t < MM) {
        float mx = -1e30f;
        float ex[MM];
#pragma unroll
        for (int j = 0; j < MM; j++) mx = fmaxf(mx, dots[t * MM + j]);
        float sm = 0.f;
#pragma unroll
        for (int j = 0; j < MM; j++) { ex[j] = __expf(dots[t * MM + j] - mx); sm += ex[j]; }
        float inv = 1.f / sm;
#pragma unroll
        for (int j = 0; j < MM; j++) {
            float v = ex[j] * inv;
            dots[t * MM + j] = v;
            attn_out[((size_t)bh * MM + t) * MM + j] = v;
        }
    }
    __syncthreads();
#pragma unroll
    for (int i = 0; i < 16; i++) {
        int e = t + i * 256;
        int m = e >> 7, d = e & 127;
        float s = 0.f;
#pragma unroll
        for (int j = 0; j < MM; j++) s += dots[m * MM + j] * qt[j * 384 + 256 + d];
        otw[(size_t)bh * 4096 + e] = s;
    }
}

// ---------------------------------------------------------------- scatter y[n, h*128+d] = sum_m ot[m,d]*w[m,n]
__global__ void scatter_kernel(const float* __restrict__ otw, const float* __restrict__ sw,
                               u16* __restrict__ y) {
    __shared__ float ot_lds[MM * 132];  // phys: m*132 + (d>>5)*33 + (d&31)
    __shared__ float w_lds[MM * 64];
    const int bh = blockIdx.y, b = bh >> 3, h = bh & 7, t = threadIdx.x;
    const int n0 = blockIdx.x * 64;

    for (int i = t; i < MM * DD; i += 256) {
        int m = i >> 7, d = i & 127;
        ot_lds[m * 132 + (d >> 5) * 33 + (d & 31)] = otw[(size_t)bh * 4096 + i];
    }
    for (int i = t; i < MM * 64; i += 256) {
        int m = i >> 6, nl = i & 63;
        w_lds[i] = sw[((size_t)bh * MM + m) * NN + n0 + nl];
    }
    __syncthreads();

    const int nl = t >> 2, dq = t & 3;
    float acc[32];
#pragma unroll
    for (int j = 0; j < 32; j++) acc[j] = 0.f;
    for (int m = 0; m < MM; m++) {
        float wv = w_lds[m * 64 + nl];
        const float* otr = &ot_lds[m * 132 + dq * 33];
#pragma unroll
        for (int j = 0; j < 32; j++) acc[j] += wv * otr[j];
    }
    u16* dstp = y + (size_t)(b * NN + n0 + nl) * HDIM + h * DD + dq * 32;
#pragma unroll
    for (int j = 0; j < 16; j++) {
        u32 pk = (u32)f2bf(acc[2 * j]) | ((u32)f2bf(acc[2 * j + 1]) << 16);
        ((u32*)dstp)[j] = pk;
    }
}

// ---------------------------------------------------------------- launch
extern "C" void kernel_launch(void* const* d_in, const int* in_sizes, int n_in,
                              void* d_out, int out_size, void* d_ws, size_t ws_size,
                              hipStream_t stream) {
    const float* x        = (const float*)d_in[0];
    const float* wkv      = (const float*)d_in[1];
    const float* bkv      = (const float*)d_in[2];
    const float* wtq      = (const float*)d_in[3];
    const float* wtq_bias = (const float*)d_in[4];
    const float* qkvp     = (const float*)d_in[5];
    const float* outw     = (const float*)d_in[6];
    const float* outb     = (const float*)d_in[7];

    float* out  = (float*)d_out;
    float* out0 = out;                      // [B,N,HD]           67108864
    float* out1 = out + 67108864;           // slice_weights      16777216
    float* out2 = out + 83886080;           // temperature + bias
    float* out4 = out + 83886337;           // attn_weights       32768

    char* ws = (char*)d_ws;
    u16*   xb    = (u16*)(ws);                          // 134217728 B (reused as y after GEMM1)
    u16*   kvb   = (u16*)(ws + 134217728);              // 268435456 B
    u16*   st_red= (u16*)(ws + 134217728);              // aliases kvb (kv dead after slice_pass)
    u16*   wkvb  = (u16*)(ws + 402653184);              // 4194304 B
    u16*   outwb = (u16*)(ws + 406847488);              // 2097152 B
    float* pst   = (float*)(ws + 408944640);            // 33554432 B
    float* pnorm = (float*)(ws + 442499072);            // 262144 B
    float* otws  = (float*)(ws + 442761216);            // 524288 B

    convert_kernel<<<dim3(2048), dim3(256), 0, stream>>>(x, wkv, outw, xb, wkvb, outwb, wtq_bias, out2);
    gemm256<0><<<dim3(256 * 8), dim3(512), 0, stream>>>(xb, wkvb, bkv, (void*)kvb, K2HD, HDIM, 8);
    slice_pass<<<dim3(64, 32), dim3(256), 0, stream>>>(kvb, wtq, out1, pst, pnorm);
    reduce_pst<<<dim3(8, 32), dim3(256), 0, stream>>>(pst, pnorm, st_red);
    finalize_kernel<<<dim3(32), dim3(256), 0, stream>>>(st_red, qkvp, out4, otws);
    scatter_kernel<<<dim3(256, 32), dim3(256), 0, stream>>>(otws, out1, xb);
    gemm256<1><<<dim3(256 * 4), dim3(512), 0, stream>>>(xb, outwb, outb, (void*)out0, HDIM, HDIM, 4);
}

// Round 6
// 1067.002 us; speedup vs baseline: 1.0679x; 1.0679x over previous
//
#include <hip/hip_runtime.h>
#include <hip/hip_bf16.h>
#include <stdint.h>

#define BB 4
#define NN 16384
#define HDIM 1024
#define HH 8
#define MM 32
#define DD 128
#define K2HD 2048

typedef unsigned int u32;
typedef unsigned short u16;
typedef __attribute__((ext_vector_type(8))) short short8;
typedef __attribute__((ext_vector_type(4))) float f32x4;

__device__ __forceinline__ float bflo(u32 v) {
    union { u32 u; float f; } c; c.u = v << 16; return c.f;
}
__device__ __forceinline__ float bfhi(u32 v) {
    union { u32 u; float f; } c; c.u = v & 0xffff0000u; return c.f;
}
__device__ __forceinline__ float bf2f(u16 v) {
    union { u32 u; float f; } c; c.u = ((u32)v) << 16; return c.f;
}
__device__ __forceinline__ u16 f2bf(float f) {
    union { float f; u32 u; } c; c.f = f;
    u32 r = c.u + 0x7fffu + ((c.u >> 16) & 1u);
    return (u16)(r >> 16);
}

__device__ __forceinline__ void gload16(const u16* g, u16* l) {
    __builtin_amdgcn_global_load_lds(
        (const __attribute__((address_space(1))) void*)g,
        (__attribute__((address_space(3))) void*)l, 16, 0, 0);
}

#define MFMA16(a, b, c) __builtin_amdgcn_mfma_f32_16x16x32_bf16(a, b, c, 0, 0, 0)

// ---------------------------------------------------------------- convert
__global__ void convert_kernel(const float* __restrict__ x, const float* __restrict__ wkv,
                               const float* __restrict__ outw,
                               u16* __restrict__ xb, u16* __restrict__ wkvb, u16* __restrict__ outwb,
                               const float* __restrict__ wtq_bias, float* __restrict__ out_misc) {
    size_t i = (size_t)blockIdx.x * blockDim.x + threadIdx.x;
    size_t stride = (size_t)gridDim.x * blockDim.x;
    const size_t nx = (size_t)BB * NN * HDIM / 4;     // uint4 groups of 4 floats
    const size_t nw = (size_t)K2HD * HDIM / 4;
    const size_t no = (size_t)HDIM * HDIM / 4;
    for (size_t j = i; j < nx; j += stride) {
        float4 v = ((const float4*)x)[j];
        ushort4 o; o.x = f2bf(v.x); o.y = f2bf(v.y); o.z = f2bf(v.z); o.w = f2bf(v.w);
        ((ushort4*)xb)[j] = o;
    }
    for (size_t j = i; j < nw; j += stride) {
        float4 v = ((const float4*)wkv)[j];
        ushort4 o; o.x = f2bf(v.x); o.y = f2bf(v.y); o.z = f2bf(v.z); o.w = f2bf(v.w);
        ((ushort4*)wkvb)[j] = o;
    }
    for (size_t j = i; j < no; j += stride) {
        float4 v = ((const float4*)outw)[j];
        ushort4 o; o.x = f2bf(v.x); o.y = f2bf(v.y); o.z = f2bf(v.z); o.w = f2bf(v.w);
        ((ushort4*)outwb)[j] = o;
    }
    if (blockIdx.x == 0) {
        if (threadIdx.x == 0) out_misc[0] = 1.0f;               // temperature
        if (threadIdx.x < HH * MM) out_misc[1 + threadIdx.x] = wtq_bias[threadIdx.x];  // bias output
    }
}

// ---------------------------------------------------------------- GEMM C = A @ B^T (+bias)
// m201-style 8-phase: 256x256 tile, BK=64, 512 threads (8 waves 2Mx4N).
// LDS [2 dbuf][2 M-half][128x64] per operand (128 KiB). 4 phases per K-tile,
// each = {ds_read subtile || stage 1 half-tile -> barrier -> lgkmcnt(0) ->
// 16 MFMA (setprio) -> barrier}; counted vmcnt(4) once per K-tile (never 0
// mid-loop). Chunk-XOR swizzle both-sides (pre-swizzled gload source +
// swizzled ds_read). XCD-aware bijective grid swizzle.
template<int OUT_F32>
__global__ __launch_bounds__(512, 1) void gemm256_8p(
        const u16* __restrict__ A, const u16* __restrict__ Bm,
        const float* __restrict__ bias, void* __restrict__ Cout,
        int Ncols, int Kd, int ntn) {
    __shared__ u16 ldsA[2][2][8192];   // [dbuf][half][128 rows x 64 k]
    __shared__ u16 ldsB[2][2][8192];
    const int t = threadIdx.x, l = t & 63, w = t >> 6;
    const int wr = w >> 2, wc = w & 3;

    const int nwg = gridDim.x, cpx = nwg >> 3, bid = blockIdx.x;
    const int swz = (bid & 7) * cpx + (bid >> 3);
    const int tm = swz / ntn, tn = swz % ntn;

    f32x4 acc[8][4];
    const f32x4 zero = {0.f, 0.f, 0.f, 0.f};
#pragma unroll
    for (int mi = 0; mi < 8; mi++)
#pragma unroll
        for (int ni = 0; ni < 4; ni++) acc[mi][ni] = zero;

    // staging: round j covers rows H*128 + j*64 + w*8 + (l>>3); phys 16B chunk (l&7)
    // holds logical chunk (l&7)^(row&7) -> pre-swizzled global source.
    const int srow = w * 8 + (l >> 3);
    const int skel = ((l & 7) ^ ((l >> 3) & 7)) * 8;
    const u16* gA = A  + (size_t)(tm * 256 + srow) * Kd + skel;
    const u16* gB = Bm + (size_t)(tn * 256 + srow) * Kd + skel;
    const int ldo = w * 512 + l * 8;    // dest element offset within a 64-row block

#define STAGE_A(T, H) { const u16* g_ = gA + (size_t)((H) * 128) * Kd + (T) * 64; \
    u16* d_ = &ldsA[(T) & 1][H][ldo]; gload16(g_, d_); gload16(g_ + (size_t)64 * Kd, d_ + 4096); }
#define STAGE_B(T, H) { const u16* g_ = gB + (size_t)((H) * 128) * Kd + (T) * 64; \
    u16* d_ = &ldsB[(T) & 1][H][ldo]; gload16(g_, d_); gload16(g_ + (size_t)64 * Kd, d_ + 4096); }

    // ds_read side: row r (r&7 == l&7 for our patterns), logical chunk kk*4+(l>>4)
    const int m16 = l & 15;
    const int ck0 = (((l >> 4) + 0) ^ (l & 7)) << 3;
    const int ck1 = (((l >> 4) + 4) ^ (l & 7)) << 3;
    const int brb = (wc & 1) * 64;      // B row base within its half

    const int nT = Kd >> 6;             // K-tiles of 64 (=16 here)

    // prologue: tile0 {A0,A1,B0,B1}, tile1 {B0,B1}; A(1) staged in tile0 q0/q1
    STAGE_A(0, 0); STAGE_A(0, 1); STAGE_B(0, 0); STAGE_B(0, 1);
    STAGE_B(1, 0); STAGE_B(1, 1);
    asm volatile("s_waitcnt vmcnt(4)" ::: "memory");   // tile0's 8 loads landed
    __builtin_amdgcn_s_barrier();

    for (int kt = 0; kt < nT; ++kt) {
        const int sl = kt & 1;
        const u16* lA = ldsA[sl][wr];
        const u16* lB = ldsB[sl][wc >> 1];
        short8 aF[4][2], bF[4][2];

        // ---- q0: 12 ds_reads (A fr0-3, B fc0-1); stage A0(kt+1); acc[0-3][0-1]
#pragma unroll
        for (int fr = 0; fr < 4; fr++) {
            aF[fr][0] = *(const short8*)&lA[(fr * 16 + m16) * 64 + ck0];
            aF[fr][1] = *(const short8*)&lA[(fr * 16 + m16) * 64 + ck1];
        }
#pragma unroll
        for (int fc = 0; fc < 2; fc++) {
            bF[fc][0] = *(const short8*)&lB[(brb + fc * 16 + m16) * 64 + ck0];
            bF[fc][1] = *(const short8*)&lB[(brb + fc * 16 + m16) * 64 + ck1];
        }
        if (kt + 1 < nT) STAGE_A(kt + 1, 0);
        __builtin_amdgcn_s_barrier();
        asm volatile("s_waitcnt lgkmcnt(0)" ::: "memory");
        __builtin_amdgcn_s_setprio(1);
#pragma unroll
        for (int kk = 0; kk < 2; kk++)
#pragma unroll
            for (int mi = 0; mi < 4; mi++) {
                acc[mi][0] = MFMA16(aF[mi][kk], bF[0][kk], acc[mi][0]);
                acc[mi][1] = MFMA16(aF[mi][kk], bF[1][kk], acc[mi][1]);
            }
        __builtin_amdgcn_s_setprio(0);
        __builtin_amdgcn_s_barrier();

        // ---- q1: 4 ds_reads (B fc2-3); stage A1(kt+1); acc[0-3][2-3]
#pragma unroll
        for (int fc = 2; fc < 4; fc++) {
            bF[fc][0] = *(const short8*)&lB[(brb + fc * 16 + m16) * 64 + ck0];
            bF[fc][1] = *(const short8*)&lB[(brb + fc * 16 + m16) * 64 + ck1];
        }
        if (kt + 1 < nT) STAGE_A(kt + 1, 1);
        __builtin_amdgcn_s_barrier();
        asm volatile("s_waitcnt lgkmcnt(0)" ::: "memory");
        __builtin_amdgcn_s_setprio(1);
#pragma unroll
        for (int kk = 0; kk < 2; kk++)
#pragma unroll
            for (int mi = 0; mi < 4; mi++) {
                acc[mi][2] = MFMA16(aF[mi][kk], bF[2][kk], acc[mi][2]);
                acc[mi][3] = MFMA16(aF[mi][kk], bF[3][kk], acc[mi][3]);
            }
        __builtin_amdgcn_s_setprio(0);
        __builtin_amdgcn_s_barrier();

        // ---- q2: 8 ds_reads (A fr4-7, reuse aF); stage B0(kt+2); acc[4-7][0-1]
#pragma unroll
        for (int fr = 0; fr < 4; fr++) {
            aF[fr][0] = *(const short8*)&lA[((fr + 4) * 16 + m16) * 64 + ck0];
            aF[fr][1] = *(const short8*)&lA[((fr + 4) * 16 + m16) * 64 + ck1];
        }
        if (kt + 2 < nT) STAGE_B(kt + 2, 0);
        __builtin_amdgcn_s_barrier();
        asm volatile("s_waitcnt lgkmcnt(0)" ::: "memory");
        __builtin_amdgcn_s_setprio(1);
#pragma unroll
        for (int kk = 0; kk < 2; kk++)
#pragma unroll
            for (int mi = 0; mi < 4; mi++) {
                acc[4 + mi][0] = MFMA16(aF[mi][kk], bF[0][kk], acc[4 + mi][0]);
                acc[4 + mi][1] = MFMA16(aF[mi][kk], bF[1][kk], acc[4 + mi][1]);
            }
        __builtin_amdgcn_s_setprio(0);
        __builtin_amdgcn_s_barrier();

        // ---- q3: no reads; stage B1(kt+2); acc[4-7][2-3]; counted vmcnt + barrier
        if (kt + 2 < nT) STAGE_B(kt + 2, 1);
        __builtin_amdgcn_s_barrier();
        __builtin_amdgcn_s_setprio(1);
#pragma unroll
        for (int kk = 0; kk < 2; kk++)
#pragma unroll
            for (int mi = 0; mi < 4; mi++) {
                acc[4 + mi][2] = MFMA16(aF[mi][kk], bF[2][kk], acc[4 + mi][2]);
                acc[4 + mi][3] = MFMA16(aF[mi][kk], bF[3][kk], acc[4 + mi][3]);
            }
        __builtin_amdgcn_s_setprio(0);
        if (kt < nT - 1) {
            if (kt + 2 < nT) asm volatile("s_waitcnt vmcnt(4)" ::: "memory");
            else             asm volatile("s_waitcnt vmcnt(0)" ::: "memory");
            __builtin_amdgcn_s_barrier();
        }
    }
#undef STAGE_A
#undef STAGE_B

    // ---- epilogue
    const int cr = (l >> 4) * 4;
    const int cc = l & 15;
#pragma unroll
    for (int ni = 0; ni < 4; ni++) {
        const int col = tn * 256 + wc * 64 + ni * 16 + cc;
        const float bv = bias[col];
#pragma unroll
        for (int mi = 0; mi < 8; mi++) {
            const int row0 = tm * 256 + wr * 128 + mi * 16 + cr;
#pragma unroll
            for (int q = 0; q < 4; q++) {
                float v = acc[mi][ni][q] + bv;
                if (OUT_F32) ((float*)Cout)[(size_t)(row0 + q) * Ncols + col] = v;
                else         ((u16*)Cout)[(size_t)(row0 + q) * Ncols + col] = f2bf(v);
            }
        }
    }
}

// ---------------------------------------------------------------- fused slice pass v2
// Phase 1: S' = wtq @ xk^T via MFMA (swapped operands: lane-group softmax over m).
// Phase 2: scalar P@V accumulation (float2), xv staged via global_load_lds.
__global__ __launch_bounds__(256) void slice_pass(
        const u16* __restrict__ kv, const float* __restrict__ wtq,
        float* __restrict__ sw_out, float* __restrict__ pst, float* __restrict__ pnorm) {
    __shared__ u16 xk_lds[128 * 128];   // 32 KB: xk half-tile (swizzled), reused for xv (linear)
    __shared__ u16 wtq_lds[MM * DD];    // 8 KB, swizzled chunks
    __shared__ u16 w_lds[MM * 258];     // 16.5 KB (pitch 258: conflict-free column reads)
    const int t = threadIdx.x, l = t & 63, w = t >> 6;
    const int bh = blockIdx.y, b = bh >> 3, h = bh & 7;
    const int n0 = blockIdx.x * 256;

    // stage wtq (f32 -> bf16), chunk-swizzled: phys_chunk = (d>>3) ^ (m&7)
    for (int i = t; i < MM * DD; i += 256) {
        int m = i >> 7, d = i & 127;
        int idx = m * 128 + (((d >> 3) ^ (m & 7)) << 3) + (d & 7);
        wtq_lds[idx] = f2bf(wtq[(size_t)h * MM * DD + i]);
    }

    // staging constants: round j covers rows j*16 + (t>>4), 16B slot (t&15)
    const int srow = t >> 4;
    const int sswz = (t & 15) ^ (srow & 7);     // pre-swizzled source chunk for xk
    const int mrow = l & 15;
    const int kg = l >> 4;                       // 0..3

    // ---------------- phase 1: per half, MFMA scores + softmax over m
    for (int half = 0; half < 2; half++) {
        __syncthreads();    // wtq staged (h=0) / previous half's frag reads done (h=1)
        {
            const u16* src = kv + ((size_t)(b * NN) + n0 + half * 128 + srow) * K2HD + h * DD + sswz * 8;
            for (int j = 0; j < 8; j++)
                gload16(src + (size_t)j * 16 * K2HD, xk_lds + j * 2048 + w * 512);
        }
        __syncthreads();    // xk half staged (vmcnt drained by syncthreads)

        f32x4 s[2][2];
        const f32x4 zero = {0.f, 0.f, 0.f, 0.f};
        s[0][0] = zero; s[0][1] = zero; s[1][0] = zero; s[1][1] = zero;
#pragma unroll
        for (int ks = 0; ks < 4; ks++) {
            const int pc = (((ks << 2) + kg) ^ (l & 7)) << 3;   // swizzled byte-chunk -> elem offset
            short8 a0 = *(const short8*)&wtq_lds[mrow * 128 + pc];
            short8 a1 = *(const short8*)&wtq_lds[(16 + mrow) * 128 + pc];
            short8 bb0 = *(const short8*)&xk_lds[(w * 32 + mrow) * 128 + pc];
            short8 bb1 = *(const short8*)&xk_lds[(w * 32 + 16 + mrow) * 128 + pc];
            s[0][0] = MFMA16(a0, bb0, s[0][0]);
            s[0][1] = MFMA16(a0, bb1, s[0][1]);
            s[1][0] = MFMA16(a1, bb0, s[1][0]);
            s[1][1] = MFMA16(a1, bb1, s[1][1]);
        }

        // softmax over m (32 values live in 4-lane group {l, l^16, l^32, l^48})
#pragma unroll
        for (int nj = 0; nj < 2; nj++) {
            float mx = s[0][nj][0];
#pragma unroll
            for (int mi = 0; mi < 2; mi++)
#pragma unroll
                for (int q = 0; q < 4; q++) mx = fmaxf(mx, s[mi][nj][q]);
            mx = fmaxf(mx, __shfl_xor(mx, 16));
            mx = fmaxf(mx, __shfl_xor(mx, 32));
            float ex[2][4], sum = 0.f;
#pragma unroll
            for (int mi = 0; mi < 2; mi++)
#pragma unroll
                for (int q = 0; q < 4; q++) { ex[mi][q] = __expf(s[mi][nj][q] - mx); sum += ex[mi][q]; }
            sum += __shfl_xor(sum, 16);
            sum += __shfl_xor(sum, 32);
            const float inv = 1.f / sum;
            const int ncol = half * 128 + w * 32 + nj * 16 + mrow;
#pragma unroll
            for (int mi = 0; mi < 2; mi++)
#pragma unroll
                for (int q = 0; q < 4; q++) {
                    const int m = mi * 16 + kg * 4 + q;
                    const float wv = ex[mi][q] * inv;
                    sw_out[((size_t)bh * MM + m) * NN + n0 + ncol] = wv;
                    w_lds[m * 258 + ncol] = f2bf(wv);
                }
        }
    }

    // ---------------- phase 2: partial slice_token. thread -> (m = t>>3, d-range (t&7)*16)
    const int am = t >> 3;
    const int ad = (t & 7) * 16;
    float2 accv[8];
#pragma unroll
    for (int j = 0; j < 8; j++) accv[j] = make_float2(0.f, 0.f);
    float wsum = 0.f;

    for (int half = 0; half < 2; half++) {
        __syncthreads();    // phase-1 xk reads + w_lds writes done (h=0) / xv reads done (h=1)
        {
            const u16* src = kv + ((size_t)(b * NN) + n0 + half * 128 + srow) * K2HD + HDIM + h * DD + (t & 15) * 8;
            for (int j = 0; j < 8; j++)
                gload16(src + (size_t)j * 16 * K2HD, xk_lds + j * 2048 + w * 512);
        }
        __syncthreads();
        for (int n = 0; n < 128; n++) {
            float wv = bf2f(w_lds[am * 258 + half * 128 + n]);
            wsum += wv;
            const u32* xvr = (const u32*)&xk_lds[n * 128 + ad];
#pragma unroll
            for (int j = 0; j < 8; j++) {
                u32 xd = xvr[j];
                accv[j].x += wv * bflo(xd);
                accv[j].y += wv * bfhi(xd);
            }
        }
    }

    float* dst = &pst[(((size_t)bh * 64 + blockIdx.x) * MM + am) * DD + ad];
#pragma unroll
    for (int j = 0; j < 8; j += 2) {
        float4 v = make_float4(accv[j].x, accv[j].y, accv[j + 1].x, accv[j + 1].y);
        *(float4*)&dst[j * 2] = v;
    }
    if ((t & 7) == 0) pnorm[((size_t)bh * 64 + blockIdx.x) * MM + am] = wsum;
}

// ---------------------------------------------------------------- reduce pst partials (parallel)
__global__ __launch_bounds__(256) void reduce_pst(const float* __restrict__ pst,
                                                  const float* __restrict__ pnorm,
                                                  u16* __restrict__ st_red) {
    __shared__ float norm_lds[MM];
    const int bh = blockIdx.y, es = blockIdx.x, t = threadIdx.x;
    if (t < MM) {
        float s = 0.f;
        for (int g = 0; g < 64; g++) s += pnorm[((size_t)bh * 64 + g) * MM + t];
        norm_lds[t] = s + 1e-5f;
    }
    __syncthreads();
    const int e = es * 512 + t * 2;
    float ax = 0.f, ay = 0.f;
    for (int g = 0; g < 64; g++) {
        const float2 v = *(const float2*)&pst[((size_t)bh * 64 + g) * 4096 + e];
        ax += v.x; ay += v.y;
    }
    const float nv = norm_lds[e >> 7];
    u32 pk = (u32)f2bf(ax / nv) | ((u32)f2bf(ay / nv) << 16);
    ((u32*)st_red)[((size_t)bh * 4096 + e) >> 1] = pk;
}

// ---------------------------------------------------------------- finalize (per b,h)
__global__ void finalize_kernel(const u16* __restrict__ st_red,
                                const float* __restrict__ qkvp, float* __restrict__ attn_out,
                                float* __restrict__ otw) {
    __shared__ float qt[MM * 384];      // 48 KB
    __shared__ u16 st_lds[MM * DD];     // 8 KB
    __shared__ float dots[MM * MM];     // 4 KB
    const int bh = blockIdx.x, h = bh & 7, t = threadIdx.x;

    {
        const uint4* src = (const uint4*)(st_red + (size_t)bh * 4096);
        ((uint4*)st_lds)[t] = src[t];
        ((uint4*)st_lds)[t + 256] = src[t + 256];
    }
    __syncthreads();
    const float* qw = qkvp + (size_t)h * DD * 384;
    for (int i = 0; i < 48; i++) {
        int j = t + i * 256;
        int m = j / 384, e = j - m * 384;
        float s = 0.f;
        for (int d = 0; d < DD; d++) s += bf2f(st_lds[m * DD + d]) * qw[d * 384 + e];
        qt[m * 384 + e] = s;
    }
    __syncthreads();
    const float scale = 0.08838834764831845f;
#pragma unroll
    for (int i = 0; i < 4; i++) {
        int idx = t * 4 + i;
        int qi = idx >> 5, kj = idx & 31;
        float s = 0.f;
        for (int d = 0; d < DD; d++) s += qt[qi * 384 + d] * qt[kj * 384 + 128 + d];
        dots[idx] = s * scale;
    }
    __syncthreads();
    if (t < MM) {
        float mx = -1e30f;
        float ex[MM];
#pragma unroll
        for (int j = 0; j < MM; j++) mx = fmaxf(mx, dots[t * MM + j]);
        float sm = 0.f;
#pragma unroll
        for (int j = 0; j < MM; j++) { ex[j] = __expf(dots[t * MM + j] - mx); sm += ex[j]; }
        float inv = 1.f / sm;
#pragma unroll
        for (int j = 0; j < MM; j++) {
            float v = ex[j] * inv;
            dots[t * MM + j] = v;
            attn_out[((size_t)bh * MM + t) * MM + j] = v;
        }
    }
    __syncthreads();
#pragma unroll
    for (int i = 0; i < 16; i++) {
        int e = t + i * 256;
        int m = e >> 7, d = e & 127;
        float s = 0.f;
#pragma unroll
        for (int j = 0; j < MM; j++) s += dots[m * MM + j] * qt[j * 384 + 256 + d];
        otw[(size_t)bh * 4096 + e] = s;
    }
}

// ---------------------------------------------------------------- scatter y[n, h*128+d] = sum_m ot[m,d]*w[m,n]
__global__ void scatter_kernel(const float* __restrict__ otw, const float* __restrict__ sw,
                               u16* __restrict__ y) {
    __shared__ float ot_lds[MM * 132];  // phys: m*132 + (d>>5)*33 + (d&31)
    __shared__ float w_lds[MM * 64];
    const int bh = blockIdx.y, b = bh >> 3, h = bh & 7, t = threadIdx.x;
    const int n0 = blockIdx.x * 64;

    for (int i = t; i < MM * DD; i += 256) {
        int m = i >> 7, d = i & 127;
        ot_lds[m * 132 + (d >> 5) * 33 + (d & 31)] = otw[(size_t)bh * 4096 + i];
    }
    for (int i = t; i < MM * 64; i += 256) {
        int m = i >> 6, nl = i & 63;
        w_lds[i] = sw[((size_t)bh * MM + m) * NN + n0 + nl];
    }
    __syncthreads();

    const int nl = t >> 2, dq = t & 3;
    float acc[32];
#pragma unroll
    for (int j = 0; j < 32; j++) acc[j] = 0.f;
    for (int m = 0; m < MM; m++) {
        float wv = w_lds[m * 64 + nl];
        const float* otr = &ot_lds[m * 132 + dq * 33];
#pragma unroll
        for (int j = 0; j < 32; j++) acc[j] += wv * otr[j];
    }
    u16* dstp = y + (size_t)(b * NN + n0 + nl) * HDIM + h * DD + dq * 32;
#pragma unroll
    for (int j = 0; j < 16; j++) {
        u32 pk = (u32)f2bf(acc[2 * j]) | ((u32)f2bf(acc[2 * j + 1]) << 16);
        ((u32*)dstp)[j] = pk;
    }
}

// ---------------------------------------------------------------- launch
extern "C" void kernel_launch(void* const* d_in, const int* in_sizes, int n_in,
                              void* d_out, int out_size, void* d_ws, size_t ws_size,
                              hipStream_t stream) {
    const float* x        = (const float*)d_in[0];
    const float* wkv      = (const float*)d_in[1];
    const float* bkv      = (const float*)d_in[2];
    const float* wtq      = (const float*)d_in[3];
    const float* wtq_bias = (const float*)d_in[4];
    const float* qkvp     = (const float*)d_in[5];
    const float* outw     = (const float*)d_in[6];
    const float* outb     = (const float*)d_in[7];

    float* out  = (float*)d_out;
    float* out0 = out;                      // [B,N,HD]           67108864
    float* out1 = out + 67108864;           // slice_weights      16777216
    float* out2 = out + 83886080;           // temperature + bias
    float* out4 = out + 83886337;           // attn_weights       32768

    char* ws = (char*)d_ws;
    u16*   xb    = (u16*)(ws);                          // 134217728 B (reused as y after GEMM1)
    u16*   kvb   = (u16*)(ws + 134217728);              // 268435456 B
    u16*   st_red= (u16*)(ws + 134217728);              // aliases kvb (kv dead after slice_pass)
    u16*   wkvb  = (u16*)(ws + 402653184);              // 4194304 B
    u16*   outwb = (u16*)(ws + 406847488);              // 2097152 B
    float* pst   = (float*)(ws + 408944640);            // 33554432 B
    float* pnorm = (float*)(ws + 442499072);            // 262144 B
    float* otws  = (float*)(ws + 442761216);            // 524288 B

    convert_kernel<<<dim3(2048), dim3(256), 0, stream>>>(x, wkv, outw, xb, wkvb, outwb, wtq_bias, out2);
    gemm256_8p<0><<<dim3(256 * 8), dim3(512), 0, stream>>>(xb, wkvb, bkv, (void*)kvb, K2HD, HDIM, 8);
    slice_pass<<<dim3(64, 32), dim3(256), 0, stream>>>(kvb, wtq, out1, pst, pnorm);
    reduce_pst<<<dim3(8, 32), dim3(256), 0, stream>>>(pst, pnorm, st_red);
    finalize_kernel<<<dim3(32), dim3(256), 0, stream>>>(st_red, qkvp, out4, otws);
    scatter_kernel<<<dim3(256, 32), dim3(256), 0, stream>>>(otws, out1, xb);
    gemm256_8p<1><<<dim3(256 * 4), dim3(512), 0, stream>>>(xb, outwb, outb, (void*)out0, HDIM, HDIM, 4);
}

// Round 8
// 874.787 us; speedup vs baseline: 1.3026x; 1.2197x over previous
//
#include <hip/hip_runtime.h>
#include <hip/hip_bf16.h>
#include <stdint.h>

#define BB 4
#define NN 16384
#define HDIM 1024
#define HH 8
#define MM 32
#define DD 128
#define K2HD 2048

typedef unsigned int u32;
typedef unsigned short u16;
typedef __attribute__((ext_vector_type(8))) short short8;
typedef __attribute__((ext_vector_type(4))) float f32x4;

__device__ __forceinline__ float bflo(u32 v) {
    union { u32 u; float f; } c; c.u = v << 16; return c.f;
}
__device__ __forceinline__ float bfhi(u32 v) {
    union { u32 u; float f; } c; c.u = v & 0xffff0000u; return c.f;
}
__device__ __forceinline__ float bf2f(u16 v) {
    union { u32 u; float f; } c; c.u = ((u32)v) << 16; return c.f;
}
__device__ __forceinline__ u16 f2bf(float f) {
    union { float f; u32 u; } c; c.f = f;
    u32 r = c.u + 0x7fffu + ((c.u >> 16) & 1u);
    return (u16)(r >> 16);
}

__device__ __forceinline__ void gload16(const u16* g, u16* l) {
    __builtin_amdgcn_global_load_lds(
        (const __attribute__((address_space(1))) void*)g,
        (__attribute__((address_space(3))) void*)l, 16, 0, 0);
}

#define MFMA16(a, b, c) __builtin_amdgcn_mfma_f32_16x16x32_bf16(a, b, c, 0, 0, 0)

// ---------------------------------------------------------------- convert
__global__ void convert_kernel(const float* __restrict__ x, const float* __restrict__ wkv,
                               u16* __restrict__ xb, u16* __restrict__ wkvb,
                               const float* __restrict__ wtq_bias, float* __restrict__ out_misc) {
    size_t i = (size_t)blockIdx.x * blockDim.x + threadIdx.x;
    size_t stride = (size_t)gridDim.x * blockDim.x;
    const size_t nx = (size_t)BB * NN * HDIM / 4;     // float4 groups
    const size_t nw = (size_t)K2HD * HDIM / 4;
    for (size_t j = i; j < nx; j += stride) {
        float4 v = ((const float4*)x)[j];
        ushort4 o; o.x = f2bf(v.x); o.y = f2bf(v.y); o.z = f2bf(v.z); o.w = f2bf(v.w);
        ((ushort4*)xb)[j] = o;
    }
    for (size_t j = i; j < nw; j += stride) {
        float4 v = ((const float4*)wkv)[j];
        ushort4 o; o.x = f2bf(v.x); o.y = f2bf(v.y); o.z = f2bf(v.z); o.w = f2bf(v.w);
        ((ushort4*)wkvb)[j] = o;
    }
    if (blockIdx.x == 0) {
        if (threadIdx.x == 0) out_misc[0] = 1.0f;               // temperature
        if (threadIdx.x < HH * MM) out_misc[1 + threadIdx.x] = wtq_bias[threadIdx.x];  // bias output
    }
}

// ---------------------------------------------------------------- GEMM C = A @ B^T (+bias)
// m201-style 8-phase: 256x256 tile, BK=64, 512 threads (8 waves 2Mx4N).
// B-operand may be per-b (bshift selects b = tm >> bshift, base += b * bstrideB
// in ELEMENTS).
template<int OUT_F32>
__global__ __launch_bounds__(512, 1) void gemm256_8p(
        const u16* __restrict__ A, const u16* __restrict__ Bm,
        const float* __restrict__ bias, void* __restrict__ Cout,
        int Ncols, int Kd, int ntn, int bshift, long long bstrideB) {
    __shared__ u16 ldsA[2][2][8192];   // [dbuf][half][128 rows x 64 k]
    __shared__ u16 ldsB[2][2][8192];
    const int t = threadIdx.x, l = t & 63, w = t >> 6;
    const int wr = w >> 2, wc = w & 3;

    const int nwg = gridDim.x, cpx = nwg >> 3, bid = blockIdx.x;
    const int swz = (bid & 7) * cpx + (bid >> 3);
    const int tm = swz / ntn, tn = swz % ntn;
    const u16* Bb = Bm + (size_t)(tm >> bshift) * bstrideB;

    f32x4 acc[8][4];
    const f32x4 zero = {0.f, 0.f, 0.f, 0.f};
#pragma unroll
    for (int mi = 0; mi < 8; mi++)
#pragma unroll
        for (int ni = 0; ni < 4; ni++) acc[mi][ni] = zero;

    const int srow = w * 8 + (l >> 3);
    const int skel = ((l & 7) ^ ((l >> 3) & 7)) * 8;
    const u16* gA = A  + (size_t)(tm * 256 + srow) * Kd + skel;
    const u16* gB = Bb + (size_t)(tn * 256 + srow) * Kd + skel;
    const int ldo = w * 512 + l * 8;

#define STAGE_A(T, H) { const u16* g_ = gA + (size_t)((H) * 128) * Kd + (T) * 64; \
    u16* d_ = &ldsA[(T) & 1][H][ldo]; gload16(g_, d_); gload16(g_ + (size_t)64 * Kd, d_ + 4096); }
#define STAGE_B(T, H) { const u16* g_ = gB + (size_t)((H) * 128) * Kd + (T) * 64; \
    u16* d_ = &ldsB[(T) & 1][H][ldo]; gload16(g_, d_); gload16(g_ + (size_t)64 * Kd, d_ + 4096); }

    const int m16 = l & 15;
    const int ck0 = (((l >> 4) + 0) ^ (l & 7)) << 3;
    const int ck1 = (((l >> 4) + 4) ^ (l & 7)) << 3;
    const int brb = (wc & 1) * 64;

    const int nT = Kd >> 6;

    STAGE_A(0, 0); STAGE_A(0, 1); STAGE_B(0, 0); STAGE_B(0, 1);
    STAGE_B(1, 0); STAGE_B(1, 1);
    asm volatile("s_waitcnt vmcnt(4)" ::: "memory");
    __builtin_amdgcn_s_barrier();

    for (int kt = 0; kt < nT; ++kt) {
        const int sl = kt & 1;
        const u16* lA = ldsA[sl][wr];
        const u16* lB = ldsB[sl][wc >> 1];
        short8 aF[4][2], bF[4][2];

        // ---- q0: A fr0-3 + B fc0-1 reads; stage A0(kt+1); acc[0-3][0-1]
#pragma unroll
        for (int fr = 0; fr < 4; fr++) {
            aF[fr][0] = *(const short8*)&lA[(fr * 16 + m16) * 64 + ck0];
            aF[fr][1] = *(const short8*)&lA[(fr * 16 + m16) * 64 + ck1];
        }
#pragma unroll
        for (int fc = 0; fc < 2; fc++) {
            bF[fc][0] = *(const short8*)&lB[(brb + fc * 16 + m16) * 64 + ck0];
            bF[fc][1] = *(const short8*)&lB[(brb + fc * 16 + m16) * 64 + ck1];
        }
        if (kt + 1 < nT) STAGE_A(kt + 1, 0);
        __builtin_amdgcn_s_barrier();
        asm volatile("s_waitcnt lgkmcnt(0)" ::: "memory");
        __builtin_amdgcn_s_setprio(1);
#pragma unroll
        for (int kk = 0; kk < 2; kk++)
#pragma unroll
            for (int mi = 0; mi < 4; mi++) {
                acc[mi][0] = MFMA16(aF[mi][kk], bF[0][kk], acc[mi][0]);
                acc[mi][1] = MFMA16(aF[mi][kk], bF[1][kk], acc[mi][1]);
            }
        __builtin_amdgcn_s_setprio(0);
        __builtin_amdgcn_s_barrier();

        // ---- q1: B fc2-3 reads; stage A1(kt+1); acc[0-3][2-3]
#pragma unroll
        for (int fc = 2; fc < 4; fc++) {
            bF[fc][0] = *(const short8*)&lB[(brb + fc * 16 + m16) * 64 + ck0];
            bF[fc][1] = *(const short8*)&lB[(brb + fc * 16 + m16) * 64 + ck1];
        }
        if (kt + 1 < nT) STAGE_A(kt + 1, 1);
        __builtin_amdgcn_s_barrier();
        asm volatile("s_waitcnt lgkmcnt(0)" ::: "memory");
        __builtin_amdgcn_s_setprio(1);
#pragma unroll
        for (int kk = 0; kk < 2; kk++)
#pragma unroll
            for (int mi = 0; mi < 4; mi++) {
                acc[mi][2] = MFMA16(aF[mi][kk], bF[2][kk], acc[mi][2]);
                acc[mi][3] = MFMA16(aF[mi][kk], bF[3][kk], acc[mi][3]);
            }
        __builtin_amdgcn_s_setprio(0);
        __builtin_amdgcn_s_barrier();

        // ---- q2: A fr4-7 reads; stage B0(kt+2); acc[4-7][0-1]
#pragma unroll
        for (int fr = 0; fr < 4; fr++) {
            aF[fr][0] = *(const short8*)&lA[((fr + 4) * 16 + m16) * 64 + ck0];
            aF[fr][1] = *(const short8*)&lA[((fr + 4) * 16 + m16) * 64 + ck1];
        }
        if (kt + 2 < nT) STAGE_B(kt + 2, 0);
        __builtin_amdgcn_s_barrier();
        asm volatile("s_waitcnt lgkmcnt(0)" ::: "memory");
        __builtin_amdgcn_s_setprio(1);
#pragma unroll
        for (int kk = 0; kk < 2; kk++)
#pragma unroll
            for (int mi = 0; mi < 4; mi++) {
                acc[4 + mi][0] = MFMA16(aF[mi][kk], bF[0][kk], acc[4 + mi][0]);
                acc[4 + mi][1] = MFMA16(aF[mi][kk], bF[1][kk], acc[4 + mi][1]);
            }
        __builtin_amdgcn_s_setprio(0);
        __builtin_amdgcn_s_barrier();

        // ---- q3: no reads; stage B1(kt+2); acc[4-7][2-3]; counted vmcnt + barrier
        if (kt + 2 < nT) STAGE_B(kt + 2, 1);
        __builtin_amdgcn_s_barrier();
        __builtin_amdgcn_s_setprio(1);
#pragma unroll
        for (int kk = 0; kk < 2; kk++)
#pragma unroll
            for (int mi = 0; mi < 4; mi++) {
                acc[4 + mi][2] = MFMA16(aF[mi][kk], bF[2][kk], acc[4 + mi][2]);
                acc[4 + mi][3] = MFMA16(aF[mi][kk], bF[3][kk], acc[4 + mi][3]);
            }
        __builtin_amdgcn_s_setprio(0);
        if (kt < nT - 1) {
            if (kt + 2 < nT) asm volatile("s_waitcnt vmcnt(4)" ::: "memory");
            else             asm volatile("s_waitcnt vmcnt(0)" ::: "memory");
            __builtin_amdgcn_s_barrier();
        }
    }
#undef STAGE_A
#undef STAGE_B

    const int cr = (l >> 4) * 4;
    const int cc = l & 15;
#pragma unroll
    for (int ni = 0; ni < 4; ni++) {
        const int col = tn * 256 + wc * 64 + ni * 16 + cc;
        const float bv = bias[col];
#pragma unroll
        for (int mi = 0; mi < 8; mi++) {
            const int row0 = tm * 256 + wr * 128 + mi * 16 + cr;
#pragma unroll
            for (int q = 0; q < 4; q++) {
                float v = acc[mi][ni][q] + bv;
                if (OUT_F32) ((float*)Cout)[(size_t)(row0 + q) * Ncols + col] = v;
                else         ((u16*)Cout)[(size_t)(row0 + q) * Ncols + col] = f2bf(v);
            }
        }
    }
}

// ---------------------------------------------------------------- fused slice pass v3
// Phase 1: S' = wtq @ xk^T via MFMA; softmax over m into f32 w_lds.
// Then: coalesced slice_weights (f32) + transposed wT (bf16) writes.
// Phase 2: scalar P@V partial accumulation, xv staged via global_load_lds.
__global__ __launch_bounds__(256) void slice_pass(
        const u16* __restrict__ kv, const float* __restrict__ wtq,
        float* __restrict__ sw_out, u16* __restrict__ wT,
        float* __restrict__ pst, float* __restrict__ pnorm) {
    __shared__ u16 xk_lds[128 * 128];   // 32 KB: xk half-tile (swizzled), reused for xv (linear)
    __shared__ u16 wtq_lds[MM * DD];    // 8 KB, swizzled chunks
    __shared__ float w_lds[MM * 258];   // 33 KB f32 (pitch 258: conflict-free column reads)
    const int t = threadIdx.x, l = t & 63, w = t >> 6;
    const int bh = blockIdx.y, b = bh >> 3, h = bh & 7;
    const int n0 = blockIdx.x * 256;

    // stage wtq (f32 -> bf16), chunk-swizzled: phys_chunk = (d>>3) ^ (m&7)
    for (int i = t; i < MM * DD; i += 256) {
        int m = i >> 7, d = i & 127;
        int idx = m * 128 + (((d >> 3) ^ (m & 7)) << 3) + (d & 7);
        wtq_lds[idx] = f2bf(wtq[(size_t)h * MM * DD + i]);
    }

    // staging constants: round j covers rows j*16 + (t>>4), 16B slot (t&15)
    const int srow = t >> 4;
    const int sswz = (t & 15) ^ (srow & 7);     // pre-swizzled source chunk for xk
    const int mrow = l & 15;
    const int kg = l >> 4;                       // 0..3

    // ---------------- phase 1: per half, MFMA scores + softmax over m
    for (int half = 0; half < 2; half++) {
        __syncthreads();    // wtq staged (h=0) / previous half's frag reads done (h=1)
        {
            const u16* src = kv + ((size_t)(b * NN) + n0 + half * 128 + srow) * K2HD + h * DD + sswz * 8;
            for (int j = 0; j < 8; j++)
                gload16(src + (size_t)j * 16 * K2HD, xk_lds + j * 2048 + w * 512);
        }
        __syncthreads();    // xk half staged

        f32x4 s[2][2];
        const f32x4 zero = {0.f, 0.f, 0.f, 0.f};
        s[0][0] = zero; s[0][1] = zero; s[1][0] = zero; s[1][1] = zero;
#pragma unroll
        for (int ks = 0; ks < 4; ks++) {
            const int pc = (((ks << 2) + kg) ^ (l & 7)) << 3;
            short8 a0 = *(const short8*)&wtq_lds[mrow * 128 + pc];
            short8 a1 = *(const short8*)&wtq_lds[(16 + mrow) * 128 + pc];
            short8 bb0 = *(const short8*)&xk_lds[(w * 32 + mrow) * 128 + pc];
            short8 bb1 = *(const short8*)&xk_lds[(w * 32 + 16 + mrow) * 128 + pc];
            s[0][0] = MFMA16(a0, bb0, s[0][0]);
            s[0][1] = MFMA16(a0, bb1, s[0][1]);
            s[1][0] = MFMA16(a1, bb0, s[1][0]);
            s[1][1] = MFMA16(a1, bb1, s[1][1]);
        }

        // softmax over m (32 values live in 4-lane group {l, l^16, l^32, l^48})
#pragma unroll
        for (int nj = 0; nj < 2; nj++) {
            float mx = s[0][nj][0];
#pragma unroll
            for (int mi = 0; mi < 2; mi++)
#pragma unroll
                for (int q = 0; q < 4; q++) mx = fmaxf(mx, s[mi][nj][q]);
            mx = fmaxf(mx, __shfl_xor(mx, 16));
            mx = fmaxf(mx, __shfl_xor(mx, 32));
            float ex[2][4], sum = 0.f;
#pragma unroll
            for (int mi = 0; mi < 2; mi++)
#pragma unroll
                for (int q = 0; q < 4; q++) { ex[mi][q] = __expf(s[mi][nj][q] - mx); sum += ex[mi][q]; }
            sum += __shfl_xor(sum, 16);
            sum += __shfl_xor(sum, 32);
            const float inv = 1.f / sum;
            const int ncol = half * 128 + w * 32 + nj * 16 + mrow;
#pragma unroll
            for (int mi = 0; mi < 2; mi++)
#pragma unroll
                for (int q = 0; q < 4; q++) {
                    const int m = mi * 16 + kg * 4 + q;
                    w_lds[m * 258 + ncol] = ex[mi][q] * inv;
                }
        }
    }
    __syncthreads();    // w_lds complete for both halves

    // ---------------- coalesced weight outputs from w_lds
    // slice_weights (f32): per m, 64 lanes x 4B consecutive
#pragma unroll 4
    for (int m = 0; m < MM; m++)
        sw_out[((size_t)bh * MM + m) * NN + n0 + t] = w_lds[m * 258 + t];
    // wT[b*NN + n][h*32 + m] bf16: per thread a 16B chunk (8 m) -> 64B-granule rows
    for (int i = t; i < 1024; i += 256) {
        const int row = i >> 2, seg = i & 3;
        u32 pk[4];
#pragma unroll
        for (int p = 0; p < 4; p++) {
            float v0 = w_lds[(seg * 8 + 2 * p) * 258 + row];
            float v1 = w_lds[(seg * 8 + 2 * p + 1) * 258 + row];
            pk[p] = (u32)f2bf(v0) | ((u32)f2bf(v1) << 16);
        }
        uint4 q4; q4.x = pk[0]; q4.y = pk[1]; q4.z = pk[2]; q4.w = pk[3];
        *(uint4*)&wT[((size_t)(b * NN) + n0 + row) * 256 + h * 32 + seg * 8] = q4;
    }

    // ---------------- phase 2: partial slice_token. thread -> (m = t>>3, d-range (t&7)*16)
    const int am = t >> 3;
    const int ad = (t & 7) * 16;
    float2 accv[8];
#pragma unroll
    for (int j = 0; j < 8; j++) accv[j] = make_float2(0.f, 0.f);
    float wsum = 0.f;

    for (int half = 0; half < 2; half++) {
        __syncthreads();    // phase-1 xk reads done (h=0) / xv reads done (h=1)
        {
            const u16* src = kv + ((size_t)(b * NN) + n0 + half * 128 + srow) * K2HD + HDIM + h * DD + (t & 15) * 8;
            for (int j = 0; j < 8; j++)
                gload16(src + (size_t)j * 16 * K2HD, xk_lds + j * 2048 + w * 512);
        }
        __syncthreads();
        for (int n = 0; n < 128; n++) {
            float wv = w_lds[am * 258 + half * 128 + n];
            wsum += wv;
            const u32* xvr = (const u32*)&xk_lds[n * 128 + ad];
#pragma unroll
            for (int j = 0; j < 8; j++) {
                u32 xd = xvr[j];
                accv[j].x += wv * bflo(xd);
                accv[j].y += wv * bfhi(xd);
            }
        }
    }

    float* dst = &pst[(((size_t)bh * 64 + blockIdx.x) * MM + am) * DD + ad];
#pragma unroll
    for (int j = 0; j < 8; j += 2) {
        float4 v = make_float4(accv[j].x, accv[j].y, accv[j + 1].x, accv[j + 1].y);
        *(float4*)&dst[j * 2] = v;
    }
    if ((t & 7) == 0) pnorm[((size_t)bh * 64 + blockIdx.x) * MM + am] = wsum;
}

// ---------------------------------------------------------------- reduce pst partials (parallel)
__global__ __launch_bounds__(256) void reduce_pst(const float* __restrict__ pst,
                                                  const float* __restrict__ pnorm,
                                                  u16* __restrict__ st_red) {
    __shared__ float norm_lds[MM];
    const int bh = blockIdx.y, es = blockIdx.x, t = threadIdx.x;
    if (t < MM) {
        float s = 0.f;
        for (int g = 0; g < 64; g++) s += pnorm[((size_t)bh * 64 + g) * MM + t];
        norm_lds[t] = s + 1e-5f;
    }
    __syncthreads();
    const int e = es * 512 + t * 2;
    float ax = 0.f, ay = 0.f;
    for (int g = 0; g < 64; g++) {
        const float2 v = *(const float2*)&pst[((size_t)bh * 64 + g) * 4096 + e];
        ax += v.x; ay += v.y;
    }
    const float nv = norm_lds[e >> 7];
    u32 pk = (u32)f2bf(ax / nv) | ((u32)f2bf(ay / nv) << 16);
    ((u32*)st_red)[((size_t)bh * 4096 + e) >> 1] = pk;
}

// ---------------------------------------------------------------- finalize (per b,h)
__global__ void finalize_kernel(const u16* __restrict__ st_red,
                                const float* __restrict__ qkvp, float* __restrict__ attn_out,
                                float* __restrict__ otw) {
    __shared__ float qt[MM * 384];      // 48 KB
    __shared__ u16 st_lds[MM * DD];     // 8 KB
    __shared__ float dots[MM * MM];     // 4 KB
    const int bh = blockIdx.x, h = bh & 7, t = threadIdx.x;

    {
        const uint4* src = (const uint4*)(st_red + (size_t)bh * 4096);
        ((uint4*)st_lds)[t] = src[t];
        ((uint4*)st_lds)[t + 256] = src[t + 256];
    }
    __syncthreads();
    const float* qw = qkvp + (size_t)h * DD * 384;
    for (int i = 0; i < 48; i++) {
        int j = t + i * 256;
        int m = j / 384, e = j - m * 384;
        float s = 0.f;
        for (int d = 0; d < DD; d++) s += bf2f(st_lds[m * DD + d]) * qw[d * 384 + e];
        qt[m * 384 + e] = s;
    }
    __syncthreads();
    const float scale = 0.08838834764831845f;
#pragma unroll
    for (int i = 0; i < 4; i++) {
        int idx = t * 4 + i;
        int qi = idx >> 5, kj = idx & 31;
        float s = 0.f;
        for (int d = 0; d < DD; d++) s += qt[qi * 384 + d] * qt[kj * 384 + 128 + d];
        dots[idx] = s * scale;
    }
    __syncthreads();
    if (t < MM) {
        float mx = -1e30f;
        float ex[MM];
#pragma unroll
        for (int j = 0; j < MM; j++) mx = fmaxf(mx, dots[t * MM + j]);
        float sm = 0.f;
#pragma unroll
        for (int j = 0; j < MM; j++) { ex[j] = __expf(dots[t * MM + j] - mx); sm += ex[j]; }
        float inv = 1.f / sm;
#pragma unroll
        for (int j = 0; j < MM; j++) {
            float v = ex[j] * inv;
            dots[t * MM + j] = v;
            attn_out[((size_t)bh * MM + t) * MM + j] = v;
        }
    }
    __syncthreads();
#pragma unroll
    for (int i = 0; i < 16; i++) {
        int e = t + i * 256;
        int m = e >> 7, d = e & 127;
        float s = 0.f;
#pragma unroll
        for (int j = 0; j < MM; j++) s += dots[m * MM + j] * qt[j * 384 + 256 + d];
        otw[(size_t)bh * 4096 + e] = s;
    }
}

// ---------------------------------------------------------------- zmat: Zt[b][e][h*32+m] = sum_d ot[bh][m][d] * outw[e][h*128+d]
__global__ __launch_bounds__(256) void zmat_kernel(const float* __restrict__ otw,
                                                   const float* __restrict__ outw,
                                                   u16* __restrict__ Zt) {
    __shared__ float ot_lds[MM * DD];   // 16 KB
    const int bh = blockIdx.y, b = bh >> 3, h = bh & 7;
    const int es = blockIdx.x;          // 0..7 -> 128 e each
    const int t = threadIdx.x;
    for (int i = t; i < MM * DD; i += 256) ot_lds[i] = otw[(size_t)bh * 4096 + i];
    __syncthreads();
    const int e = es * 128 + (t >> 1);
    const int m0 = (t & 1) * 16;
    const float* ow = outw + (size_t)e * HDIM + h * DD;
    float acc[16];
#pragma unroll
    for (int m = 0; m < 16; m++) acc[m] = 0.f;
    for (int d = 0; d < DD; d += 4) {
        float4 o4 = *(const float4*)&ow[d];
#pragma unroll
        for (int m = 0; m < 16; m++) {
            const float* otr = &ot_lds[(m0 + m) * DD + d];
            acc[m] += o4.x * otr[0] + o4.y * otr[1] + o4.z * otr[2] + o4.w * otr[3];
        }
    }
    u32 pk[8];
#pragma unroll
    for (int p = 0; p < 8; p++)
        pk[p] = (u32)f2bf(acc[2 * p]) | ((u32)f2bf(acc[2 * p + 1]) << 16);
    u16* dst = Zt + ((size_t)b * 1024 + e) * 256 + h * 32 + m0;
#pragma unroll
    for (int p = 0; p < 2; p++) {
        uint4 q4; q4.x = pk[4 * p]; q4.y = pk[4 * p + 1]; q4.z = pk[4 * p + 2]; q4.w = pk[4 * p + 3];
        *(uint4*)&dst[p * 8] = q4;
    }
}

// ---------------------------------------------------------------- launch
extern "C" void kernel_launch(void* const* d_in, const int* in_sizes, int n_in,
                              void* d_out, int out_size, void* d_ws, size_t ws_size,
                              hipStream_t stream) {
    const float* x        = (const float*)d_in[0];
    const float* wkv      = (const float*)d_in[1];
    const float* bkv      = (const float*)d_in[2];
    const float* wtq      = (const float*)d_in[3];
    const float* wtq_bias = (const float*)d_in[4];
    const float* qkvp     = (const float*)d_in[5];
    const float* outw     = (const float*)d_in[6];
    const float* outb     = (const float*)d_in[7];

    float* out  = (float*)d_out;
    float* out0 = out;                      // [B,N,HD]           67108864
    float* out1 = out + 67108864;           // slice_weights      16777216
    float* out2 = out + 83886080;           // temperature + bias
    float* out4 = out + 83886337;           // attn_weights       32768

    char* ws = (char*)d_ws;
    u16*   xb    = (u16*)(ws);                          // 134 MB: x bf16; reused as wT (33.5 MB) after GEMM1
    u16*   wT    = xb;
    u16*   kvb   = (u16*)(ws + 134217728);              // 268 MB
    u16*   st_red= (u16*)(ws + 134217728);              // aliases kvb (kv dead after slice_pass)
    u16*   Zt    = (u16*)(ws + 142606336);              // kvb + 8 MB (2 MB, after st_red's 256 KB)
    u16*   wkvb  = (u16*)(ws + 402653184);              // 4 MB
    float* pst   = (float*)(ws + 408944640);            // 33.5 MB
    float* pnorm = (float*)(ws + 442499072);            // 256 KB
    float* otws  = (float*)(ws + 442761216);            // 512 KB

    convert_kernel<<<dim3(2048), dim3(256), 0, stream>>>(x, wkv, xb, wkvb, wtq_bias, out2);
    gemm256_8p<0><<<dim3(256 * 8), dim3(512), 0, stream>>>(xb, wkvb, bkv, (void*)kvb, K2HD, HDIM, 8, 30, 0);
    slice_pass<<<dim3(64, 32), dim3(256), 0, stream>>>(kvb, wtq, out1, wT, pst, pnorm);
    reduce_pst<<<dim3(8, 32), dim3(256), 0, stream>>>(pst, pnorm, st_red);
    finalize_kernel<<<dim3(32), dim3(256), 0, stream>>>(st_red, qkvp, out4, otws);
    zmat_kernel<<<dim3(8, 32), dim3(256), 0, stream>>>(otws, outw, Zt);
    // out0[b*N+n, e] = sum_{hm} wT[b*N+n, hm] * Zt[b][e][hm] + outb[e]
    gemm256_8p<1><<<dim3(256 * 4), dim3(512), 0, stream>>>(wT, Zt, outb, (void*)out0, HDIM, 256, 4, 6, (long long)1024 * 256);
}

// Round 9
// 812.261 us; speedup vs baseline: 1.4029x; 1.0770x over previous
//
#include <hip/hip_runtime.h>
#include <hip/hip_bf16.h>
#include <stdint.h>

#define BB 4
#define NN 16384
#define HDIM 1024
#define HH 8
#define MM 32
#define DD 128

typedef unsigned int u32;
typedef unsigned short u16;
typedef __attribute__((ext_vector_type(8))) short short8;
typedef __attribute__((ext_vector_type(4))) float f32x4;

__device__ __forceinline__ float bflo(u32 v) {
    union { u32 u; float f; } c; c.u = v << 16; return c.f;
}
__device__ __forceinline__ float bfhi(u32 v) {
    union { u32 u; float f; } c; c.u = v & 0xffff0000u; return c.f;
}
__device__ __forceinline__ float bf2f(u16 v) {
    union { u32 u; float f; } c; c.u = ((u32)v) << 16; return c.f;
}
__device__ __forceinline__ u16 f2bf(float f) {
    union { float f; u32 u; } c; c.f = f;
    u32 r = c.u + 0x7fffu + ((c.u >> 16) & 1u);
    return (u16)(r >> 16);
}

__device__ __forceinline__ void gload16(const u16* g, u16* l) {
    __builtin_amdgcn_global_load_lds(
        (const __attribute__((address_space(1))) void*)g,
        (__attribute__((address_space(3))) void*)l, 16, 0, 0);
}

#define MFMA16(a, b, c) __builtin_amdgcn_mfma_f32_16x16x32_bf16(a, b, c, 0, 0, 0)

// ---------------------------------------------------------------- convert
__global__ void convert_kernel(const float* __restrict__ x, const float* __restrict__ wkv,
                               u16* __restrict__ xb, u16* __restrict__ wkvb,
                               const float* __restrict__ wtq_bias, float* __restrict__ out_misc) {
    size_t i = (size_t)blockIdx.x * blockDim.x + threadIdx.x;
    size_t stride = (size_t)gridDim.x * blockDim.x;
    const size_t nx = (size_t)BB * NN * HDIM / 4;
    const size_t nw = (size_t)2048 * HDIM / 4;
    for (size_t j = i; j < nx; j += stride) {
        float4 v = ((const float4*)x)[j];
        ushort4 o; o.x = f2bf(v.x); o.y = f2bf(v.y); o.z = f2bf(v.z); o.w = f2bf(v.w);
        ((ushort4*)xb)[j] = o;
    }
    for (size_t j = i; j < nw; j += stride) {
        float4 v = ((const float4*)wkv)[j];
        ushort4 o; o.x = f2bf(v.x); o.y = f2bf(v.y); o.z = f2bf(v.z); o.w = f2bf(v.w);
        ((ushort4*)wkvb)[j] = o;
    }
    if (blockIdx.x == 0) {
        if (threadIdx.x == 0) out_misc[0] = 1.0f;
        if (threadIdx.x < HH * MM) out_misc[1 + threadIdx.x] = wtq_bias[threadIdx.x];
    }
}

// ---------------------------------------------------------------- GEMM1: kv = x @ Wkv^T (+bias)
// 8-phase 256x256/BK=64 body. Epilogue: K-half (tn<4) -> kvk[65536][1024] bf16;
// V-half (tn>=4) -> TRANSPOSED vT[(b*8+h)*128+d][16384 n] bf16 via per-lane 8B packs.
__global__ __launch_bounds__(512, 1) void gemm_kv(
        const u16* __restrict__ A, const u16* __restrict__ Bm,
        const float* __restrict__ bias, u16* __restrict__ Ck, u16* __restrict__ CvT) {
    __shared__ u16 ldsA[2][2][8192];
    __shared__ u16 ldsB[2][2][8192];
    const int Kd = 1024, ntn = 8;
    const int t = threadIdx.x, l = t & 63, w = t >> 6;
    const int wr = w >> 2, wc = w & 3;

    const int nwg = gridDim.x, cpx = nwg >> 3, bid = blockIdx.x;
    const int swz = (bid & 7) * cpx + (bid >> 3);
    const int tm = swz / ntn, tn = swz % ntn;

    f32x4 acc[8][4];
    const f32x4 zero = {0.f, 0.f, 0.f, 0.f};
#pragma unroll
    for (int mi = 0; mi < 8; mi++)
#pragma unroll
        for (int ni = 0; ni < 4; ni++) acc[mi][ni] = zero;

    const int srow = w * 8 + (l >> 3);
    const int skel = ((l & 7) ^ ((l >> 3) & 7)) * 8;
    const u16* gA = A  + (size_t)(tm * 256 + srow) * Kd + skel;
    const u16* gB = Bm + (size_t)(tn * 256 + srow) * Kd + skel;
    const int ldo = w * 512 + l * 8;

#define STAGE_A(T, H) { const u16* g_ = gA + (size_t)((H) * 128) * Kd + (T) * 64; \
    u16* d_ = &ldsA[(T) & 1][H][ldo]; gload16(g_, d_); gload16(g_ + (size_t)64 * Kd, d_ + 4096); }
#define STAGE_B(T, H) { const u16* g_ = gB + (size_t)((H) * 128) * Kd + (T) * 64; \
    u16* d_ = &ldsB[(T) & 1][H][ldo]; gload16(g_, d_); gload16(g_ + (size_t)64 * Kd, d_ + 4096); }

    const int m16 = l & 15;
    const int ck0 = (((l >> 4) + 0) ^ (l & 7)) << 3;
    const int ck1 = (((l >> 4) + 4) ^ (l & 7)) << 3;
    const int brb = (wc & 1) * 64;
    const int nT = Kd >> 6;

    STAGE_A(0, 0); STAGE_A(0, 1); STAGE_B(0, 0); STAGE_B(0, 1);
    STAGE_B(1, 0); STAGE_B(1, 1);
    asm volatile("s_waitcnt vmcnt(4)" ::: "memory");
    __builtin_amdgcn_s_barrier();

    for (int kt = 0; kt < nT; ++kt) {
        const int sl = kt & 1;
        const u16* lA = ldsA[sl][wr];
        const u16* lB = ldsB[sl][wc >> 1];
        short8 aF[4][2], bF[4][2];

#pragma unroll
        for (int fr = 0; fr < 4; fr++) {
            aF[fr][0] = *(const short8*)&lA[(fr * 16 + m16) * 64 + ck0];
            aF[fr][1] = *(const short8*)&lA[(fr * 16 + m16) * 64 + ck1];
        }
#pragma unroll
        for (int fc = 0; fc < 2; fc++) {
            bF[fc][0] = *(const short8*)&lB[(brb + fc * 16 + m16) * 64 + ck0];
            bF[fc][1] = *(const short8*)&lB[(brb + fc * 16 + m16) * 64 + ck1];
        }
        if (kt + 1 < nT) STAGE_A(kt + 1, 0);
        __builtin_amdgcn_s_barrier();
        asm volatile("s_waitcnt lgkmcnt(0)" ::: "memory");
        __builtin_amdgcn_s_setprio(1);
#pragma unroll
        for (int kk = 0; kk < 2; kk++)
#pragma unroll
            for (int mi = 0; mi < 4; mi++) {
                acc[mi][0] = MFMA16(aF[mi][kk], bF[0][kk], acc[mi][0]);
                acc[mi][1] = MFMA16(aF[mi][kk], bF[1][kk], acc[mi][1]);
            }
        __builtin_amdgcn_s_setprio(0);
        __builtin_amdgcn_s_barrier();

#pragma unroll
        for (int fc = 2; fc < 4; fc++) {
            bF[fc][0] = *(const short8*)&lB[(brb + fc * 16 + m16) * 64 + ck0];
            bF[fc][1] = *(const short8*)&lB[(brb + fc * 16 + m16) * 64 + ck1];
        }
        if (kt + 1 < nT) STAGE_A(kt + 1, 1);
        __builtin_amdgcn_s_barrier();
        asm volatile("s_waitcnt lgkmcnt(0)" ::: "memory");
        __builtin_amdgcn_s_setprio(1);
#pragma unroll
        for (int kk = 0; kk < 2; kk++)
#pragma unroll
            for (int mi = 0; mi < 4; mi++) {
                acc[mi][2] = MFMA16(aF[mi][kk], bF[2][kk], acc[mi][2]);
                acc[mi][3] = MFMA16(aF[mi][kk], bF[3][kk], acc[mi][3]);
            }
        __builtin_amdgcn_s_setprio(0);
        __builtin_amdgcn_s_barrier();

#pragma unroll
        for (int fr = 0; fr < 4; fr++) {
            aF[fr][0] = *(const short8*)&lA[((fr + 4) * 16 + m16) * 64 + ck0];
            aF[fr][1] = *(const short8*)&lA[((fr + 4) * 16 + m16) * 64 + ck1];
        }
        if (kt + 2 < nT) STAGE_B(kt + 2, 0);
        __builtin_amdgcn_s_barrier();
        asm volatile("s_waitcnt lgkmcnt(0)" ::: "memory");
        __builtin_amdgcn_s_setprio(1);
#pragma unroll
        for (int kk = 0; kk < 2; kk++)
#pragma unroll
            for (int mi = 0; mi < 4; mi++) {
                acc[4 + mi][0] = MFMA16(aF[mi][kk], bF[0][kk], acc[4 + mi][0]);
                acc[4 + mi][1] = MFMA16(aF[mi][kk], bF[1][kk], acc[4 + mi][1]);
            }
        __builtin_amdgcn_s_setprio(0);
        __builtin_amdgcn_s_barrier();

        if (kt + 2 < nT) STAGE_B(kt + 2, 1);
        __builtin_amdgcn_s_barrier();
        __builtin_amdgcn_s_setprio(1);
#pragma unroll
        for (int kk = 0; kk < 2; kk++)
#pragma unroll
            for (int mi = 0; mi < 4; mi++) {
                acc[4 + mi][2] = MFMA16(aF[mi][kk], bF[2][kk], acc[4 + mi][2]);
                acc[4 + mi][3] = MFMA16(aF[mi][kk], bF[3][kk], acc[4 + mi][3]);
            }
        __builtin_amdgcn_s_setprio(0);
        if (kt < nT - 1) {
            if (kt + 2 < nT) asm volatile("s_waitcnt vmcnt(4)" ::: "memory");
            else             asm volatile("s_waitcnt vmcnt(0)" ::: "memory");
            __builtin_amdgcn_s_barrier();
        }
    }
#undef STAGE_A
#undef STAGE_B

    const int cr = (l >> 4) * 4;
    const int cc = l & 15;
    if (tn < 4) {
        // K half: direct bf16 to kvk [65536][1024]
#pragma unroll
        for (int ni = 0; ni < 4; ni++) {
            const int col = tn * 256 + wc * 64 + ni * 16 + cc;
            const float bv = bias[col];
#pragma unroll
            for (int mi = 0; mi < 8; mi++) {
                const int row0 = tm * 256 + wr * 128 + mi * 16 + cr;
#pragma unroll
                for (int q = 0; q < 4; q++)
                    Ck[(size_t)(row0 + q) * 1024 + col] = f2bf(acc[mi][ni][q] + bv);
            }
        }
    } else {
        // V half transposed: lane's 4 acc values = 4 consecutive n -> one 8B store
        const int b = tm >> 6;
        const size_t nbase = (size_t)(tm & 63) * 256 + wr * 128 + cr;
#pragma unroll
        for (int ni = 0; ni < 4; ni++) {
            const int cg = (tn - 4) * 256 + wc * 64 + ni * 16 + cc;   // h*128+d
            const float bv = bias[1024 + cg];
            u16* rowp = CvT + (((size_t)(b * 1024 + cg)) << 14) + nbase;
#pragma unroll
            for (int mi = 0; mi < 8; mi++) {
                u32 lo = (u32)f2bf(acc[mi][ni][0] + bv) | ((u32)f2bf(acc[mi][ni][1] + bv) << 16);
                u32 hi = (u32)f2bf(acc[mi][ni][2] + bv) | ((u32)f2bf(acc[mi][ni][3] + bv) << 16);
                uint2 pk; pk.x = lo; pk.y = hi;
                *(uint2*)&rowp[mi * 16] = pk;
            }
        }
    }
}

// ---------------------------------------------------------------- slice pass v4
// Phase 1: MFMA scores + lane-group softmax -> w_bf (swizzled bf16 LDS).
// Outputs sw_out/wT/pnorm from w_bf. Phase 2: MFMA P@V using transposed vT.
__global__ __launch_bounds__(256) void slice_pass(
        const u16* __restrict__ kvk, const u16* __restrict__ vTg,
        const float* __restrict__ wtq,
        float* __restrict__ sw_out, u16* __restrict__ wT,
        float* __restrict__ pst, float* __restrict__ pnorm) {
    __shared__ u16 xk_lds[128 * 128];   // 32 KB: xk halves (phase 1) / vT halves [64][256] (phase 2)
    __shared__ u16 wtq_lds[MM * DD];    // 8 KB, chunk-swizzled
    __shared__ u16 w_bf[MM * 256];      // 16 KB, chunk-swizzled: elem(m,n) at m*256+((n>>3)^(m&7))*8+(n&7)
    const int t = threadIdx.x, l = t & 63, w = t >> 6;
    const int bh = blockIdx.y, b = bh >> 3, h = bh & 7;
    const int n0 = blockIdx.x * 256;

    for (int i = t; i < MM * DD; i += 256) {
        int m = i >> 7, d = i & 127;
        int idx = m * 128 + (((d >> 3) ^ (m & 7)) << 3) + (d & 7);
        wtq_lds[idx] = f2bf(wtq[(size_t)h * MM * DD + i]);
    }

    const int srow = t >> 4;
    const int sswz = (t & 15) ^ (srow & 7);
    const int mrow = l & 15;
    const int kg = l >> 4;

    // ---------------- phase 1
    for (int half = 0; half < 2; half++) {
        __syncthreads();
        {
            const u16* src = kvk + ((size_t)(b * NN) + n0 + half * 128 + srow) * 1024 + h * DD + sswz * 8;
            for (int j = 0; j < 8; j++)
                gload16(src + (size_t)j * 16 * 1024, xk_lds + j * 2048 + w * 512);
        }
        __syncthreads();

        f32x4 s[2][2];
        const f32x4 zero = {0.f, 0.f, 0.f, 0.f};
        s[0][0] = zero; s[0][1] = zero; s[1][0] = zero; s[1][1] = zero;
#pragma unroll
        for (int ks = 0; ks < 4; ks++) {
            const int pc = (((ks << 2) + kg) ^ (l & 7)) << 3;
            short8 a0 = *(const short8*)&wtq_lds[mrow * 128 + pc];
            short8 a1 = *(const short8*)&wtq_lds[(16 + mrow) * 128 + pc];
            short8 bb0 = *(const short8*)&xk_lds[(w * 32 + mrow) * 128 + pc];
            short8 bb1 = *(const short8*)&xk_lds[(w * 32 + 16 + mrow) * 128 + pc];
            s[0][0] = MFMA16(a0, bb0, s[0][0]);
            s[0][1] = MFMA16(a0, bb1, s[0][1]);
            s[1][0] = MFMA16(a1, bb0, s[1][0]);
            s[1][1] = MFMA16(a1, bb1, s[1][1]);
        }

#pragma unroll
        for (int nj = 0; nj < 2; nj++) {
            float mx = s[0][nj][0];
#pragma unroll
            for (int mi = 0; mi < 2; mi++)
#pragma unroll
                for (int q = 0; q < 4; q++) mx = fmaxf(mx, s[mi][nj][q]);
            mx = fmaxf(mx, __shfl_xor(mx, 16));
            mx = fmaxf(mx, __shfl_xor(mx, 32));
            float ex[2][4], sum = 0.f;
#pragma unroll
            for (int mi = 0; mi < 2; mi++)
#pragma unroll
                for (int q = 0; q < 4; q++) { ex[mi][q] = __expf(s[mi][nj][q] - mx); sum += ex[mi][q]; }
            sum += __shfl_xor(sum, 16);
            sum += __shfl_xor(sum, 32);
            const float inv = 1.f / sum;
            const int ncol = half * 128 + w * 32 + nj * 16 + mrow;
#pragma unroll
            for (int mi = 0; mi < 2; mi++)
#pragma unroll
                for (int q = 0; q < 4; q++) {
                    const int m = mi * 16 + kg * 4 + q;
                    w_bf[m * 256 + (((ncol >> 3) ^ (m & 7)) << 3) + (ncol & 7)] = f2bf(ex[mi][q] * inv);
                }
        }
    }
    __syncthreads();    // w_bf complete; xk reads done

    // ---------------- outputs from w_bf
#pragma unroll 4
    for (int m = 0; m < MM; m++)
        sw_out[((size_t)bh * MM + m) * NN + n0 + t] =
            bf2f(w_bf[m * 256 + (((t >> 3) ^ (m & 7)) << 3) + (t & 7)]);
    for (int i = t; i < 1024; i += 256) {
        const int row = i >> 2, seg = i & 3;
        u32 pk[4];
#pragma unroll
        for (int p = 0; p < 4; p++) {
            const int m0 = seg * 8 + 2 * p, m1 = m0 + 1;
            u16 w0 = w_bf[m0 * 256 + (((row >> 3) ^ (m0 & 7)) << 3) + (row & 7)];
            u16 w1 = w_bf[m1 * 256 + (((row >> 3) ^ (m1 & 7)) << 3) + (row & 7)];
            pk[p] = (u32)w0 | ((u32)w1 << 16);
        }
        uint4 q4; q4.x = pk[0]; q4.y = pk[1]; q4.z = pk[2]; q4.w = pk[3];
        *(uint4*)&wT[((size_t)(b * NN) + n0 + row) * 256 + h * 32 + seg * 8] = q4;
    }
    {
        const int pm = t >> 3, ps = t & 7;
        float ssum = 0.f;
        for (int j = 0; j < 32; j++) {
            const int n = ps * 32 + j;
            ssum += bf2f(w_bf[pm * 256 + (((n >> 3) ^ (pm & 7)) << 3) + (n & 7)]);
        }
        ssum += __shfl_xor(ssum, 1); ssum += __shfl_xor(ssum, 2); ssum += __shfl_xor(ssum, 4);
        if (ps == 0) pnorm[((size_t)bh * 64 + blockIdx.x) * MM + pm] = ssum;
    }

    // ---------------- phase 2: st[m][d] partial = sum_n w[m][n]*v[n][d] via MFMA
    f32x4 acc2[2][2];
    const f32x4 zero2 = {0.f, 0.f, 0.f, 0.f};
    acc2[0][0] = zero2; acc2[0][1] = zero2; acc2[1][0] = zero2; acc2[1][1] = zero2;

#pragma unroll
    for (int H = 0; H < 2; H++) {
        if (H == 0) __syncthreads();          // xk_lds free across waves
        {
            const size_t rg0 = (size_t)(b * 1024 + h * 128 + H * 64);
#pragma unroll
            for (int j = 0; j < 8; j++) {
                const int rl = w * 16 + j * 2 + (l >> 5);
                gload16(vTg + ((rg0 + rl) << 14) + n0 + (((l & 31) ^ (rl & 7)) << 3),
                        xk_lds + (w * 16 + j * 2) * 256 + l * 8);
            }
        }
        asm volatile("s_waitcnt vmcnt(0)" ::: "memory");   // wave reads only its own staged rows
        __builtin_amdgcn_sched_barrier(0);
#pragma unroll
        for (int ks = 0; ks < 8; ks++) {
            const int pc = (((ks << 2) + kg) ^ (l & 7)) << 3;
            short8 av0 = *(const short8*)&w_bf[mrow * 256 + pc];
            short8 av1 = *(const short8*)&w_bf[(16 + mrow) * 256 + pc];
            short8 bv  = *(const short8*)&xk_lds[(w * 16 + mrow) * 256 + pc];
            acc2[H][0] = MFMA16(av0, bv, acc2[H][0]);
            acc2[H][1] = MFMA16(av1, bv, acc2[H][1]);
        }
    }

    // pst write: lane holds C[m=kg*4+q + mt*16][d=H*64 + w*16 + mrow]
    {
        const size_t base = ((size_t)bh * 64 + blockIdx.x) * MM;
#pragma unroll
        for (int H2 = 0; H2 < 2; H2++)
#pragma unroll
            for (int mt = 0; mt < 2; mt++)
#pragma unroll
                for (int q = 0; q < 4; q++) {
                    const int m = mt * 16 + kg * 4 + q;
                    const int d = H2 * 64 + w * 16 + mrow;
                    pst[(base + m) * DD + d] = acc2[H2][mt][q];
                }
    }
}

// ---------------------------------------------------------------- reduce pst partials
__global__ __launch_bounds__(256) void reduce_pst(const float* __restrict__ pst,
                                                  const float* __restrict__ pnorm,
                                                  u16* __restrict__ st_red) {
    __shared__ float norm_lds[MM];
    const int bh = blockIdx.y, es = blockIdx.x, t = threadIdx.x;
    if (t < MM) {
        float s = 0.f;
        for (int g = 0; g < 64; g++) s += pnorm[((size_t)bh * 64 + g) * MM + t];
        norm_lds[t] = s + 1e-5f;
    }
    __syncthreads();
    const int e = es * 512 + t * 2;
    float ax = 0.f, ay = 0.f;
    for (int g = 0; g < 64; g++) {
        const float2 v = *(const float2*)&pst[((size_t)bh * 64 + g) * 4096 + e];
        ax += v.x; ay += v.y;
    }
    const float nv = norm_lds[e >> 7];
    u32 pk = (u32)f2bf(ax / nv) | ((u32)f2bf(ay / nv) << 16);
    ((u32*)st_red)[((size_t)bh * 4096 + e) >> 1] = pk;
}

// ---------------------------------------------------------------- finalize (per b,h)
__global__ void finalize_kernel(const u16* __restrict__ st_red,
                                const float* __restrict__ qkvp, float* __restrict__ attn_out,
                                float* __restrict__ otw) {
    __shared__ float qt[MM * 384];
    __shared__ u16 st_lds[MM * DD];
    __shared__ float dots[MM * MM];
    const int bh = blockIdx.x, h = bh & 7, t = threadIdx.x;

    {
        const uint4* src = (const uint4*)(st_red + (size_t)bh * 4096);
        ((uint4*)st_lds)[t] = src[t];
        ((uint4*)st_lds)[t + 256] = src[t + 256];
    }
    __syncthreads();
    const float* qw = qkvp + (size_t)h * DD * 384;
    for (int i = 0; i < 48; i++) {
        int j = t + i * 256;
        int m = j / 384, e = j - m * 384;
        float s = 0.f;
        for (int d = 0; d < DD; d++) s += bf2f(st_lds[m * DD + d]) * qw[d * 384 + e];
        qt[m * 384 + e] = s;
    }
    __syncthreads();
    const float scale = 0.08838834764831845f;
#pragma unroll
    for (int i = 0; i < 4; i++) {
        int idx = t * 4 + i;
        int qi = idx >> 5, kj = idx & 31;
        float s = 0.f;
        for (int d = 0; d < DD; d++) s += qt[qi * 384 + d] * qt[kj * 384 + 128 + d];
        dots[idx] = s * scale;
    }
    __syncthreads();
    if (t < MM) {
        float mx = -1e30f;
        float ex[MM];
#pragma unroll
        for (int j = 0; j < MM; j++) mx = fmaxf(mx, dots[t * MM + j]);
        float sm = 0.f;
#pragma unroll
        for (int j = 0; j < MM; j++) { ex[j] = __expf(dots[t * MM + j] - mx); sm += ex[j]; }
        float inv = 1.f / sm;
#pragma unroll
        for (int j = 0; j < MM; j++) {
            float v = ex[j] * inv;
            dots[t * MM + j] = v;
            attn_out[((size_t)bh * MM + t) * MM + j] = v;
        }
    }
    __syncthreads();
#pragma unroll
    for (int i = 0; i < 16; i++) {
        int e = t + i * 256;
        int m = e >> 7, d = e & 127;
        float s = 0.f;
#pragma unroll
        for (int j = 0; j < MM; j++) s += dots[m * MM + j] * qt[j * 384 + 256 + d];
        otw[(size_t)bh * 4096 + e] = s;
    }
}

// ---------------------------------------------------------------- zmat
__global__ __launch_bounds__(256) void zmat_kernel(const float* __restrict__ otw,
                                                   const float* __restrict__ outw,
                                                   u16* __restrict__ Zt) {
    __shared__ float ot_lds[MM * DD];
    const int bh = blockIdx.y, b = bh >> 3, h = bh & 7;
    const int es = blockIdx.x;
    const int t = threadIdx.x;
    for (int i = t; i < MM * DD; i += 256) ot_lds[i] = otw[(size_t)bh * 4096 + i];
    __syncthreads();
    const int e = es * 128 + (t >> 1);
    const int m0 = (t & 1) * 16;
    const float* ow = outw + (size_t)e * HDIM + h * DD;
    float acc[16];
#pragma unroll
    for (int m = 0; m < 16; m++) acc[m] = 0.f;
    for (int d = 0; d < DD; d += 4) {
        float4 o4 = *(const float4*)&ow[d];
#pragma unroll
        for (int m = 0; m < 16; m++) {
            const float* otr = &ot_lds[(m0 + m) * DD + d];
            acc[m] += o4.x * otr[0] + o4.y * otr[1] + o4.z * otr[2] + o4.w * otr[3];
        }
    }
    u32 pk[8];
#pragma unroll
    for (int p = 0; p < 8; p++)
        pk[p] = (u32)f2bf(acc[2 * p]) | ((u32)f2bf(acc[2 * p + 1]) << 16);
    u16* dst = Zt + ((size_t)b * 1024 + e) * 256 + h * 32 + m0;
#pragma unroll
    for (int p = 0; p < 2; p++) {
        uint4 q4; q4.x = pk[4 * p]; q4.y = pk[4 * p + 1]; q4.z = pk[4 * p + 2]; q4.w = pk[4 * p + 3];
        *(uint4*)&dst[p * 8] = q4;
    }
}

// ---------------------------------------------------------------- GEMM3 (f32 out, per-b B)
__global__ __launch_bounds__(512, 1) void gemm256_8p(
        const u16* __restrict__ A, const u16* __restrict__ Bm,
        const float* __restrict__ bias, float* __restrict__ Cout,
        int Ncols, int Kd, int ntn, int bshift, long long bstrideB) {
    __shared__ u16 ldsA[2][2][8192];
    __shared__ u16 ldsB[2][2][8192];
    const int t = threadIdx.x, l = t & 63, w = t >> 6;
    const int wr = w >> 2, wc = w & 3;

    const int nwg = gridDim.x, cpx = nwg >> 3, bid = blockIdx.x;
    const int swz = (bid & 7) * cpx + (bid >> 3);
    const int tm = swz / ntn, tn = swz % ntn;
    const u16* Bb = Bm + (size_t)(tm >> bshift) * bstrideB;

    f32x4 acc[8][4];
    const f32x4 zero = {0.f, 0.f, 0.f, 0.f};
#pragma unroll
    for (int mi = 0; mi < 8; mi++)
#pragma unroll
        for (int ni = 0; ni < 4; ni++) acc[mi][ni] = zero;

    const int srow = w * 8 + (l >> 3);
    const int skel = ((l & 7) ^ ((l >> 3) & 7)) * 8;
    const u16* gA = A  + (size_t)(tm * 256 + srow) * Kd + skel;
    const u16* gB = Bb + (size_t)(tn * 256 + srow) * Kd + skel;
    const int ldo = w * 512 + l * 8;

#define STAGE_A(T, H) { const u16* g_ = gA + (size_t)((H) * 128) * Kd + (T) * 64; \
    u16* d_ = &ldsA[(T) & 1][H][ldo]; gload16(g_, d_); gload16(g_ + (size_t)64 * Kd, d_ + 4096); }
#define STAGE_B(T, H) { const u16* g_ = gB + (size_t)((H) * 128) * Kd + (T) * 64; \
    u16* d_ = &ldsB[(T) & 1][H][ldo]; gload16(g_, d_); gload16(g_ + (size_t)64 * Kd, d_ + 4096); }

    const int m16 = l & 15;
    const int ck0 = (((l >> 4) + 0) ^ (l & 7)) << 3;
    const int ck1 = (((l >> 4) + 4) ^ (l & 7)) << 3;
    const int brb = (wc & 1) * 64;
    const int nT = Kd >> 6;

    STAGE_A(0, 0); STAGE_A(0, 1); STAGE_B(0, 0); STAGE_B(0, 1);
    STAGE_B(1, 0); STAGE_B(1, 1);
    asm volatile("s_waitcnt vmcnt(4)" ::: "memory");
    __builtin_amdgcn_s_barrier();

    for (int kt = 0; kt < nT; ++kt) {
        const int sl = kt & 1;
        const u16* lA = ldsA[sl][wr];
        const u16* lB = ldsB[sl][wc >> 1];
        short8 aF[4][2], bF[4][2];

#pragma unroll
        for (int fr = 0; fr < 4; fr++) {
            aF[fr][0] = *(const short8*)&lA[(fr * 16 + m16) * 64 + ck0];
            aF[fr][1] = *(const short8*)&lA[(fr * 16 + m16) * 64 + ck1];
        }
#pragma unroll
        for (int fc = 0; fc < 2; fc++) {
            bF[fc][0] = *(const short8*)&lB[(brb + fc * 16 + m16) * 64 + ck0];
            bF[fc][1] = *(const short8*)&lB[(brb + fc * 16 + m16) * 64 + ck1];
        }
        if (kt + 1 < nT) STAGE_A(kt + 1, 0);
        __builtin_amdgcn_s_barrier();
        asm volatile("s_waitcnt lgkmcnt(0)" ::: "memory");
        __builtin_amdgcn_s_setprio(1);
#pragma unroll
        for (int kk = 0; kk < 2; kk++)
#pragma unroll
            for (int mi = 0; mi < 4; mi++) {
                acc[mi][0] = MFMA16(aF[mi][kk], bF[0][kk], acc[mi][0]);
                acc[mi][1] = MFMA16(aF[mi][kk], bF[1][kk], acc[mi][1]);
            }
        __builtin_amdgcn_s_setprio(0);
        __builtin_amdgcn_s_barrier();

#pragma unroll
        for (int fc = 2; fc < 4; fc++) {
            bF[fc][0] = *(const short8*)&lB[(brb + fc * 16 + m16) * 64 + ck0];
            bF[fc][1] = *(const short8*)&lB[(brb + fc * 16 + m16) * 64 + ck1];
        }
        if (kt + 1 < nT) STAGE_A(kt + 1, 1);
        __builtin_amdgcn_s_barrier();
        asm volatile("s_waitcnt lgkmcnt(0)" ::: "memory");
        __builtin_amdgcn_s_setprio(1);
#pragma unroll
        for (int kk = 0; kk < 2; kk++)
#pragma unroll
            for (int mi = 0; mi < 4; mi++) {
                acc[mi][2] = MFMA16(aF[mi][kk], bF[2][kk], acc[mi][2]);
                acc[mi][3] = MFMA16(aF[mi][kk], bF[3][kk], acc[mi][3]);
            }
        __builtin_amdgcn_s_setprio(0);
        __builtin_amdgcn_s_barrier();

#pragma unroll
        for (int fr = 0; fr < 4; fr++) {
            aF[fr][0] = *(const short8*)&lA[((fr + 4) * 16 + m16) * 64 + ck0];
            aF[fr][1] = *(const short8*)&lA[((fr + 4) * 16 + m16) * 64 + ck1];
        }
        if (kt + 2 < nT) STAGE_B(kt + 2, 0);
        __builtin_amdgcn_s_barrier();
        asm volatile("s_waitcnt lgkmcnt(0)" ::: "memory");
        __builtin_amdgcn_s_setprio(1);
#pragma unroll
        for (int kk = 0; kk < 2; kk++)
#pragma unroll
            for (int mi = 0; mi < 4; mi++) {
                acc[4 + mi][0] = MFMA16(aF[mi][kk], bF[0][kk], acc[4 + mi][0]);
                acc[4 + mi][1] = MFMA16(aF[mi][kk], bF[1][kk], acc[4 + mi][1]);
            }
        __builtin_amdgcn_s_setprio(0);
        __builtin_amdgcn_s_barrier();

        if (kt + 2 < nT) STAGE_B(kt + 2, 1);
        __builtin_amdgcn_s_barrier();
        __builtin_amdgcn_s_setprio(1);
#pragma unroll
        for (int kk = 0; kk < 2; kk++)
#pragma unroll
            for (int mi = 0; mi < 4; mi++) {
                acc[4 + mi][2] = MFMA16(aF[mi][kk], bF[2][kk], acc[4 + mi][2]);
                acc[4 + mi][3] = MFMA16(aF[mi][kk], bF[3][kk], acc[4 + mi][3]);
            }
        __builtin_amdgcn_s_setprio(0);
        if (kt < nT - 1) {
            if (kt + 2 < nT) asm volatile("s_waitcnt vmcnt(4)" ::: "memory");
            else             asm volatile("s_waitcnt vmcnt(0)" ::: "memory");
            __builtin_amdgcn_s_barrier();
        }
    }
#undef STAGE_A
#undef STAGE_B

    const int cr = (l >> 4) * 4;
    const int cc = l & 15;
#pragma unroll
    for (int ni = 0; ni < 4; ni++) {
        const int col = tn * 256 + wc * 64 + ni * 16 + cc;
        const float bv = bias[col];
#pragma unroll
        for (int mi = 0; mi < 8; mi++) {
            const int row0 = tm * 256 + wr * 128 + mi * 16 + cr;
#pragma unroll
            for (int q = 0; q < 4; q++)
                Cout[(size_t)(row0 + q) * Ncols + col] = acc[mi][ni][q] + bv;
        }
    }
}

// ---------------------------------------------------------------- launch
extern "C" void kernel_launch(void* const* d_in, const int* in_sizes, int n_in,
                              void* d_out, int out_size, void* d_ws, size_t ws_size,
                              hipStream_t stream) {
    const float* x        = (const float*)d_in[0];
    const float* wkv      = (const float*)d_in[1];
    const float* bkv      = (const float*)d_in[2];
    const float* wtq      = (const float*)d_in[3];
    const float* wtq_bias = (const float*)d_in[4];
    const float* qkvp     = (const float*)d_in[5];
    const float* outw     = (const float*)d_in[6];
    const float* outb     = (const float*)d_in[7];

    float* out  = (float*)d_out;
    float* out0 = out;                      // [B,N,HD]
    float* out1 = out + 67108864;           // slice_weights
    float* out2 = out + 83886080;           // temperature + bias
    float* out4 = out + 83886337;           // attn_weights

    char* ws = (char*)d_ws;
    u16*   xb    = (u16*)(ws);                          // 134 MB: x bf16; reused as wT
    u16*   wT    = xb;
    u16*   kvk   = (u16*)(ws + 134217728);              // 134 MB [65536][1024] (K half)
    u16*   st_red= (u16*)(ws + 134217728);              // aliases kvk (dead after slice_pass)
    u16*   Zt    = (u16*)(ws + 142606336);              // inside kvk region, used post-slice
    u16*   vTg   = (u16*)(ws + 268435456);              // 134 MB [4096][16384] (V^T)
    u16*   wkvb  = (u16*)(ws + 402653184);              // 4 MB
    float* pst   = (float*)(ws + 408944640);            // 33.5 MB
    float* pnorm = (float*)(ws + 442499072);            // 256 KB
    float* otws  = (float*)(ws + 442761216);            // 512 KB

    convert_kernel<<<dim3(2048), dim3(256), 0, stream>>>(x, wkv, xb, wkvb, wtq_bias, out2);
    gemm_kv<<<dim3(2048), dim3(512), 0, stream>>>(xb, wkvb, bkv, kvk, vTg);
    slice_pass<<<dim3(64, 32), dim3(256), 0, stream>>>(kvk, vTg, wtq, out1, wT, pst, pnorm);
    reduce_pst<<<dim3(8, 32), dim3(256), 0, stream>>>(pst, pnorm, st_red);
    finalize_kernel<<<dim3(32), dim3(256), 0, stream>>>(st_red, qkvp, out4, otws);
    zmat_kernel<<<dim3(8, 32), dim3(256), 0, stream>>>(otws, outw, Zt);
    gemm256_8p<<<dim3(1024), dim3(512), 0, stream>>>(wT, Zt, outb, out0, HDIM, 256, 4, 6, (long long)1024 * 256);
}

// Round 10
// 736.625 us; speedup vs baseline: 1.5469x; 1.1027x over previous
//
#include <hip/hip_runtime.h>
#include <hip/hip_bf16.h>
#include <stdint.h>

#define BB 4
#define NN 16384
#define HDIM 1024
#define HH 8
#define MM 32
#define DD 128

typedef unsigned int u32;
typedef unsigned short u16;
typedef __attribute__((ext_vector_type(8))) short short8;
typedef __attribute__((ext_vector_type(4))) float f32x4;

__device__ __forceinline__ float bf2f(u16 v) {
    union { u32 u; float f; } c; c.u = ((u32)v) << 16; return c.f;
}
__device__ __forceinline__ u16 f2bf(float f) {
    union { float f; u32 u; } c; c.f = f;
    u32 r = c.u + 0x7fffu + ((c.u >> 16) & 1u);
    return (u16)(r >> 16);
}

__device__ __forceinline__ void gload16(const u16* g, u16* l) {
    __builtin_amdgcn_global_load_lds(
        (const __attribute__((address_space(1))) void*)g,
        (__attribute__((address_space(3))) void*)l, 16, 0, 0);
}

#define MFMA16(a, b, c) __builtin_amdgcn_mfma_f32_16x16x32_bf16(a, b, c, 0, 0, 0)

// ---------------------------------------------------------------- convert: x -> bf16; Wkv V-half -> bf16
__global__ void convert_kernel(const float* __restrict__ x, const float* __restrict__ wkv,
                               u16* __restrict__ xb, u16* __restrict__ wkvb_v,
                               const float* __restrict__ wtq_bias, float* __restrict__ out_misc) {
    size_t i = (size_t)blockIdx.x * blockDim.x + threadIdx.x;
    size_t stride = (size_t)gridDim.x * blockDim.x;
    const size_t nx = (size_t)BB * NN * HDIM / 4;
    const size_t nw = (size_t)1024 * HDIM / 4;      // V rows only
    const float* wkv_v = wkv + (size_t)1024 * HDIM;
    for (size_t j = i; j < nx; j += stride) {
        float4 v = ((const float4*)x)[j];
        ushort4 o; o.x = f2bf(v.x); o.y = f2bf(v.y); o.z = f2bf(v.z); o.w = f2bf(v.w);
        ((ushort4*)xb)[j] = o;
    }
    for (size_t j = i; j < nw; j += stride) {
        float4 v = ((const float4*)wkv_v)[j];
        ushort4 o; o.x = f2bf(v.x); o.y = f2bf(v.y); o.z = f2bf(v.z); o.w = f2bf(v.w);
        ((ushort4*)wkvb_v)[j] = o;
    }
    if (blockIdx.x == 0) {
        if (threadIdx.x == 0) out_misc[0] = 1.0f;
        if (threadIdx.x < HH * MM) out_misc[1 + threadIdx.x] = wtq_bias[threadIdx.x];
    }
}

// ---------------------------------------------------------------- WQ = wtq @ Wkv_K ; wq_bias = wtq @ bkv_K
// grid (8 e-chunks, 8 h), 256 threads. WQb bf16 [256 hm][1024 e].
__global__ __launch_bounds__(256) void wq_kernel(const float* __restrict__ wtq,
                                                 const float* __restrict__ wkv,
                                                 const float* __restrict__ bkv,
                                                 u16* __restrict__ WQb, float* __restrict__ wqbias) {
    __shared__ float wtql[MM * DD];     // 16 KB
    const int ec = blockIdx.x, h = blockIdx.y, t = threadIdx.x;
    for (int i = t; i < MM * DD; i += 256) wtql[i] = wtq[(size_t)h * MM * DD + i];
    __syncthreads();
    const int m = t >> 3;
    const int e = ec * 128 + (t & 7) * 16;
    float acc[16];
#pragma unroll
    for (int j = 0; j < 16; j++) acc[j] = 0.f;
    for (int d = 0; d < DD; d++) {
        const float wv = wtql[m * DD + d];
        const float4* row = (const float4*)(wkv + (size_t)(h * DD + d) * HDIM + e);
#pragma unroll
        for (int j4 = 0; j4 < 4; j4++) {
            float4 v = row[j4];
            acc[j4 * 4 + 0] += wv * v.x; acc[j4 * 4 + 1] += wv * v.y;
            acc[j4 * 4 + 2] += wv * v.z; acc[j4 * 4 + 3] += wv * v.w;
        }
    }
    u32 pk[8];
#pragma unroll
    for (int p = 0; p < 8; p++)
        pk[p] = (u32)f2bf(acc[2 * p]) | ((u32)f2bf(acc[2 * p + 1]) << 16);
    u16* dst = WQb + (size_t)(h * MM + m) * HDIM + e;
#pragma unroll
    for (int p = 0; p < 2; p++) {
        uint4 q4; q4.x = pk[4 * p]; q4.y = pk[4 * p + 1]; q4.z = pk[4 * p + 2]; q4.w = pk[4 * p + 3];
        *(uint4*)&dst[p * 8] = q4;
    }
    if (ec == 0 && t < MM) {
        float s = 0.f;
        for (int d = 0; d < DD; d++) s += wtql[t * DD + d] * bkv[h * DD + d];
        wqbias[h * MM + t] = s;
    }
}

// ---------------------------------------------------------------- unified 8-phase GEMM (256x256, BK=64)
// MODE 0: f32 C row-major (+bias[col]), per-b B (bshift/bstrideB elements).
// MODE 1: bf16 transposed C: dst[(b*crows + col)<<14 + n], bias[bofs+col]; crows = NCols param.
template<int MODE>
__global__ __launch_bounds__(512, 1) void gemm_nt(
        const u16* __restrict__ A, const u16* __restrict__ Bm,
        const float* __restrict__ bias, void* __restrict__ Cout,
        int NCols, int Kd, int ntn, int bofs, int bshift, long long bstrideB) {
    __shared__ u16 ldsA[2][2][8192];
    __shared__ u16 ldsB[2][2][8192];
    const int t = threadIdx.x, l = t & 63, w = t >> 6;
    const int wr = w >> 2, wc = w & 3;

    const int nwg = gridDim.x, cpx = nwg >> 3, bid = blockIdx.x;
    const int swz = (bid & 7) * cpx + (bid >> 3);
    const int tm = swz / ntn, tn = swz % ntn;
    const u16* Bb = Bm + (size_t)(tm >> bshift) * bstrideB;

    f32x4 acc[8][4];
    const f32x4 zero = {0.f, 0.f, 0.f, 0.f};
#pragma unroll
    for (int mi = 0; mi < 8; mi++)
#pragma unroll
        for (int ni = 0; ni < 4; ni++) acc[mi][ni] = zero;

    const int srow = w * 8 + (l >> 3);
    const int skel = ((l & 7) ^ ((l >> 3) & 7)) * 8;
    const u16* gA = A  + (size_t)(tm * 256 + srow) * Kd + skel;
    const u16* gB = Bb + (size_t)(tn * 256 + srow) * Kd + skel;
    const int ldo = w * 512 + l * 8;

#define STAGE_A(T, H) { const u16* g_ = gA + (size_t)((H) * 128) * Kd + (T) * 64; \
    u16* d_ = &ldsA[(T) & 1][H][ldo]; gload16(g_, d_); gload16(g_ + (size_t)64 * Kd, d_ + 4096); }
#define STAGE_B(T, H) { const u16* g_ = gB + (size_t)((H) * 128) * Kd + (T) * 64; \
    u16* d_ = &ldsB[(T) & 1][H][ldo]; gload16(g_, d_); gload16(g_ + (size_t)64 * Kd, d_ + 4096); }

    const int m16 = l & 15;
    const int ck0 = (((l >> 4) + 0) ^ (l & 7)) << 3;
    const int ck1 = (((l >> 4) + 4) ^ (l & 7)) << 3;
    const int brb = (wc & 1) * 64;
    const int nT = Kd >> 6;

    STAGE_A(0, 0); STAGE_A(0, 1); STAGE_B(0, 0); STAGE_B(0, 1);
    STAGE_B(1, 0); STAGE_B(1, 1);
    asm volatile("s_waitcnt vmcnt(4)" ::: "memory");
    __builtin_amdgcn_s_barrier();

    for (int kt = 0; kt < nT; ++kt) {
        const int sl = kt & 1;
        const u16* lA = ldsA[sl][wr];
        const u16* lB = ldsB[sl][wc >> 1];
        short8 aF[4][2], bF[4][2];

#pragma unroll
        for (int fr = 0; fr < 4; fr++) {
            aF[fr][0] = *(const short8*)&lA[(fr * 16 + m16) * 64 + ck0];
            aF[fr][1] = *(const short8*)&lA[(fr * 16 + m16) * 64 + ck1];
        }
#pragma unroll
        for (int fc = 0; fc < 2; fc++) {
            bF[fc][0] = *(const short8*)&lB[(brb + fc * 16 + m16) * 64 + ck0];
            bF[fc][1] = *(const short8*)&lB[(brb + fc * 16 + m16) * 64 + ck1];
        }
        if (kt + 1 < nT) STAGE_A(kt + 1, 0);
        __builtin_amdgcn_s_barrier();
        asm volatile("s_waitcnt lgkmcnt(0)" ::: "memory");
        __builtin_amdgcn_s_setprio(1);
#pragma unroll
        for (int kk = 0; kk < 2; kk++)
#pragma unroll
            for (int mi = 0; mi < 4; mi++) {
                acc[mi][0] = MFMA16(aF[mi][kk], bF[0][kk], acc[mi][0]);
                acc[mi][1] = MFMA16(aF[mi][kk], bF[1][kk], acc[mi][1]);
            }
        __builtin_amdgcn_s_setprio(0);
        __builtin_amdgcn_s_barrier();

#pragma unroll
        for (int fc = 2; fc < 4; fc++) {
            bF[fc][0] = *(const short8*)&lB[(brb + fc * 16 + m16) * 64 + ck0];
            bF[fc][1] = *(const short8*)&lB[(brb + fc * 16 + m16) * 64 + ck1];
        }
        if (kt + 1 < nT) STAGE_A(kt + 1, 1);
        __builtin_amdgcn_s_barrier();
        asm volatile("s_waitcnt lgkmcnt(0)" ::: "memory");
        __builtin_amdgcn_s_setprio(1);
#pragma unroll
        for (int kk = 0; kk < 2; kk++)
#pragma unroll
            for (int mi = 0; mi < 4; mi++) {
                acc[mi][2] = MFMA16(aF[mi][kk], bF[2][kk], acc[mi][2]);
                acc[mi][3] = MFMA16(aF[mi][kk], bF[3][kk], acc[mi][3]);
            }
        __builtin_amdgcn_s_setprio(0);
        __builtin_amdgcn_s_barrier();

#pragma unroll
        for (int fr = 0; fr < 4; fr++) {
            aF[fr][0] = *(const short8*)&lA[((fr + 4) * 16 + m16) * 64 + ck0];
            aF[fr][1] = *(const short8*)&lA[((fr + 4) * 16 + m16) * 64 + ck1];
        }
        if (kt + 2 < nT) STAGE_B(kt + 2, 0);
        __builtin_amdgcn_s_barrier();
        asm volatile("s_waitcnt lgkmcnt(0)" ::: "memory");
        __builtin_amdgcn_s_setprio(1);
#pragma unroll
        for (int kk = 0; kk < 2; kk++)
#pragma unroll
            for (int mi = 0; mi < 4; mi++) {
                acc[4 + mi][0] = MFMA16(aF[mi][kk], bF[0][kk], acc[4 + mi][0]);
                acc[4 + mi][1] = MFMA16(aF[mi][kk], bF[1][kk], acc[4 + mi][1]);
            }
        __builtin_amdgcn_s_setprio(0);
        __builtin_amdgcn_s_barrier();

        if (kt + 2 < nT) STAGE_B(kt + 2, 1);
        __builtin_amdgcn_s_barrier();
        __builtin_amdgcn_s_setprio(1);
#pragma unroll
        for (int kk = 0; kk < 2; kk++)
#pragma unroll
            for (int mi = 0; mi < 4; mi++) {
                acc[4 + mi][2] = MFMA16(aF[mi][kk], bF[2][kk], acc[4 + mi][2]);
                acc[4 + mi][3] = MFMA16(aF[mi][kk], bF[3][kk], acc[4 + mi][3]);
            }
        __builtin_amdgcn_s_setprio(0);
        if (kt < nT - 1) {
            if (kt + 2 < nT) asm volatile("s_waitcnt vmcnt(4)" ::: "memory");
            else             asm volatile("s_waitcnt vmcnt(0)" ::: "memory");
            __builtin_amdgcn_s_barrier();
        }
    }
#undef STAGE_A
#undef STAGE_B

    const int cr = (l >> 4) * 4;
    const int cc = l & 15;
    if (MODE == 0) {
#pragma unroll
        for (int ni = 0; ni < 4; ni++) {
            const int col = tn * 256 + wc * 64 + ni * 16 + cc;
            const float bv = bias[col];
#pragma unroll
            for (int mi = 0; mi < 8; mi++) {
                const int row0 = tm * 256 + wr * 128 + mi * 16 + cr;
#pragma unroll
                for (int q = 0; q < 4; q++)
                    ((float*)Cout)[(size_t)(row0 + q) * NCols + col] = acc[mi][ni][q] + bv;
            }
        }
    } else {
        // transposed bf16: lane's 4 acc values = 4 consecutive n -> one 8B store
        const int b = tm >> 6;
        const size_t nbase = (size_t)(tm & 63) * 256 + wr * 128 + cr;
#pragma unroll
        for (int ni = 0; ni < 4; ni++) {
            const int cg = tn * 256 + wc * 64 + ni * 16 + cc;
            const float bv = bias[bofs + cg];
            u16* rowp = (u16*)Cout + (((size_t)(b * NCols + cg)) << 14) + nbase;
#pragma unroll
            for (int mi = 0; mi < 8; mi++) {
                u32 lo = (u32)f2bf(acc[mi][ni][0] + bv) | ((u32)f2bf(acc[mi][ni][1] + bv) << 16);
                u32 hi = (u32)f2bf(acc[mi][ni][2] + bv) | ((u32)f2bf(acc[mi][ni][3] + bv) << 16);
                uint2 pk; pk.x = lo; pk.y = hi;
                *(uint2*)&rowp[mi * 16] = pk;
            }
        }
    }
}

// ---------------------------------------------------------------- slice pass v5
// Stage scoresT tile [32 m][256 n] -> per-thread softmax over m -> sw_out/wT/w_bf;
// then MFMA P@V (v4 code) -> pst, pnorm.
__global__ __launch_bounds__(256, 2) void slice_pass(
        const u16* __restrict__ scoresT, const u16* __restrict__ vTg,
        float* __restrict__ sw_out, u16* __restrict__ wT,
        float* __restrict__ pst, float* __restrict__ pnorm) {
    __shared__ u16 sc_lds[MM * 256];    // 16 KB linear [m][n]
    __shared__ u16 w_bf[MM * 256];      // 16 KB swizzled: (m,n) at m*256+((n>>3)^(m&7))*8+(n&7)
    __shared__ u16 vbuf[64 * 256];      // 32 KB vT halves [64 rows][256 n]
    const int t = threadIdx.x, l = t & 63, w = t >> 6;
    const int bh = blockIdx.y, b = bh >> 3, h = bh & 7;
    const int n0 = blockIdx.x * 256;
    const int mrow = l & 15;
    const int kg = l >> 4;

    // stage scores rows (linear LDS; wave w covers rows w*8..w*8+7)
    {
        const size_t rb = (size_t)(b * 256 + h * MM);
#pragma unroll
        for (int j = 0; j < 4; j++) {
            const int rl = w * 8 + j * 2 + (l >> 5);
            gload16(scoresT + ((rb + rl) << 14) + n0 + (l & 31) * 8,
                    sc_lds + (w * 8 + j * 2) * 256 + l * 8);
        }
    }
    __syncthreads();

    // per-thread softmax over m for n = t
    {
        float sv[MM];
#pragma unroll
        for (int m = 0; m < MM; m++) sv[m] = bf2f(sc_lds[m * 256 + t]);
        float mx = sv[0];
#pragma unroll
        for (int m = 1; m < MM; m++) mx = fmaxf(mx, sv[m]);
        float sum = 0.f;
#pragma unroll
        for (int m = 0; m < MM; m++) { sv[m] = __expf(sv[m] - mx); sum += sv[m]; }
        const float inv = 1.f / sum;
        u32 pk[16];
#pragma unroll
        for (int m = 0; m < MM; m++) {
            const float wv = sv[m] * inv;
            sw_out[((size_t)bh * MM + m) * NN + n0 + t] = wv;
            const u16 wb = f2bf(wv);
            w_bf[m * 256 + (((t >> 3) ^ (m & 7)) << 3) + (t & 7)] = wb;
            if (m & 1) pk[m >> 1] |= ((u32)wb << 16); else pk[m >> 1] = (u32)wb;
        }
        u16* wrow = wT + ((size_t)(b * NN) + n0 + t) * 256 + h * MM;
#pragma unroll
        for (int p = 0; p < 4; p++) {
            uint4 q4; q4.x = pk[4 * p]; q4.y = pk[4 * p + 1]; q4.z = pk[4 * p + 2]; q4.w = pk[4 * p + 3];
            *(uint4*)&wrow[p * 8] = q4;
        }
    }
    __syncthreads();    // w_bf complete

    // pnorm partials
    {
        const int pm = t >> 3, ps = t & 7;
        float ssum = 0.f;
        for (int j = 0; j < 32; j++) {
            const int n = ps * 32 + j;
            ssum += bf2f(w_bf[pm * 256 + (((n >> 3) ^ (pm & 7)) << 3) + (n & 7)]);
        }
        ssum += __shfl_xor(ssum, 1); ssum += __shfl_xor(ssum, 2); ssum += __shfl_xor(ssum, 4);
        if (ps == 0) pnorm[((size_t)bh * 64 + blockIdx.x) * MM + pm] = ssum;
    }

    // P@V via MFMA (v4 verified code)
    f32x4 acc2[2][2];
    const f32x4 zero2 = {0.f, 0.f, 0.f, 0.f};
    acc2[0][0] = zero2; acc2[0][1] = zero2; acc2[1][0] = zero2; acc2[1][1] = zero2;

#pragma unroll
    for (int H = 0; H < 2; H++) {
        {
            const size_t rg0 = (size_t)(b * 1024 + h * 128 + H * 64);
#pragma unroll
            for (int j = 0; j < 8; j++) {
                const int rl = w * 16 + j * 2 + (l >> 5);
                gload16(vTg + ((rg0 + rl) << 14) + n0 + (((l & 31) ^ (rl & 7)) << 3),
                        vbuf + (w * 16 + j * 2) * 256 + l * 8);
            }
        }
        asm volatile("s_waitcnt vmcnt(0)" ::: "memory");   // wave reads only its own staged rows
        __builtin_amdgcn_sched_barrier(0);
#pragma unroll
        for (int ks = 0; ks < 8; ks++) {
            const int pc = (((ks << 2) + kg) ^ (l & 7)) << 3;
            short8 av0 = *(const short8*)&w_bf[mrow * 256 + pc];
            short8 av1 = *(const short8*)&w_bf[(16 + mrow) * 256 + pc];
            short8 bv  = *(const short8*)&vbuf[(w * 16 + mrow) * 256 + pc];
            acc2[H][0] = MFMA16(av0, bv, acc2[H][0]);
            acc2[H][1] = MFMA16(av1, bv, acc2[H][1]);
        }
    }

    {
        const size_t base = ((size_t)bh * 64 + blockIdx.x) * MM;
#pragma unroll
        for (int H2 = 0; H2 < 2; H2++)
#pragma unroll
            for (int mt = 0; mt < 2; mt++)
#pragma unroll
                for (int q = 0; q < 4; q++) {
                    const int m = mt * 16 + kg * 4 + q;
                    const int d = H2 * 64 + w * 16 + mrow;
                    pst[(base + m) * DD + d] = acc2[H2][mt][q];
                }
    }
}

// ---------------------------------------------------------------- reduce pst partials
__global__ __launch_bounds__(256) void reduce_pst(const float* __restrict__ pst,
                                                  const float* __restrict__ pnorm,
                                                  u16* __restrict__ st_red) {
    __shared__ float norm_lds[MM];
    const int bh = blockIdx.y, es = blockIdx.x, t = threadIdx.x;
    if (t < MM) {
        float s = 0.f;
        for (int g = 0; g < 64; g++) s += pnorm[((size_t)bh * 64 + g) * MM + t];
        norm_lds[t] = s + 1e-5f;
    }
    __syncthreads();
    const int e = es * 512 + t * 2;
    float ax = 0.f, ay = 0.f;
    for (int g = 0; g < 64; g++) {
        const float2 v = *(const float2*)&pst[((size_t)bh * 64 + g) * 4096 + e];
        ax += v.x; ay += v.y;
    }
    const float nv = norm_lds[e >> 7];
    u32 pk = (u32)f2bf(ax / nv) | ((u32)f2bf(ay / nv) << 16);
    ((u32*)st_red)[((size_t)bh * 4096 + e) >> 1] = pk;
}

// ---------------------------------------------------------------- finalize (per b,h)
__global__ void finalize_kernel(const u16* __restrict__ st_red,
                                const float* __restrict__ qkvp, float* __restrict__ attn_out,
                                float* __restrict__ otw) {
    __shared__ float qt[MM * 384];
    __shared__ u16 st_lds[MM * DD];
    __shared__ float dots[MM * MM];
    const int bh = blockIdx.x, h = bh & 7, t = threadIdx.x;

    {
        const uint4* src = (const uint4*)(st_red + (size_t)bh * 4096);
        ((uint4*)st_lds)[t] = src[t];
        ((uint4*)st_lds)[t + 256] = src[t + 256];
    }
    __syncthreads();
    const float* qw = qkvp + (size_t)h * DD * 384;
    for (int i = 0; i < 48; i++) {
        int j = t + i * 256;
        int m = j / 384, e = j - m * 384;
        float s = 0.f;
        for (int d = 0; d < DD; d++) s += bf2f(st_lds[m * DD + d]) * qw[d * 384 + e];
        qt[m * 384 + e] = s;
    }
    __syncthreads();
    const float scale = 0.08838834764831845f;
#pragma unroll
    for (int i = 0; i < 4; i++) {
        int idx = t * 4 + i;
        int qi = idx >> 5, kj = idx & 31;
        float s = 0.f;
        for (int d = 0; d < DD; d++) s += qt[qi * 384 + d] * qt[kj * 384 + 128 + d];
        dots[idx] = s * scale;
    }
    __syncthreads();
    if (t < MM) {
        float mx = -1e30f;
        float ex[MM];
#pragma unroll
        for (int j = 0; j < MM; j++) mx = fmaxf(mx, dots[t * MM + j]);
        float sm = 0.f;
#pragma unroll
        for (int j = 0; j < MM; j++) { ex[j] = __expf(dots[t * MM + j] - mx); sm += ex[j]; }
        float inv = 1.f / sm;
#pragma unroll
        for (int j = 0; j < MM; j++) {
            float v = ex[j] * inv;
            dots[t * MM + j] = v;
            attn_out[((size_t)bh * MM + t) * MM + j] = v;
        }
    }
    __syncthreads();
#pragma unroll
    for (int i = 0; i < 16; i++) {
        int e = t + i * 256;
        int m = e >> 7, d = e & 127;
        float s = 0.f;
#pragma unroll
        for (int j = 0; j < MM; j++) s += dots[m * MM + j] * qt[j * 384 + 256 + d];
        otw[(size_t)bh * 4096 + e] = s;
    }
}

// ---------------------------------------------------------------- zmat
__global__ __launch_bounds__(256) void zmat_kernel(const float* __restrict__ otw,
                                                   const float* __restrict__ outw,
                                                   u16* __restrict__ Zt) {
    __shared__ float ot_lds[MM * DD];
    const int bh = blockIdx.y, b = bh >> 3, h = bh & 7;
    const int es = blockIdx.x;
    const int t = threadIdx.x;
    for (int i = t; i < MM * DD; i += 256) ot_lds[i] = otw[(size_t)bh * 4096 + i];
    __syncthreads();
    const int e = es * 128 + (t >> 1);
    const int m0 = (t & 1) * 16;
    const float* ow = outw + (size_t)e * HDIM + h * DD;
    float acc[16];
#pragma unroll
    for (int m = 0; m < 16; m++) acc[m] = 0.f;
    for (int d = 0; d < DD; d += 4) {
        float4 o4 = *(const float4*)&ow[d];
#pragma unroll
        for (int m = 0; m < 16; m++) {
            const float* otr = &ot_lds[(m0 + m) * DD + d];
            acc[m] += o4.x * otr[0] + o4.y * otr[1] + o4.z * otr[2] + o4.w * otr[3];
        }
    }
    u32 pk[8];
#pragma unroll
    for (int p = 0; p < 8; p++)
        pk[p] = (u32)f2bf(acc[2 * p]) | ((u32)f2bf(acc[2 * p + 1]) << 16);
    u16* dst = Zt + ((size_t)b * 1024 + e) * 256 + h * MM + m0;
#pragma unroll
    for (int p = 0; p < 2; p++) {
        uint4 q4; q4.x = pk[4 * p]; q4.y = pk[4 * p + 1]; q4.z = pk[4 * p + 2]; q4.w = pk[4 * p + 3];
        *(uint4*)&dst[p * 8] = q4;
    }
}

// ---------------------------------------------------------------- launch
extern "C" void kernel_launch(void* const* d_in, const int* in_sizes, int n_in,
                              void* d_out, int out_size, void* d_ws, size_t ws_size,
                              hipStream_t stream) {
    const float* x        = (const float*)d_in[0];
    const float* wkv      = (const float*)d_in[1];
    const float* bkv      = (const float*)d_in[2];
    const float* wtq      = (const float*)d_in[3];
    const float* wtq_bias = (const float*)d_in[4];
    const float* qkvp     = (const float*)d_in[5];
    const float* outw     = (const float*)d_in[6];
    const float* outb     = (const float*)d_in[7];

    float* out  = (float*)d_out;
    float* out0 = out;                      // [B,N,HD]
    float* out1 = out + 67108864;           // slice_weights
    float* out2 = out + 83886080;           // temperature + bias
    float* out4 = out + 83886337;           // attn_weights

    char* ws = (char*)d_ws;
    u16*   xb     = (u16*)(ws);                         // 134 MB: x bf16; reused as wT
    u16*   wT     = xb;
    u16*   scoresT= (u16*)(ws + 134217728);             // 33.5 MB [b*256+hm][16384]
    u16*   st_red = (u16*)(ws + 134217728);             // aliases scoresT (dead after slice_pass)
    u16*   vTg    = (u16*)(ws + 268435456);             // 134 MB [b*1024+hd][16384]
    u16*   Zt     = (u16*)(ws + 268435456);             // aliases vTg (dead after slice_pass)
    u16*   wkvb_v = (u16*)(ws + 402653184);             // 2 MB (V rows only)
    u16*   WQb    = (u16*)(ws + 404750336);             // 512 KB
    float* wqbias = (float*)(ws + 405274624);           // 1 KB
    float* pst    = (float*)(ws + 408944640);           // 33.5 MB
    float* pnorm  = (float*)(ws + 442499072);           // 256 KB
    float* otws   = (float*)(ws + 442761216);           // 512 KB

    convert_kernel<<<dim3(2048), dim3(256), 0, stream>>>(x, wkv, xb, wkvb_v, wtq_bias, out2);
    wq_kernel<<<dim3(8, 8), dim3(256), 0, stream>>>(wtq, wkv, bkv, WQb, wqbias);
    // V-half GEMM -> transposed vT
    gemm_nt<1><<<dim3(1024), dim3(512), 0, stream>>>(xb, wkvb_v, bkv, (void*)vTg, 1024, HDIM, 4, 1024, 30, 0);
    // scores GEMM -> transposed scoresT
    gemm_nt<1><<<dim3(256), dim3(512), 0, stream>>>(xb, WQb, wqbias, (void*)scoresT, 256, HDIM, 1, 0, 30, 0);
    slice_pass<<<dim3(64, 32), dim3(256), 0, stream>>>(scoresT, vTg, out1, wT, pst, pnorm);
    reduce_pst<<<dim3(8, 32), dim3(256), 0, stream>>>(pst, pnorm, st_red);
    finalize_kernel<<<dim3(32), dim3(256), 0, stream>>>(st_red, qkvp, out4, otws);
    zmat_kernel<<<dim3(8, 32), dim3(256), 0, stream>>>(otws, outw, Zt);
    gemm_nt<0><<<dim3(1024), dim3(512), 0, stream>>>(wT, Zt, outb, (void*)out0, HDIM, 256, 4, 0, 6, (long long)1024 * 256);
}

// Round 11
// 709.115 us; speedup vs baseline: 1.6069x; 1.0388x over previous
//
#include <hip/hip_runtime.h>
#include <hip/hip_bf16.h>
#include <stdint.h>

#define BB 4
#define NN 16384
#define HDIM 1024
#define HH 8
#define MM 32
#define DD 128

typedef unsigned int u32;
typedef unsigned short u16;
typedef __attribute__((ext_vector_type(8))) short short8;
typedef __attribute__((ext_vector_type(4))) float f32x4;

__device__ __forceinline__ float bf2f(u16 v) {
    union { u32 u; float f; } c; c.u = ((u32)v) << 16; return c.f;
}
__device__ __forceinline__ u16 f2bf(float f) {
    union { float f; u32 u; } c; c.f = f;
    u32 r = c.u + 0x7fffu + ((c.u >> 16) & 1u);
    return (u16)(r >> 16);
}

__device__ __forceinline__ void gload16(const u16* g, u16* l) {
    __builtin_amdgcn_global_load_lds(
        (const __attribute__((address_space(1))) void*)g,
        (__attribute__((address_space(3))) void*)l, 16, 0, 0);
}

#define MFMA16(a, b, c) __builtin_amdgcn_mfma_f32_16x16x32_bf16(a, b, c, 0, 0, 0)

// ---------------------------------------------------------------- convert + transpose
// 128x128 tiles: xb[n][e] bf16 AND xbT[b][e][n] bf16 via LDS transpose.
__global__ __launch_bounds__(256) void convert_kernel(const float* __restrict__ x,
                                                      u16* __restrict__ xb, u16* __restrict__ xbT,
                                                      const float* __restrict__ wtq_bias,
                                                      float* __restrict__ out_misc) {
    __shared__ u32 tl[128 * 65];        // [n 128][e-pair 64, pad 65] 33 KB
    const int t = threadIdx.x;
    const int eb = blockIdx.x & 7;
    const int nb = blockIdx.x >> 3;     // 512 global n-tiles (b*N/128)
    const size_t n0 = (size_t)nb * 128;
    const int e0 = eb * 128;

#pragma unroll 4
    for (int i = 0; i < 32; i++) {
        const int idx = t + i * 256;          // over 8192 float2
        const int nl = idx >> 6, e2 = idx & 63;
        const float2 v = *(const float2*)&x[(n0 + nl) * 1024 + e0 + e2 * 2];
        const u32 pk = (u32)f2bf(v.x) | ((u32)f2bf(v.y) << 16);
        ((u32*)xb)[((n0 + nl) * 1024 + e0) / 2 + e2] = pk;
        tl[nl * 65 + e2] = pk;
    }
    __syncthreads();
    const int b = (int)(n0 >> 14);
    const int nloc = (int)(n0 & 16383);
#pragma unroll 4
    for (int i = 0; i < 32; i++) {
        const int idx = t + i * 256;          // over 8192 u32 outputs (128 e x 64 n-pairs)
        const int el = idx >> 6, n2 = idx & 63;
        const u32 w0 = tl[(2 * n2) * 65 + (el >> 1)];
        const u32 w1 = tl[(2 * n2 + 1) * 65 + (el >> 1)];
        const int sh = (el & 1) * 16;
        const u32 o = ((w0 >> sh) & 0xffffu) | (((w1 >> sh) & 0xffffu) << 16);
        ((u32*)xbT)[((size_t)(b * 1024 + e0 + el) * 16384 + nloc + 2 * n2) >> 1] = o;
    }
    if (blockIdx.x == 0) {
        if (t == 0) out_misc[0] = 1.0f;
        if (t < HH * MM) out_misc[1 + t] = wtq_bias[t];
    }
}

// ---------------------------------------------------------------- WQ = wtq @ Wkv_K ; wq_bias; Wv -> bf16
__global__ __launch_bounds__(256) void wq_kernel(const float* __restrict__ wtq,
                                                 const float* __restrict__ wkv,
                                                 const float* __restrict__ bkv,
                                                 u16* __restrict__ WQb, float* __restrict__ wqbias,
                                                 u16* __restrict__ wvb) {
    __shared__ float wtql[MM * DD];
    const int ec = blockIdx.x, h = blockIdx.y, t = threadIdx.x;
    for (int i = t; i < MM * DD; i += 256) wtql[i] = wtq[(size_t)h * MM * DD + i];
    __syncthreads();
    const int m = t >> 3;
    const int e = ec * 128 + (t & 7) * 16;
    float acc[16];
#pragma unroll
    for (int j = 0; j < 16; j++) acc[j] = 0.f;
    for (int d = 0; d < DD; d++) {
        const float wv = wtql[m * DD + d];
        const float4* row = (const float4*)(wkv + (size_t)(h * DD + d) * HDIM + e);
#pragma unroll
        for (int j4 = 0; j4 < 4; j4++) {
            float4 v = row[j4];
            acc[j4 * 4 + 0] += wv * v.x; acc[j4 * 4 + 1] += wv * v.y;
            acc[j4 * 4 + 2] += wv * v.z; acc[j4 * 4 + 3] += wv * v.w;
        }
    }
    u32 pk[8];
#pragma unroll
    for (int p = 0; p < 8; p++)
        pk[p] = (u32)f2bf(acc[2 * p]) | ((u32)f2bf(acc[2 * p + 1]) << 16);
    u16* dst = WQb + (size_t)(h * MM + m) * HDIM + e;
#pragma unroll
    for (int p = 0; p < 2; p++) {
        uint4 q4; q4.x = pk[4 * p]; q4.y = pk[4 * p + 1]; q4.z = pk[4 * p + 2]; q4.w = pk[4 * p + 3];
        *(uint4*)&dst[p * 8] = q4;
    }
    if (ec == 0 && t < MM) {
        float s = 0.f;
        for (int d = 0; d < DD; d++) s += wtql[t * DD + d] * bkv[h * DD + d];
        wqbias[h * MM + t] = s;
    }
    // Wv f32 -> bf16 (64 blocks x 4096 float4 = 1M elems)
    {
        const int blk = blockIdx.y * 8 + blockIdx.x;
        const float4* src = (const float4*)(wkv + (size_t)1024 * 1024);
        for (int i = t; i < 4096; i += 256) {
            const int idx4 = blk * 4096 + i;
            float4 v = src[idx4];
            ushort4 o; o.x = f2bf(v.x); o.y = f2bf(v.y); o.z = f2bf(v.z); o.w = f2bf(v.w);
            ((ushort4*)wvb)[idx4] = o;
        }
    }
}

// ---------------------------------------------------------------- unified 8-phase GEMM (256x256, BK-slice=Kd, row-stride ldk)
// K-split via blockIdx.y (offset ks*Kd along K; MODE 0 dest += ks*kCstride).
// MODE 0: f32 C row-major (+bias[col] if bias), per-b B via bshift/bstrideB.
// MODE 1: bf16 transposed C: dst[(b*NCols + col)<<14 + n], bias[bofs+col].
template<int MODE>
__global__ __launch_bounds__(512, 1) void gemm_nt(
        const u16* __restrict__ A, const u16* __restrict__ Bm,
        const float* __restrict__ bias, void* __restrict__ Cout,
        int NCols, int Kd, int ldk, int ntn, int bofs, int bshift,
        long long bstrideB, long long kCstride) {
    __shared__ u16 ldsA[2][2][8192];
    __shared__ u16 ldsB[2][2][8192];
    const int t = threadIdx.x, l = t & 63, w = t >> 6;
    const int wr = w >> 2, wc = w & 3;

    const int nwg = gridDim.x, cpx = nwg >> 3, bid = blockIdx.x;
    const int swz = (bid & 7) * cpx + (bid >> 3);
    const int tm = swz / ntn, tn = swz % ntn;
    const int ks = blockIdx.y;
    const u16* Bb = Bm + (size_t)(tm >> bshift) * bstrideB;

    f32x4 acc[8][4];
    const f32x4 zero = {0.f, 0.f, 0.f, 0.f};
#pragma unroll
    for (int mi = 0; mi < 8; mi++)
#pragma unroll
        for (int ni = 0; ni < 4; ni++) acc[mi][ni] = zero;

    const int srow = w * 8 + (l >> 3);
    const int skel = ((l & 7) ^ ((l >> 3) & 7)) * 8;
    const u16* gA = A  + (size_t)(tm * 256 + srow) * ldk + (size_t)ks * Kd + skel;
    const u16* gB = Bb + (size_t)(tn * 256 + srow) * ldk + (size_t)ks * Kd + skel;
    const int ldo = w * 512 + l * 8;

#define STAGE_A(T, H) { const u16* g_ = gA + (size_t)((H) * 128) * ldk + (T) * 64; \
    u16* d_ = &ldsA[(T) & 1][H][ldo]; gload16(g_, d_); gload16(g_ + (size_t)64 * ldk, d_ + 4096); }
#define STAGE_B(T, H) { const u16* g_ = gB + (size_t)((H) * 128) * ldk + (T) * 64; \
    u16* d_ = &ldsB[(T) & 1][H][ldo]; gload16(g_, d_); gload16(g_ + (size_t)64 * ldk, d_ + 4096); }

    const int m16 = l & 15;
    const int ck0 = (((l >> 4) + 0) ^ (l & 7)) << 3;
    const int ck1 = (((l >> 4) + 4) ^ (l & 7)) << 3;
    const int brb = (wc & 1) * 64;
    const int nT = Kd >> 6;

    STAGE_A(0, 0); STAGE_A(0, 1); STAGE_B(0, 0); STAGE_B(0, 1);
    STAGE_B(1, 0); STAGE_B(1, 1);
    asm volatile("s_waitcnt vmcnt(4)" ::: "memory");
    __builtin_amdgcn_s_barrier();

    for (int kt = 0; kt < nT; ++kt) {
        const int sl = kt & 1;
        const u16* lA = ldsA[sl][wr];
        const u16* lB = ldsB[sl][wc >> 1];
        short8 aF[4][2], bF[4][2];

#pragma unroll
        for (int fr = 0; fr < 4; fr++) {
            aF[fr][0] = *(const short8*)&lA[(fr * 16 + m16) * 64 + ck0];
            aF[fr][1] = *(const short8*)&lA[(fr * 16 + m16) * 64 + ck1];
        }
#pragma unroll
        for (int fc = 0; fc < 2; fc++) {
            bF[fc][0] = *(const short8*)&lB[(brb + fc * 16 + m16) * 64 + ck0];
            bF[fc][1] = *(const short8*)&lB[(brb + fc * 16 + m16) * 64 + ck1];
        }
        if (kt + 1 < nT) STAGE_A(kt + 1, 0);
        __builtin_amdgcn_s_barrier();
        asm volatile("s_waitcnt lgkmcnt(0)" ::: "memory");
        __builtin_amdgcn_s_setprio(1);
#pragma unroll
        for (int kk = 0; kk < 2; kk++)
#pragma unroll
            for (int mi = 0; mi < 4; mi++) {
                acc[mi][0] = MFMA16(aF[mi][kk], bF[0][kk], acc[mi][0]);
                acc[mi][1] = MFMA16(aF[mi][kk], bF[1][kk], acc[mi][1]);
            }
        __builtin_amdgcn_s_setprio(0);
        __builtin_amdgcn_s_barrier();

#pragma unroll
        for (int fc = 2; fc < 4; fc++) {
            bF[fc][0] = *(const short8*)&lB[(brb + fc * 16 + m16) * 64 + ck0];
            bF[fc][1] = *(const short8*)&lB[(brb + fc * 16 + m16) * 64 + ck1];
        }
        if (kt + 1 < nT) STAGE_A(kt + 1, 1);
        __builtin_amdgcn_s_barrier();
        asm volatile("s_waitcnt lgkmcnt(0)" ::: "memory");
        __builtin_amdgcn_s_setprio(1);
#pragma unroll
        for (int kk = 0; kk < 2; kk++)
#pragma unroll
            for (int mi = 0; mi < 4; mi++) {
                acc[mi][2] = MFMA16(aF[mi][kk], bF[2][kk], acc[mi][2]);
                acc[mi][3] = MFMA16(aF[mi][kk], bF[3][kk], acc[mi][3]);
            }
        __builtin_amdgcn_s_setprio(0);
        __builtin_amdgcn_s_barrier();

#pragma unroll
        for (int fr = 0; fr < 4; fr++) {
            aF[fr][0] = *(const short8*)&lA[((fr + 4) * 16 + m16) * 64 + ck0];
            aF[fr][1] = *(const short8*)&lA[((fr + 4) * 16 + m16) * 64 + ck1];
        }
        if (kt + 2 < nT) STAGE_B(kt + 2, 0);
        __builtin_amdgcn_s_barrier();
        asm volatile("s_waitcnt lgkmcnt(0)" ::: "memory");
        __builtin_amdgcn_s_setprio(1);
#pragma unroll
        for (int kk = 0; kk < 2; kk++)
#pragma unroll
            for (int mi = 0; mi < 4; mi++) {
                acc[4 + mi][0] = MFMA16(aF[mi][kk], bF[0][kk], acc[4 + mi][0]);
                acc[4 + mi][1] = MFMA16(aF[mi][kk], bF[1][kk], acc[4 + mi][1]);
            }
        __builtin_amdgcn_s_setprio(0);
        __builtin_amdgcn_s_barrier();

        if (kt + 2 < nT) STAGE_B(kt + 2, 1);
        __builtin_amdgcn_s_barrier();
        __builtin_amdgcn_s_setprio(1);
#pragma unroll
        for (int kk = 0; kk < 2; kk++)
#pragma unroll
            for (int mi = 0; mi < 4; mi++) {
                acc[4 + mi][2] = MFMA16(aF[mi][kk], bF[2][kk], acc[4 + mi][2]);
                acc[4 + mi][3] = MFMA16(aF[mi][kk], bF[3][kk], acc[4 + mi][3]);
            }
        __builtin_amdgcn_s_setprio(0);
        if (kt < nT - 1) {
            if (kt + 2 < nT) asm volatile("s_waitcnt vmcnt(4)" ::: "memory");
            else             asm volatile("s_waitcnt vmcnt(0)" ::: "memory");
            __builtin_amdgcn_s_barrier();
        }
    }
#undef STAGE_A
#undef STAGE_B

    const int cr = (l >> 4) * 4;
    const int cc = l & 15;
    if (MODE == 0) {
        float* Cp = (float*)Cout + (size_t)ks * kCstride;
#pragma unroll
        for (int ni = 0; ni < 4; ni++) {
            const int col = tn * 256 + wc * 64 + ni * 16 + cc;
            const float bv = bias ? bias[col] : 0.0f;
#pragma unroll
            for (int mi = 0; mi < 8; mi++) {
                const int row0 = tm * 256 + wr * 128 + mi * 16 + cr;
#pragma unroll
                for (int q = 0; q < 4; q++)
                    Cp[(size_t)(row0 + q) * NCols + col] = acc[mi][ni][q] + bv;
            }
        }
    } else {
        const int b = tm >> 6;
        const size_t nbase = (size_t)(tm & 63) * 256 + wr * 128 + cr;
#pragma unroll
        for (int ni = 0; ni < 4; ni++) {
            const int cg = tn * 256 + wc * 64 + ni * 16 + cc;
            const float bv = bias[bofs + cg];
            u16* rowp = (u16*)Cout + (((size_t)(b * NCols + cg)) << 14) + nbase;
#pragma unroll
            for (int mi = 0; mi < 8; mi++) {
                u32 lo = (u32)f2bf(acc[mi][ni][0] + bv) | ((u32)f2bf(acc[mi][ni][1] + bv) << 16);
                u32 hi = (u32)f2bf(acc[mi][ni][2] + bv) | ((u32)f2bf(acc[mi][ni][3] + bv) << 16);
                uint2 pk; pk.x = lo; pk.y = hi;
                *(uint2*)&rowp[mi * 16] = pk;
            }
        }
    }
}

// ---------------------------------------------------------------- slice pass v6: softmax + weight outputs only
__global__ __launch_bounds__(256, 2) void slice_pass(
        const u16* __restrict__ scoresT,
        float* __restrict__ sw_out, u16* __restrict__ wN, u16* __restrict__ wT,
        float* __restrict__ pnorm) {
    __shared__ u16 sc_lds[MM * 256];    // 16 KB linear [m][n]
    __shared__ u16 w_lin[MM * 256];     // 16 KB linear [m][n]
    const int t = threadIdx.x, l = t & 63, w = t >> 6;
    const int bh = blockIdx.y, b = bh >> 3, h = bh & 7;
    const int n0 = blockIdx.x * 256;

    // stage scores rows (v5-verified pattern)
    {
        const size_t rb = (size_t)(b * 256 + h * MM);
#pragma unroll
        for (int j = 0; j < 4; j++) {
            const int rl = w * 8 + j * 2 + (l >> 5);
            gload16(scoresT + ((rb + rl) << 14) + n0 + (l & 31) * 8,
                    sc_lds + (w * 8 + j * 2) * 256 + l * 8);
        }
    }
    __syncthreads();

    // per-thread softmax over m for n = t
    {
        float sv[MM];
#pragma unroll
        for (int m = 0; m < MM; m++) sv[m] = bf2f(sc_lds[m * 256 + t]);
        float mx = sv[0];
#pragma unroll
        for (int m = 1; m < MM; m++) mx = fmaxf(mx, sv[m]);
        float sum = 0.f;
#pragma unroll
        for (int m = 0; m < MM; m++) { sv[m] = __expf(sv[m] - mx); sum += sv[m]; }
        const float inv = 1.f / sum;
        u32 pk[16];
#pragma unroll
        for (int m = 0; m < MM; m++) {
            const float wv = sv[m] * inv;
            const size_t row = (size_t)bh * MM + m;
            sw_out[row * NN + n0 + t] = wv;
            const u16 wb = f2bf(wv);
            w_lin[m * 256 + t] = wb;
            wN[row * NN + n0 + t] = wb;
            if (m & 1) pk[m >> 1] |= ((u32)wb << 16); else pk[m >> 1] = (u32)wb;
        }
        u16* wrow = wT + ((size_t)(b * NN) + n0 + t) * 256 + h * MM;
#pragma unroll
        for (int p = 0; p < 4; p++) {
            uint4 q4; q4.x = pk[4 * p]; q4.y = pk[4 * p + 1]; q4.z = pk[4 * p + 2]; q4.w = pk[4 * p + 3];
            *(uint4*)&wrow[p * 8] = q4;
        }
    }
    __syncthreads();

    // pnorm partials
    {
        const int pm = t >> 3, ps = t & 7;
        float ssum = 0.f;
        for (int j = 0; j < 32; j++) ssum += bf2f(w_lin[pm * 256 + ps * 32 + j]);
        ssum += __shfl_xor(ssum, 1); ssum += __shfl_xor(ssum, 2); ssum += __shfl_xor(ssum, 4);
        if (ps == 0) pnorm[((size_t)bh * 64 + blockIdx.x) * MM + pm] = ssum;
    }
}

// ---------------------------------------------------------------- sum U k-split partials -> bf16
__global__ __launch_bounds__(256) void sum_U(const float* __restrict__ U_part, u16* __restrict__ U_sum) {
    const int i = blockIdx.x * 256 + threadIdx.x;   // 262144 float4 groups
    float4 s = make_float4(0.f, 0.f, 0.f, 0.f);
    for (int ks = 0; ks < 8; ks++) {
        const float4 v = ((const float4*)(U_part + (size_t)ks * 1048576))[i];
        s.x += v.x; s.y += v.y; s.z += v.z; s.w += v.w;
    }
    ushort4 o; o.x = f2bf(s.x); o.y = f2bf(s.y); o.z = f2bf(s.z); o.w = f2bf(s.w);
    ((ushort4*)U_sum)[i] = o;
}

// ---------------------------------------------------------------- st_fix: st_red = (C + bv*norm)/(norm+eps), bf16
__global__ __launch_bounds__(256) void st_fix(const float* __restrict__ C_st,
                                              const float* __restrict__ pnorm,
                                              const float* __restrict__ bkv,
                                              u16* __restrict__ st_red) {
    __shared__ float norm[MM];
    const int bh = blockIdx.x, b = bh >> 3, h = bh & 7, t = threadIdx.x;
    if (t < MM) {
        float s = 0.f;
        for (int g = 0; g < 64; g++) s += pnorm[((size_t)bh * 64 + g) * MM + t];
        norm[t] = s;
    }
    __syncthreads();
#pragma unroll
    for (int i = 0; i < 16; i++) {
        const int idx = t * 16 + i;
        const int m = idx >> 7, d = idx & 127;
        const float nv = norm[m];
        const float c = C_st[(size_t)(h * 128 + d) * 1024 + b * 256 + h * 32 + m];
        const float v = (c + bkv[1024 + h * 128 + d] * nv) / (nv + 1e-5f);
        st_red[(size_t)bh * 4096 + idx] = f2bf(v);
    }
}

// ---------------------------------------------------------------- finalize (per b,h)
__global__ void finalize_kernel(const u16* __restrict__ st_red,
                                const float* __restrict__ qkvp, float* __restrict__ attn_out,
                                float* __restrict__ otw) {
    __shared__ float qt[MM * 384];
    __shared__ u16 st_lds[MM * DD];
    __shared__ float dots[MM * MM];
    const int bh = blockIdx.x, h = bh & 7, t = threadIdx.x;

    {
        const uint4* src = (const uint4*)(st_red + (size_t)bh * 4096);
        ((uint4*)st_lds)[t] = src[t];
        ((uint4*)st_lds)[t + 256] = src[t + 256];
    }
    __syncthreads();
    const float* qw = qkvp + (size_t)h * DD * 384;
    for (int i = 0; i < 48; i++) {
        int j = t + i * 256;
        int m = j / 384, e = j - m * 384;
        float s = 0.f;
        for (int d = 0; d < DD; d++) s += bf2f(st_lds[m * DD + d]) * qw[d * 384 + e];
        qt[m * 384 + e] = s;
    }
    __syncthreads();
    const float scale = 0.08838834764831845f;
#pragma unroll
    for (int i = 0; i < 4; i++) {
        int idx = t * 4 + i;
        int qi = idx >> 5, kj = idx & 31;
        float s = 0.f;
        for (int d = 0; d < DD; d++) s += qt[qi * 384 + d] * qt[kj * 384 + 128 + d];
        dots[idx] = s * scale;
    }
    __syncthreads();
    if (t < MM) {
        float mx = -1e30f;
        float ex[MM];
#pragma unroll
        for (int j = 0; j < MM; j++) mx = fmaxf(mx, dots[t * MM + j]);
        float sm = 0.f;
#pragma unroll
        for (int j = 0; j < MM; j++) { ex[j] = __expf(dots[t * MM + j] - mx); sm += ex[j]; }
        float inv = 1.f / sm;
#pragma unroll
        for (int j = 0; j < MM; j++) {
            float v = ex[j] * inv;
            dots[t * MM + j] = v;
            attn_out[((size_t)bh * MM + t) * MM + j] = v;
        }
    }
    __syncthreads();
#pragma unroll
    for (int i = 0; i < 16; i++) {
        int e = t + i * 256;
        int m = e >> 7, d = e & 127;
        float s = 0.f;
#pragma unroll
        for (int j = 0; j < MM; j++) s += dots[m * MM + j] * qt[j * 384 + 256 + d];
        otw[(size_t)bh * 4096 + e] = s;
    }
}

// ---------------------------------------------------------------- zmat
__global__ __launch_bounds__(256) void zmat_kernel(const float* __restrict__ otw,
                                                   const float* __restrict__ outw,
                                                   u16* __restrict__ Zt) {
    __shared__ float ot_lds[MM * DD];
    const int bh = blockIdx.y, b = bh >> 3, h = bh & 7;
    const int es = blockIdx.x;
    const int t = threadIdx.x;
    for (int i = t; i < MM * DD; i += 256) ot_lds[i] = otw[(size_t)bh * 4096 + i];
    __syncthreads();
    const int e = es * 128 + (t >> 1);
    const int m0 = (t & 1) * 16;
    const float* ow = outw + (size_t)e * HDIM + h * DD;
    float acc[16];
#pragma unroll
    for (int m = 0; m < 16; m++) acc[m] = 0.f;
    for (int d = 0; d < DD; d += 4) {
        float4 o4 = *(const float4*)&ow[d];
#pragma unroll
        for (int m = 0; m < 16; m++) {
            const float* otr = &ot_lds[(m0 + m) * DD + d];
            acc[m] += o4.x * otr[0] + o4.y * otr[1] + o4.z * otr[2] + o4.w * otr[3];
        }
    }
    u32 pk[8];
#pragma unroll
    for (int p = 0; p < 8; p++)
        pk[p] = (u32)f2bf(acc[2 * p]) | ((u32)f2bf(acc[2 * p + 1]) << 16);
    u16* dst = Zt + ((size_t)b * 1024 + e) * 256 + h * MM + m0;
#pragma unroll
    for (int p = 0; p < 2; p++) {
        uint4 q4; q4.x = pk[4 * p]; q4.y = pk[4 * p + 1]; q4.z = pk[4 * p + 2]; q4.w = pk[4 * p + 3];
        *(uint4*)&dst[p * 8] = q4;
    }
}

// ---------------------------------------------------------------- launch
extern "C" void kernel_launch(void* const* d_in, const int* in_sizes, int n_in,
                              void* d_out, int out_size, void* d_ws, size_t ws_size,
                              hipStream_t stream) {
    const float* x        = (const float*)d_in[0];
    const float* wkv      = (const float*)d_in[1];
    const float* bkv      = (const float*)d_in[2];
    const float* wtq      = (const float*)d_in[3];
    const float* wtq_bias = (const float*)d_in[4];
    const float* qkvp     = (const float*)d_in[5];
    const float* outw     = (const float*)d_in[6];
    const float* outb     = (const float*)d_in[7];

    float* out  = (float*)d_out;
    float* out0 = out;                      // [B,N,HD]
    float* out1 = out + 67108864;           // slice_weights
    float* out2 = out + 83886080;           // temperature + bias
    float* out4 = out + 83886337;           // attn_weights

    char* ws = (char*)d_ws;
    u16*   xb     = (u16*)(ws);                         // 134 MB; reused as wT after gemm_score
    u16*   wT     = xb;
    u16*   xbT    = (u16*)(ws + 134217728);             // 134 MB [b][e][n]
    u16*   wN     = (u16*)(ws + 268435456);             // 33.5 MB [b*256+hm][n]
    u16*   scoresT= (u16*)(ws + 301989888);             // 33.5 MB [b*256+hm][n]
    float* U_part = (float*)(ws + 335544320);           // 33.5 MB (8 ks x 1024 x 1024 f32)
    u16*   U_sum  = (u16*)(ws + 369098752);             // 2 MB
    float* C_st   = (float*)(ws + 371195904);           // 4 MB [hd][bhm]
    u16*   wvb    = (u16*)(ws + 375390208);             // 2 MB Wv bf16
    u16*   WQb    = (u16*)(ws + 377487360);             // 512 KB
    float* wqbias = (float*)(ws + 378011648);           // 1 KB
    float* pnorm  = (float*)(ws + 378012672);           // 256 KB
    u16*   st_red = (u16*)(ws + 378274816);             // 256 KB
    float* otws   = (float*)(ws + 378537984);           // 512 KB
    u16*   Zt     = (u16*)(ws + 379060224);             // 2 MB

    convert_kernel<<<dim3(4096), dim3(256), 0, stream>>>(x, xb, xbT, wtq_bias, out2);
    wq_kernel<<<dim3(8, 8), dim3(256), 0, stream>>>(wtq, wkv, bkv, WQb, wqbias, wvb);
    // scores = x @ WQ^T -> transposed scoresT
    gemm_nt<1><<<dim3(256), dim3(512), 0, stream>>>(xb, WQb, wqbias, (void*)scoresT,
                                                    256, 1024, 1024, 1, 0, 30, 0, 0);
    slice_pass<<<dim3(64, 32), dim3(256), 0, stream>>>(scoresT, out1, wN, wT, pnorm);
    // U = w @ x : A=wN [b*256+hm][16384], B=xbT per-b [1024 e][16384], split-K x8
    gemm_nt<0><<<dim3(16, 8), dim3(512), 0, stream>>>(wN, xbT, nullptr, (void*)U_part,
                                                      1024, 2048, 16384, 4, 0, 0,
                                                      (long long)16777216, (long long)1048576);
    sum_U<<<dim3(1024), dim3(256), 0, stream>>>(U_part, U_sum);
    // C_st = Wv @ U_sum^T  (f32 [hd][bhm]; cross-h columns unused)
    gemm_nt<0><<<dim3(16), dim3(512), 0, stream>>>(wvb, U_sum, nullptr, (void*)C_st,
                                                   1024, 1024, 1024, 4, 0, 30, 0, 0);
    st_fix<<<dim3(32), dim3(256), 0, stream>>>(C_st, pnorm, bkv, st_red);
    finalize_kernel<<<dim3(32), dim3(256), 0, stream>>>(st_red, qkvp, out4, otws);
    zmat_kernel<<<dim3(8, 32), dim3(256), 0, stream>>>(otws, outw, Zt);
    gemm_nt<0><<<dim3(1024), dim3(512), 0, stream>>>(wT, Zt, outb, (void*)out0,
                                                     1024, 256, 256, 4, 0, 6,
                                                     (long long)262144, 0);
}

// Round 12
// 662.240 us; speedup vs baseline: 1.7207x; 1.0708x over previous
//
#include <hip/hip_runtime.h>
#include <hip/hip_bf16.h>
#include <stdint.h>

#define BB 4
#define NN 16384
#define HDIM 1024
#define HH 8
#define MM 32
#define DD 128

typedef unsigned int u32;
typedef unsigned short u16;
typedef __attribute__((ext_vector_type(8))) short short8;
typedef __attribute__((ext_vector_type(4))) float f32x4;

__device__ __forceinline__ float bf2f(u16 v) {
    union { u32 u; float f; } c; c.u = ((u32)v) << 16; return c.f;
}
__device__ __forceinline__ u16 f2bf(float f) {
    union { float f; u32 u; } c; c.f = f;
    u32 r = c.u + 0x7fffu + ((c.u >> 16) & 1u);
    return (u16)(r >> 16);
}

__device__ __forceinline__ void gload16(const u16* g, u16* l) {
    __builtin_amdgcn_global_load_lds(
        (const __attribute__((address_space(1))) void*)g,
        (__attribute__((address_space(3))) void*)l, 16, 0, 0);
}

#define MFMA16(a, b, c) __builtin_amdgcn_mfma_f32_16x16x32_bf16(a, b, c, 0, 0, 0)

// ---------------------------------------------------------------- convert + transpose
__global__ __launch_bounds__(256) void convert_kernel(const float* __restrict__ x,
                                                      u16* __restrict__ xb, u16* __restrict__ xbT,
                                                      const float* __restrict__ wtq_bias,
                                                      float* __restrict__ out_misc) {
    __shared__ u32 tl[128 * 65];
    const int t = threadIdx.x;
    const int eb = blockIdx.x & 7;
    const int nb = blockIdx.x >> 3;
    const size_t n0 = (size_t)nb * 128;
    const int e0 = eb * 128;

#pragma unroll 4
    for (int i = 0; i < 32; i++) {
        const int idx = t + i * 256;
        const int nl = idx >> 6, e2 = idx & 63;
        const float2 v = *(const float2*)&x[(n0 + nl) * 1024 + e0 + e2 * 2];
        const u32 pk = (u32)f2bf(v.x) | ((u32)f2bf(v.y) << 16);
        ((u32*)xb)[((n0 + nl) * 1024 + e0) / 2 + e2] = pk;
        tl[nl * 65 + e2] = pk;
    }
    __syncthreads();
    const int b = (int)(n0 >> 14);
    const int nloc = (int)(n0 & 16383);
#pragma unroll 4
    for (int i = 0; i < 32; i++) {
        const int idx = t + i * 256;
        const int el = idx >> 6, n2 = idx & 63;
        const u32 w0 = tl[(2 * n2) * 65 + (el >> 1)];
        const u32 w1 = tl[(2 * n2 + 1) * 65 + (el >> 1)];
        const int sh = (el & 1) * 16;
        const u32 o = ((w0 >> sh) & 0xffffu) | (((w1 >> sh) & 0xffffu) << 16);
        ((u32*)xbT)[((size_t)(b * 1024 + e0 + el) * 16384 + nloc + 2 * n2) >> 1] = o;
    }
    if (blockIdx.x == 0) {
        if (t == 0) out_misc[0] = 1.0f;
        if (t < HH * MM) out_misc[1 + t] = wtq_bias[t];
    }
}

// ---------------------------------------------------------------- WQ = wtq @ Wkv_K ; wq_bias; Wv -> bf16
__global__ __launch_bounds__(256) void wq_kernel(const float* __restrict__ wtq,
                                                 const float* __restrict__ wkv,
                                                 const float* __restrict__ bkv,
                                                 u16* __restrict__ WQb, float* __restrict__ wqbias,
                                                 u16* __restrict__ wvb) {
    __shared__ float wtql[MM * DD];
    const int ec = blockIdx.x, h = blockIdx.y, t = threadIdx.x;
    for (int i = t; i < MM * DD; i += 256) wtql[i] = wtq[(size_t)h * MM * DD + i];
    __syncthreads();
    const int m = t >> 3;
    const int e = ec * 128 + (t & 7) * 16;
    float acc[16];
#pragma unroll
    for (int j = 0; j < 16; j++) acc[j] = 0.f;
    for (int d = 0; d < DD; d++) {
        const float wv = wtql[m * DD + d];
        const float4* row = (const float4*)(wkv + (size_t)(h * DD + d) * HDIM + e);
#pragma unroll
        for (int j4 = 0; j4 < 4; j4++) {
            float4 v = row[j4];
            acc[j4 * 4 + 0] += wv * v.x; acc[j4 * 4 + 1] += wv * v.y;
            acc[j4 * 4 + 2] += wv * v.z; acc[j4 * 4 + 3] += wv * v.w;
        }
    }
    u32 pk[8];
#pragma unroll
    for (int p = 0; p < 8; p++)
        pk[p] = (u32)f2bf(acc[2 * p]) | ((u32)f2bf(acc[2 * p + 1]) << 16);
    u16* dst = WQb + (size_t)(h * MM + m) * HDIM + e;
#pragma unroll
    for (int p = 0; p < 2; p++) {
        uint4 q4; q4.x = pk[4 * p]; q4.y = pk[4 * p + 1]; q4.z = pk[4 * p + 2]; q4.w = pk[4 * p + 3];
        *(uint4*)&dst[p * 8] = q4;
    }
    if (ec == 0 && t < MM) {
        float s = 0.f;
        for (int d = 0; d < DD; d++) s += wtql[t * DD + d] * bkv[h * DD + d];
        wqbias[h * MM + t] = s;
    }
    {
        const int blk = blockIdx.y * 8 + blockIdx.x;
        const float4* src = (const float4*)(wkv + (size_t)1024 * 1024);
        for (int i = t; i < 4096; i += 256) {
            const int idx4 = blk * 4096 + i;
            float4 v = src[idx4];
            ushort4 o; o.x = f2bf(v.x); o.y = f2bf(v.y); o.z = f2bf(v.z); o.w = f2bf(v.w);
            ((ushort4*)wvb)[idx4] = o;
        }
    }
}

// ---------------------------------------------------------------- unified 8-phase GEMM (256x256)
template<int MODE>
__global__ __launch_bounds__(512, 1) void gemm_nt(
        const u16* __restrict__ A, const u16* __restrict__ Bm,
        const float* __restrict__ bias, void* __restrict__ Cout,
        int NCols, int Kd, int ldk, int ntn, int bofs, int bshift,
        long long bstrideB, long long kCstride) {
    __shared__ u16 ldsA[2][2][8192];
    __shared__ u16 ldsB[2][2][8192];
    const int t = threadIdx.x, l = t & 63, w = t >> 6;
    const int wr = w >> 2, wc = w & 3;

    const int nwg = gridDim.x, cpx = nwg >> 3, bid = blockIdx.x;
    const int swz = (nwg >= 8) ? ((bid & 7) * cpx + (bid >> 3)) : bid;
    const int tm = swz / ntn, tn = swz % ntn;
    const int ks = blockIdx.y;
    const u16* Bb = Bm + (size_t)(tm >> bshift) * bstrideB;

    f32x4 acc[8][4];
    const f32x4 zero = {0.f, 0.f, 0.f, 0.f};
#pragma unroll
    for (int mi = 0; mi < 8; mi++)
#pragma unroll
        for (int ni = 0; ni < 4; ni++) acc[mi][ni] = zero;

    const int srow = w * 8 + (l >> 3);
    const int skel = ((l & 7) ^ ((l >> 3) & 7)) * 8;
    const u16* gA = A  + (size_t)(tm * 256 + srow) * ldk + (size_t)ks * Kd + skel;
    const u16* gB = Bb + (size_t)(tn * 256 + srow) * ldk + (size_t)ks * Kd + skel;
    const int ldo = w * 512 + l * 8;

#define STAGE_A(T, H) { const u16* g_ = gA + (size_t)((H) * 128) * ldk + (T) * 64; \
    u16* d_ = &ldsA[(T) & 1][H][ldo]; gload16(g_, d_); gload16(g_ + (size_t)64 * ldk, d_ + 4096); }
#define STAGE_B(T, H) { const u16* g_ = gB + (size_t)((H) * 128) * ldk + (T) * 64; \
    u16* d_ = &ldsB[(T) & 1][H][ldo]; gload16(g_, d_); gload16(g_ + (size_t)64 * ldk, d_ + 4096); }

    const int m16 = l & 15;
    const int ck0 = (((l >> 4) + 0) ^ (l & 7)) << 3;
    const int ck1 = (((l >> 4) + 4) ^ (l & 7)) << 3;
    const int brb = (wc & 1) * 64;
    const int nT = Kd >> 6;

    STAGE_A(0, 0); STAGE_A(0, 1); STAGE_B(0, 0); STAGE_B(0, 1);
    STAGE_B(1, 0); STAGE_B(1, 1);
    asm volatile("s_waitcnt vmcnt(4)" ::: "memory");
    __builtin_amdgcn_s_barrier();

    for (int kt = 0; kt < nT; ++kt) {
        const int sl = kt & 1;
        const u16* lA = ldsA[sl][wr];
        const u16* lB = ldsB[sl][wc >> 1];
        short8 aF[4][2], bF[4][2];

#pragma unroll
        for (int fr = 0; fr < 4; fr++) {
            aF[fr][0] = *(const short8*)&lA[(fr * 16 + m16) * 64 + ck0];
            aF[fr][1] = *(const short8*)&lA[(fr * 16 + m16) * 64 + ck1];
        }
#pragma unroll
        for (int fc = 0; fc < 2; fc++) {
            bF[fc][0] = *(const short8*)&lB[(brb + fc * 16 + m16) * 64 + ck0];
            bF[fc][1] = *(const short8*)&lB[(brb + fc * 16 + m16) * 64 + ck1];
        }
        if (kt + 1 < nT) STAGE_A(kt + 1, 0);
        __builtin_amdgcn_s_barrier();
        asm volatile("s_waitcnt lgkmcnt(0)" ::: "memory");
        __builtin_amdgcn_s_setprio(1);
#pragma unroll
        for (int kk = 0; kk < 2; kk++)
#pragma unroll
            for (int mi = 0; mi < 4; mi++) {
                acc[mi][0] = MFMA16(aF[mi][kk], bF[0][kk], acc[mi][0]);
                acc[mi][1] = MFMA16(aF[mi][kk], bF[1][kk], acc[mi][1]);
            }
        __builtin_amdgcn_s_setprio(0);
        __builtin_amdgcn_s_barrier();

#pragma unroll
        for (int fc = 2; fc < 4; fc++) {
            bF[fc][0] = *(const short8*)&lB[(brb + fc * 16 + m16) * 64 + ck0];
            bF[fc][1] = *(const short8*)&lB[(brb + fc * 16 + m16) * 64 + ck1];
        }
        if (kt + 1 < nT) STAGE_A(kt + 1, 1);
        __builtin_amdgcn_s_barrier();
        asm volatile("s_waitcnt lgkmcnt(0)" ::: "memory");
        __builtin_amdgcn_s_setprio(1);
#pragma unroll
        for (int kk = 0; kk < 2; kk++)
#pragma unroll
            for (int mi = 0; mi < 4; mi++) {
                acc[mi][2] = MFMA16(aF[mi][kk], bF[2][kk], acc[mi][2]);
                acc[mi][3] = MFMA16(aF[mi][kk], bF[3][kk], acc[mi][3]);
            }
        __builtin_amdgcn_s_setprio(0);
        __builtin_amdgcn_s_barrier();

#pragma unroll
        for (int fr = 0; fr < 4; fr++) {
            aF[fr][0] = *(const short8*)&lA[((fr + 4) * 16 + m16) * 64 + ck0];
            aF[fr][1] = *(const short8*)&lA[((fr + 4) * 16 + m16) * 64 + ck1];
        }
        if (kt + 2 < nT) STAGE_B(kt + 2, 0);
        __builtin_amdgcn_s_barrier();
        asm volatile("s_waitcnt lgkmcnt(0)" ::: "memory");
        __builtin_amdgcn_s_setprio(1);
#pragma unroll
        for (int kk = 0; kk < 2; kk++)
#pragma unroll
            for (int mi = 0; mi < 4; mi++) {
                acc[4 + mi][0] = MFMA16(aF[mi][kk], bF[0][kk], acc[4 + mi][0]);
                acc[4 + mi][1] = MFMA16(aF[mi][kk], bF[1][kk], acc[4 + mi][1]);
            }
        __builtin_amdgcn_s_setprio(0);
        __builtin_amdgcn_s_barrier();

        if (kt + 2 < nT) STAGE_B(kt + 2, 1);
        __builtin_amdgcn_s_barrier();
        __builtin_amdgcn_s_setprio(1);
#pragma unroll
        for (int kk = 0; kk < 2; kk++)
#pragma unroll
            for (int mi = 0; mi < 4; mi++) {
                acc[4 + mi][2] = MFMA16(aF[mi][kk], bF[2][kk], acc[4 + mi][2]);
                acc[4 + mi][3] = MFMA16(aF[mi][kk], bF[3][kk], acc[4 + mi][3]);
            }
        __builtin_amdgcn_s_setprio(0);
        if (kt < nT - 1) {
            if (kt + 2 < nT) asm volatile("s_waitcnt vmcnt(4)" ::: "memory");
            else             asm volatile("s_waitcnt vmcnt(0)" ::: "memory");
            __builtin_amdgcn_s_barrier();
        }
    }
#undef STAGE_A
#undef STAGE_B

    const int cr = (l >> 4) * 4;
    const int cc = l & 15;
    if (MODE == 0) {
        float* Cp = (float*)Cout + (size_t)ks * kCstride;
#pragma unroll
        for (int ni = 0; ni < 4; ni++) {
            const int col = tn * 256 + wc * 64 + ni * 16 + cc;
            const float bv = bias ? bias[col] : 0.0f;
#pragma unroll
            for (int mi = 0; mi < 8; mi++) {
                const int row0 = tm * 256 + wr * 128 + mi * 16 + cr;
#pragma unroll
                for (int q = 0; q < 4; q++)
                    Cp[(size_t)(row0 + q) * NCols + col] = acc[mi][ni][q] + bv;
            }
        }
    } else {
        const int b = tm >> 6;
        const size_t nbase = (size_t)(tm & 63) * 256 + wr * 128 + cr;
#pragma unroll
        for (int ni = 0; ni < 4; ni++) {
            const int cg = tn * 256 + wc * 64 + ni * 16 + cc;
            const float bv = bias[bofs + cg];
            u16* rowp = (u16*)Cout + (((size_t)(b * NCols + cg)) << 14) + nbase;
#pragma unroll
            for (int mi = 0; mi < 8; mi++) {
                u32 lo = (u32)f2bf(acc[mi][ni][0] + bv) | ((u32)f2bf(acc[mi][ni][1] + bv) << 16);
                u32 hi = (u32)f2bf(acc[mi][ni][2] + bv) | ((u32)f2bf(acc[mi][ni][3] + bv) << 16);
                uint2 pk; pk.x = lo; pk.y = hi;
                *(uint2*)&rowp[mi * 16] = pk;
            }
        }
    }
}

// ---------------------------------------------------------------- small 2-phase GEMM (128x128, BK=32, 16 KB LDS)
// C[row][col] f32 (+bias if non-null). Per-tile B select via bshift/bstrideB.
// K-split via blockIdx.y (slice Kds at offset ks*Kds; C += ks*kCstride).
__global__ __launch_bounds__(256, 2) void gemm_small(
        const u16* __restrict__ A, const u16* __restrict__ Bm,
        const float* __restrict__ bias, float* __restrict__ Cout,
        int Ncols, int Kds, int ldk, int ntn, int bshift,
        long long bstrideB, long long kCstride) {
    __shared__ u16 lds_a[128 * 32];
    __shared__ u16 lds_b[128 * 32];
    const int t = threadIdx.x, l = t & 63, w = t >> 6;
    const int wr = w >> 1, wc = w & 1;

    const int nwg = gridDim.x, cpx = nwg >> 3, bid = blockIdx.x;
    const int swz = (nwg >= 8) ? ((bid & 7) * cpx + (bid >> 3)) : bid;
    const int tm = swz / ntn, tn = swz % ntn;
    const int ks = blockIdx.y;
    const u16* Bb = Bm + (size_t)(tm >> bshift) * bstrideB;

    f32x4 acc[4][4];
    const f32x4 zero = {0.f, 0.f, 0.f, 0.f};
#pragma unroll
    for (int mi = 0; mi < 4; mi++)
#pragma unroll
        for (int ni = 0; ni < 4; ni++) acc[mi][ni] = zero;

    const int srow = w * 32 + (l >> 2);
    const int scol = (l & 3) * 8;
    const u16* ga = A  + (size_t)(tm * 128 + srow) * ldk + (size_t)ks * Kds + scol;
    const u16* gb = Bb + (size_t)(tn * 128 + srow) * ldk + (size_t)ks * Kds + scol;
    u16* la = &lds_a[(w * 32) * 32];
    u16* lb = &lds_b[(w * 32) * 32];
    const size_t rstep = (size_t)16 * ldk;

    const int nK = Kds >> 5;
    const int kg = (l >> 4) * 8;
    const int ra = wr * 64 + (l & 15);
    const int rb = wc * 64 + (l & 15);

    for (int kt = 0; kt < nK; kt++) {
        __syncthreads();
        const int ko = kt << 5;
        gload16(ga + ko,         la);
        gload16(ga + ko + rstep, la + 16 * 32);
        gload16(gb + ko,         lb);
        gload16(gb + ko + rstep, lb + 16 * 32);
        __syncthreads();

        short8 af[4], bfr[4];
#pragma unroll
        for (int mi = 0; mi < 4; mi++) af[mi] = *(const short8*)&lds_a[(ra + mi * 16) * 32 + kg];
#pragma unroll
        for (int ni = 0; ni < 4; ni++) bfr[ni] = *(const short8*)&lds_b[(rb + ni * 16) * 32 + kg];
#pragma unroll
        for (int mi = 0; mi < 4; mi++)
#pragma unroll
            for (int ni = 0; ni < 4; ni++)
                acc[mi][ni] = MFMA16(af[mi], bfr[ni], acc[mi][ni]);
    }

    float* Cp = Cout + (size_t)ks * kCstride;
#pragma unroll
    for (int ni = 0; ni < 4; ni++) {
        const int col = tn * 128 + wc * 64 + ni * 16 + (l & 15);
        const float bv = bias ? bias[col] : 0.0f;
#pragma unroll
        for (int mi = 0; mi < 4; mi++) {
            const int row0 = tm * 128 + wr * 64 + mi * 16 + ((l >> 4) << 2);
#pragma unroll
            for (int q = 0; q < 4; q++)
                Cp[(size_t)(row0 + q) * Ncols + col] = acc[mi][ni][q] + bv;
        }
    }
}

// ---------------------------------------------------------------- slice pass v6
__global__ __launch_bounds__(256, 2) void slice_pass(
        const u16* __restrict__ scoresT,
        float* __restrict__ sw_out, u16* __restrict__ wN, u16* __restrict__ wT,
        float* __restrict__ pnorm) {
    __shared__ u16 sc_lds[MM * 256];
    __shared__ u16 w_lin[MM * 256];
    const int t = threadIdx.x, l = t & 63, w = t >> 6;
    const int bh = blockIdx.y, b = bh >> 3, h = bh & 7;
    const int n0 = blockIdx.x * 256;

    {
        const size_t rb = (size_t)(b * 256 + h * MM);
#pragma unroll
        for (int j = 0; j < 4; j++) {
            const int rl = w * 8 + j * 2 + (l >> 5);
            gload16(scoresT + ((rb + rl) << 14) + n0 + (l & 31) * 8,
                    sc_lds + (w * 8 + j * 2) * 256 + l * 8);
        }
    }
    __syncthreads();

    {
        float sv[MM];
#pragma unroll
        for (int m = 0; m < MM; m++) sv[m] = bf2f(sc_lds[m * 256 + t]);
        float mx = sv[0];
#pragma unroll
        for (int m = 1; m < MM; m++) mx = fmaxf(mx, sv[m]);
        float sum = 0.f;
#pragma unroll
        for (int m = 0; m < MM; m++) { sv[m] = __expf(sv[m] - mx); sum += sv[m]; }
        const float inv = 1.f / sum;
        u32 pk[16];
#pragma unroll
        for (int m = 0; m < MM; m++) {
            const float wv = sv[m] * inv;
            const size_t row = (size_t)bh * MM + m;
            sw_out[row * NN + n0 + t] = wv;
            const u16 wb = f2bf(wv);
            w_lin[m * 256 + t] = wb;
            wN[row * NN + n0 + t] = wb;
            if (m & 1) pk[m >> 1] |= ((u32)wb << 16); else pk[m >> 1] = (u32)wb;
        }
        u16* wrow = wT + ((size_t)(b * NN) + n0 + t) * 256 + h * MM;
#pragma unroll
        for (int p = 0; p < 4; p++) {
            uint4 q4; q4.x = pk[4 * p]; q4.y = pk[4 * p + 1]; q4.z = pk[4 * p + 2]; q4.w = pk[4 * p + 3];
            *(uint4*)&wrow[p * 8] = q4;
        }
    }
    __syncthreads();

    {
        const int pm = t >> 3, ps = t & 7;
        float ssum = 0.f;
        for (int j = 0; j < 32; j++) ssum += bf2f(w_lin[pm * 256 + ps * 32 + j]);
        ssum += __shfl_xor(ssum, 1); ssum += __shfl_xor(ssum, 2); ssum += __shfl_xor(ssum, 4);
        if (ps == 0) pnorm[((size_t)bh * 64 + blockIdx.x) * MM + pm] = ssum;
    }
}

// ---------------------------------------------------------------- sum U k-split partials (16) -> reordered bf16 U2
// U2 row r2 = h*128 + b*32 + m
__global__ __launch_bounds__(256) void sum_U(const float* __restrict__ U_part, u16* __restrict__ U2) {
    const int i = blockIdx.x * 256 + threadIdx.x;   // 262144 float4 groups
    float4 s = make_float4(0.f, 0.f, 0.f, 0.f);
    for (int ks = 0; ks < 16; ks++) {
        const float4 v = ((const float4*)(U_part + (size_t)ks * 1048576))[i];
        s.x += v.x; s.y += v.y; s.z += v.z; s.w += v.w;
    }
    const int r = i >> 8, e4 = i & 255;
    const int b = r >> 8, h = (r >> 5) & 7, m = r & 31;
    const int r2 = h * 128 + b * 32 + m;
    ushort4 o; o.x = f2bf(s.x); o.y = f2bf(s.y); o.z = f2bf(s.z); o.w = f2bf(s.w);
    ((ushort4*)U2)[r2 * 256 + e4] = o;
}

// ---------------------------------------------------------------- sum C_st k-split partials (8)
__global__ __launch_bounds__(256) void sum_Cst(const float* __restrict__ C2, float* __restrict__ C_st) {
    const int i = blockIdx.x * 256 + threadIdx.x;   // 32768 float4 groups over [1024][128]
    float4 s = make_float4(0.f, 0.f, 0.f, 0.f);
    for (int ks = 0; ks < 8; ks++) {
        const float4 v = ((const float4*)(C2 + (size_t)ks * 131072))[i];
        s.x += v.x; s.y += v.y; s.z += v.z; s.w += v.w;
    }
    ((float4*)C_st)[i] = s;
}

// ---------------------------------------------------------------- st_fix: st_red = (C + bv*norm)/(norm+eps), bf16
// C_st layout [1024 hd][128 col], col = b*32 + m
__global__ __launch_bounds__(256) void st_fix(const float* __restrict__ C_st,
                                              const float* __restrict__ pnorm,
                                              const float* __restrict__ bkv,
                                              u16* __restrict__ st_red) {
    __shared__ float norm[MM];
    const int bh = blockIdx.x, b = bh >> 3, h = bh & 7, t = threadIdx.x;
    if (t < MM) {
        float s = 0.f;
        for (int g = 0; g < 64; g++) s += pnorm[((size_t)bh * 64 + g) * MM + t];
        norm[t] = s;
    }
    __syncthreads();
#pragma unroll
    for (int i = 0; i < 16; i++) {
        const int idx = t * 16 + i;
        const int m = idx >> 7, d = idx & 127;
        const float nv = norm[m];
        const float c = C_st[(size_t)(h * 128 + d) * 128 + b * 32 + m];
        const float v = (c + bkv[1024 + h * 128 + d] * nv) / (nv + 1e-5f);
        st_red[(size_t)bh * 4096 + idx] = f2bf(v);
    }
}

// ---------------------------------------------------------------- finalize (per b,h)
__global__ void finalize_kernel(const u16* __restrict__ st_red,
                                const float* __restrict__ qkvp, float* __restrict__ attn_out,
                                float* __restrict__ otw) {
    __shared__ float qt[MM * 384];
    __shared__ u16 st_lds[MM * DD];
    __shared__ float dots[MM * MM];
    const int bh = blockIdx.x, h = bh & 7, t = threadIdx.x;

    {
        const uint4* src = (const uint4*)(st_red + (size_t)bh * 4096);
        ((uint4*)st_lds)[t] = src[t];
        ((uint4*)st_lds)[t + 256] = src[t + 256];
    }
    __syncthreads();
    const float* qw = qkvp + (size_t)h * DD * 384;
    for (int i = 0; i < 48; i++) {
        int j = t + i * 256;
        int m = j / 384, e = j - m * 384;
        float s = 0.f;
        for (int d = 0; d < DD; d++) s += bf2f(st_lds[m * DD + d]) * qw[d * 384 + e];
        qt[m * 384 + e] = s;
    }
    __syncthreads();
    const float scale = 0.08838834764831845f;
#pragma unroll
    for (int i = 0; i < 4; i++) {
        int idx = t * 4 + i;
        int qi = idx >> 5, kj = idx & 31;
        float s = 0.f;
        for (int d = 0; d < DD; d++) s += qt[qi * 384 + d] * qt[kj * 384 + 128 + d];
        dots[idx] = s * scale;
    }
    __syncthreads();
    if (t < MM) {
        float mx = -1e30f;
        float ex[MM];
#pragma unroll
        for (int j = 0; j < MM; j++) mx = fmaxf(mx, dots[t * MM + j]);
        float sm = 0.f;
#pragma unroll
        for (int j = 0; j < MM; j++) { ex[j] = __expf(dots[t * MM + j] - mx); sm += ex[j]; }
        float inv = 1.f / sm;
#pragma unroll
        for (int j = 0; j < MM; j++) {
            float v = ex[j] * inv;
            dots[t * MM + j] = v;
            attn_out[((size_t)bh * MM + t) * MM + j] = v;
        }
    }
    __syncthreads();
#pragma unroll
    for (int i = 0; i < 16; i++) {
        int e = t + i * 256;
        int m = e >> 7, d = e & 127;
        float s = 0.f;
#pragma unroll
        for (int j = 0; j < MM; j++) s += dots[m * MM + j] * qt[j * 384 + 256 + d];
        otw[(size_t)bh * 4096 + e] = s;
    }
}

// ---------------------------------------------------------------- zmat
__global__ __launch_bounds__(256) void zmat_kernel(const float* __restrict__ otw,
                                                   const float* __restrict__ outw,
                                                   u16* __restrict__ Zt) {
    __shared__ float ot_lds[MM * DD];
    const int bh = blockIdx.y, b = bh >> 3, h = bh & 7;
    const int es = blockIdx.x;
    const int t = threadIdx.x;
    for (int i = t; i < MM * DD; i += 256) ot_lds[i] = otw[(size_t)bh * 4096 + i];
    __syncthreads();
    const int e = es * 128 + (t >> 1);
    const int m0 = (t & 1) * 16;
    const float* ow = outw + (size_t)e * HDIM + h * DD;
    float acc[16];
#pragma unroll
    for (int m = 0; m < 16; m++) acc[m] = 0.f;
    for (int d = 0; d < DD; d += 4) {
        float4 o4 = *(const float4*)&ow[d];
#pragma unroll
        for (int m = 0; m < 16; m++) {
            const float* otr = &ot_lds[(m0 + m) * DD + d];
            acc[m] += o4.x * otr[0] + o4.y * otr[1] + o4.z * otr[2] + o4.w * otr[3];
        }
    }
    u32 pk[8];
#pragma unroll
    for (int p = 0; p < 8; p++)
        pk[p] = (u32)f2bf(acc[2 * p]) | ((u32)f2bf(acc[2 * p + 1]) << 16);
    u16* dst = Zt + ((size_t)b * 1024 + e) * 256 + h * MM + m0;
#pragma unroll
    for (int p = 0; p < 2; p++) {
        uint4 q4; q4.x = pk[4 * p]; q4.y = pk[4 * p + 1]; q4.z = pk[4 * p + 2]; q4.w = pk[4 * p + 3];
        *(uint4*)&dst[p * 8] = q4;
    }
}

// ---------------------------------------------------------------- launch
extern "C" void kernel_launch(void* const* d_in, const int* in_sizes, int n_in,
                              void* d_out, int out_size, void* d_ws, size_t ws_size,
                              hipStream_t stream) {
    const float* x        = (const float*)d_in[0];
    const float* wkv      = (const float*)d_in[1];
    const float* bkv      = (const float*)d_in[2];
    const float* wtq      = (const float*)d_in[3];
    const float* wtq_bias = (const float*)d_in[4];
    const float* qkvp     = (const float*)d_in[5];
    const float* outw     = (const float*)d_in[6];
    const float* outb     = (const float*)d_in[7];

    float* out  = (float*)d_out;
    float* out0 = out;                      // [B,N,HD]
    float* out1 = out + 67108864;           // slice_weights
    float* out2 = out + 83886080;           // temperature + bias
    float* out4 = out + 83886337;           // attn_weights

    char* ws = (char*)d_ws;
    u16*   xb     = (u16*)(ws);                         // 134 MB; reused as wT after gemm_score
    u16*   wT     = xb;
    u16*   xbT    = (u16*)(ws + 134217728);             // 134 MB [b][e][n]
    u16*   wN     = (u16*)(ws + 268435456);             // 33.5 MB [b*256+hm][n]
    u16*   scoresT= (u16*)(ws + 301989888);             // 33.5 MB
    float* U_part = (float*)(ws + 335544320);           // 67 MB (16 x 1024x1024 f32)
    u16*   U2     = (u16*)(ws + 402653184);             // 2 MB [h*128+b*32+m][1024 e]
    float* C2     = (float*)(ws + 404750336);           // 4 MB (8 x 1024x128 f32)
    float* C_st   = (float*)(ws + 408944640);           // 512 KB [1024 hd][128 bm]
    u16*   wvb    = (u16*)(ws + 409468928);             // 2 MB
    u16*   WQb    = (u16*)(ws + 411566080);             // 512 KB
    float* wqbias = (float*)(ws + 412090368);           // 1 KB
    float* pnorm  = (float*)(ws + 412091392);           // 256 KB
    u16*   st_red = (u16*)(ws + 412353536);             // 256 KB
    float* otws   = (float*)(ws + 412615680);           // 512 KB
    u16*   Zt     = (u16*)(ws + 413138944);             // 2 MB

    convert_kernel<<<dim3(4096), dim3(256), 0, stream>>>(x, xb, xbT, wtq_bias, out2);
    wq_kernel<<<dim3(8, 8), dim3(256), 0, stream>>>(wtq, wkv, bkv, WQb, wqbias, wvb);
    // scores = x @ WQ^T -> transposed scoresT
    gemm_nt<1><<<dim3(256), dim3(512), 0, stream>>>(xb, WQb, wqbias, (void*)scoresT,
                                                    256, 1024, 1024, 1, 0, 30, 0, 0);
    slice_pass<<<dim3(64, 32), dim3(256), 0, stream>>>(scoresT, out1, wN, wT, pnorm);
    // U = w @ x : split-K x16 over n (Kd=1024 each)
    gemm_nt<0><<<dim3(16, 16), dim3(512), 0, stream>>>(wN, xbT, nullptr, (void*)U_part,
                                                       1024, 1024, 16384, 4, 0, 0,
                                                       (long long)16777216, (long long)1048576);
    sum_U<<<dim3(1024), dim3(256), 0, stream>>>(U_part, U2);
    // C_st[hd][b*32+m] = Wv_h @ U2_h^T, per-h diagonal tiles, split-K x8
    gemm_small<<<dim3(8, 8), dim3(256), 0, stream>>>(wvb, U2, nullptr, C2,
                                                     128, 128, 1024, 1, 0,
                                                     (long long)131072, (long long)131072);
    sum_Cst<<<dim3(128), dim3(256), 0, stream>>>(C2, C_st);
    st_fix<<<dim3(32), dim3(256), 0, stream>>>(C_st, pnorm, bkv, st_red);
    finalize_kernel<<<dim3(32), dim3(256), 0, stream>>>(st_red, qkvp, out4, otws);
    zmat_kernel<<<dim3(8, 32), dim3(256), 0, stream>>>(otws, outw, Zt);
    // out0 = wT @ Zt^T (+outb), 128^2 tiles, 4 blocks/CU for write overlap
    gemm_small<<<dim3(4096), dim3(256), 0, stream>>>(wT, Zt, outb, out0,
                                                     1024, 256, 256, 8, 7,
                                                     (long long)262144, 0);
}